// Round 3
// baseline (16862.361 us; speedup 1.0000x reference)
//
#include <hip/hip_runtime.h>
#include <math.h>

#define B_SZ 128
#define T_SZ 128
#define EMBD 300
#define ND 512
#define G3 1536

typedef short s16x8 __attribute__((ext_vector_type(8)));
typedef float f32x4 __attribute__((ext_vector_type(4)));

__device__ __forceinline__ unsigned short f2b(float x) {
    unsigned u = __float_as_uint(x);
    unsigned r = (u + 0x7fff + ((u >> 16) & 1)) >> 16;  // RNE
    return (unsigned short)r;
}
__device__ __forceinline__ float b2f(unsigned short v) {
    return __uint_as_float(((unsigned)v) << 16);
}
__device__ __forceinline__ float fsigmoid(float x) {
    return 1.0f / (1.0f + __expf(-x));
}
__device__ __forceinline__ float ftanh(float x) {
    return 1.0f - 2.0f / (__expf(2.0f * x) + 1.0f);
}

// ---------------- generic MFMA GEMM ----------------
// C[M,N] = gather(A,idxA) @ Wb^T (+bias) (+addC). Wb bf16 (N x Kpad) zero-padded.
// Block 256 thr = 4 waves (2x2), tile 64x64, BK=32.
template<typename AT, bool OB>
__global__ __launch_bounds__(256)
void mfma_gemm(const AT* __restrict__ A, const int* __restrict__ idxA,
               const unsigned short* __restrict__ Wb, const float* __restrict__ bias,
               const float* __restrict__ addC, void* __restrict__ Cv,
               int M, int N, int K, int ldA, int Kpad, int ldC, int ldAdd)
{
    __shared__ unsigned short As[64][40];
    __shared__ unsigned short Bs[64][40];
    const int tid = threadIdx.x;
    const int wv = tid >> 6, lane = tid & 63;
    const int wm = wv >> 1, wn = wv & 1;
    const int m0 = blockIdx.y * 64, n0 = blockIdx.x * 64;

    f32x4 acc[2][2] = {{{0.f,0.f,0.f,0.f},{0.f,0.f,0.f,0.f}},
                       {{0.f,0.f,0.f,0.f},{0.f,0.f,0.f,0.f}}};
    const int r_st = tid >> 2, k_st = (tid & 3) * 8;

    long arow = -1;
    {
        int gm = m0 + r_st;
        if (gm < M) arow = idxA ? (long)idxA[gm] : (long)gm;
    }

    const int kIters = (K + 31) / 32;
    for (int it = 0; it < kIters; ++it) {
        const int k0 = it * 32;
        const int kg = k0 + k_st;
        // stage A
        {
            s16x8 pk = {0,0,0,0,0,0,0,0};
            if (arow >= 0) {
                if constexpr (sizeof(AT) == 2) {
                    if (kg + 8 <= K) {
                        pk = *(const s16x8*)((const unsigned short*)A + arow * (long)ldA + kg);
                    } else {
#pragma unroll
                        for (int j = 0; j < 8; ++j)
                            if (kg + j < K) pk[j] = (short)((const unsigned short*)A)[arow * (long)ldA + kg + j];
                    }
                } else {
                    if (kg + 8 <= K) {
                        const float* p = (const float*)A + arow * (long)ldA + kg;
                        f32x4 u0 = *(const f32x4*)p;
                        f32x4 u1 = *(const f32x4*)(p + 4);
#pragma unroll
                        for (int j = 0; j < 4; ++j) { pk[j] = (short)f2b(u0[j]); pk[4+j] = (short)f2b(u1[j]); }
                    } else {
#pragma unroll
                        for (int j = 0; j < 8; ++j) {
                            int kk = kg + j;
                            if (kk < K) pk[j] = (short)f2b(((const float*)A)[arow * (long)ldA + kk]);
                        }
                    }
                }
            }
            *(s16x8*)&As[r_st][k_st] = pk;
        }
        // stage B
        {
            int gn = n0 + r_st;
            s16x8 pk = {0,0,0,0,0,0,0,0};
            if (gn < N) pk = *(const s16x8*)&Wb[(long)gn * Kpad + kg];
            *(s16x8*)&Bs[r_st][k_st] = pk;
        }
        __syncthreads();
        {
            const int koff = (lane >> 4) * 8;
            s16x8 af[2], bfr[2];
#pragma unroll
            for (int f = 0; f < 2; ++f) {
                af[f]  = *(s16x8*)&As[wm * 32 + f * 16 + (lane & 15)][koff];
                bfr[f] = *(s16x8*)&Bs[wn * 32 + f * 16 + (lane & 15)][koff];
            }
#pragma unroll
            for (int fi = 0; fi < 2; ++fi)
#pragma unroll
                for (int fj = 0; fj < 2; ++fj)
                    acc[fi][fj] = __builtin_amdgcn_mfma_f32_16x16x32_bf16(
                        af[fi], bfr[fj], acc[fi][fj], 0, 0, 0);
        }
        __syncthreads();
    }
#pragma unroll
    for (int fi = 0; fi < 2; ++fi)
#pragma unroll
        for (int fj = 0; fj < 2; ++fj)
#pragma unroll
            for (int r = 0; r < 4; ++r) {
                int m = m0 + wm * 32 + fi * 16 + (lane >> 4) * 4 + r;
                int n = n0 + wn * 32 + fj * 16 + (lane & 15);
                if (m < M && n < N) {
                    float v = acc[fi][fj][r];
                    if (bias) v += bias[n];
                    if (addC) v += addC[(long)m * ldAdd + n];
                    if constexpr (OB) ((unsigned short*)Cv)[(long)m * ldC + n] = f2b(v);
                    else               ((float*)Cv)[(long)m * ldC + n] = v;
                }
            }
}

// ---------------- fused GRU step (gemm h@Whh 3 gates + combine) ----------------
// grid (8,2): x over d (n0), y over b (m0)
__global__ __launch_bounds__(256)
void gru_step(const float* __restrict__ h_in, const unsigned short* __restrict__ Whh_b,
              const float* __restrict__ GI_t, const float* __restrict__ bhh,
              const int* __restrict__ toks, int t, int first,
              const unsigned short* __restrict__ o_prev,
              float* __restrict__ h_out, unsigned short* __restrict__ o_out)
{
    __shared__ unsigned short As[64][40];
    __shared__ unsigned short Bs[3][64][40];
    const int tid = threadIdx.x;
    const int wv = tid >> 6, lane = tid & 63;
    const int wm = wv >> 1, wn = wv & 1;
    const int m0 = blockIdx.y * 64, n0 = blockIdx.x * 64;
    const int r_st = tid >> 2, k_st = (tid & 3) * 8;

    f32x4 acc[3][2][2] = {};

    for (int it = 0; it < 16; ++it) {
        const int k0 = it * 32;
        {
            const float* p = h_in + (long)(m0 + r_st) * ND + k0 + k_st;
            f32x4 u0 = *(const f32x4*)p;
            f32x4 u1 = *(const f32x4*)(p + 4);
            s16x8 pk;
#pragma unroll
            for (int j = 0; j < 4; ++j) { pk[j] = (short)f2b(u0[j]); pk[4+j] = (short)f2b(u1[j]); }
            *(s16x8*)&As[r_st][k_st] = pk;
        }
#pragma unroll
        for (int g = 0; g < 3; ++g)
            *(s16x8*)&Bs[g][r_st][k_st] =
                *(const s16x8*)&Whh_b[((long)(g * ND + n0 + r_st)) * ND + k0 + k_st];
        __syncthreads();
        {
            const int koff = (lane >> 4) * 8;
            s16x8 af[2];
            af[0] = *(s16x8*)&As[wm * 32 + (lane & 15)][koff];
            af[1] = *(s16x8*)&As[wm * 32 + 16 + (lane & 15)][koff];
#pragma unroll
            for (int g = 0; g < 3; ++g) {
                s16x8 b0 = *(s16x8*)&Bs[g][wn * 32 + (lane & 15)][koff];
                s16x8 b1 = *(s16x8*)&Bs[g][wn * 32 + 16 + (lane & 15)][koff];
                acc[g][0][0] = __builtin_amdgcn_mfma_f32_16x16x32_bf16(af[0], b0, acc[g][0][0], 0,0,0);
                acc[g][0][1] = __builtin_amdgcn_mfma_f32_16x16x32_bf16(af[0], b1, acc[g][0][1], 0,0,0);
                acc[g][1][0] = __builtin_amdgcn_mfma_f32_16x16x32_bf16(af[1], b0, acc[g][1][0], 0,0,0);
                acc[g][1][1] = __builtin_amdgcn_mfma_f32_16x16x32_bf16(af[1], b1, acc[g][1][1], 0,0,0);
            }
        }
        __syncthreads();
    }
#pragma unroll
    for (int fi = 0; fi < 2; ++fi)
#pragma unroll
        for (int fj = 0; fj < 2; ++fj)
#pragma unroll
            for (int rr = 0; rr < 4; ++rr) {
                int b = m0 + wm * 32 + fi * 16 + (lane >> 4) * 4 + rr;
                int d = n0 + wn * 32 + fj * 16 + (lane & 15);
                const float* gib = GI_t + (long)b * G3;
                float ghr = acc[0][fi][fj][rr] + bhh[d];
                float ghz = acc[1][fi][fj][rr] + bhh[ND + d];
                float ghn = acc[2][fi][fj][rr] + bhh[2 * ND + d];
                float rg = fsigmoid(gib[d] + ghr);
                float zg = fsigmoid(gib[ND + d] + ghz);
                float ng = ftanh(gib[2 * ND + d] + rg * ghn);
                float hp = h_in[(long)b * ND + d];
                float hr = (1.0f - zg) * ng + zg * hp;
                bool m = toks[b * T_SZ + t] != 0;
                h_out[(long)b * ND + d] = m ? hr : hp;
                float ov = first ? hr : (m ? hr : b2f(o_prev[(long)b * ND + d]));
                o_out[(long)b * ND + d] = f2b(ov);
            }
}

// ---------------- fused match-GRU step ----------------
// acc: 0=r(sum), 1=z(sum), 2=gi_n (from a), 3=gh_n (from r)
// Wrz: (1024 x 1024) bf16: row j<512 gate r, j>=512 gate z; col k<512 from m_Wih_L, k>=512 from m_Whh.
__global__ __launch_bounds__(256)
void match_step(const float* __restrict__ abuf, const float* __restrict__ r_in,
                const unsigned short* __restrict__ Wrz,
                const unsigned short* __restrict__ Wgin,
                const unsigned short* __restrict__ Wghn,
                const float* __restrict__ OHGI_t, const float* __restrict__ mbhh,
                const int* __restrict__ hyp, int t, float* __restrict__ r_out)
{
    __shared__ unsigned short As[64][40];
    __shared__ unsigned short Bs[3][64][40];
    const int tid = threadIdx.x;
    const int wv = tid >> 6, lane = tid & 63;
    const int wm = wv >> 1, wn = wv & 1;
    const int m0 = blockIdx.y * 64, n0 = blockIdx.x * 64;
    const int r_st = tid >> 2, k_st = (tid & 3) * 8;

    f32x4 accR[2][2] = {}, accZ[2][2] = {}, accGN[2][2] = {}, accHN[2][2] = {};

    // phase 1: k in [0,512): A = abuf, third tile = Wgin -> accGN
    for (int it = 0; it < 16; ++it) {
        const int k0 = it * 32;
        {
            const float* p = abuf + (long)(m0 + r_st) * ND + k0 + k_st;
            f32x4 u0 = *(const f32x4*)p;
            f32x4 u1 = *(const f32x4*)(p + 4);
            s16x8 pk;
#pragma unroll
            for (int j = 0; j < 4; ++j) { pk[j] = (short)f2b(u0[j]); pk[4+j] = (short)f2b(u1[j]); }
            *(s16x8*)&As[r_st][k_st] = pk;
        }
        *(s16x8*)&Bs[0][r_st][k_st] = *(const s16x8*)&Wrz[(long)(n0 + r_st) * 1024 + k0 + k_st];
        *(s16x8*)&Bs[1][r_st][k_st] = *(const s16x8*)&Wrz[(long)(ND + n0 + r_st) * 1024 + k0 + k_st];
        *(s16x8*)&Bs[2][r_st][k_st] = *(const s16x8*)&Wgin[(long)(n0 + r_st) * ND + k0 + k_st];
        __syncthreads();
        {
            const int koff = (lane >> 4) * 8;
            s16x8 af[2];
            af[0] = *(s16x8*)&As[wm * 32 + (lane & 15)][koff];
            af[1] = *(s16x8*)&As[wm * 32 + 16 + (lane & 15)][koff];
#pragma unroll
            for (int f = 0; f < 2; ++f) {
                s16x8 b0 = *(s16x8*)&Bs[0][wn * 32 + f * 16 + (lane & 15)][koff];
                s16x8 b1 = *(s16x8*)&Bs[1][wn * 32 + f * 16 + (lane & 15)][koff];
                s16x8 b2 = *(s16x8*)&Bs[2][wn * 32 + f * 16 + (lane & 15)][koff];
                accR[0][f]  = __builtin_amdgcn_mfma_f32_16x16x32_bf16(af[0], b0, accR[0][f], 0,0,0);
                accR[1][f]  = __builtin_amdgcn_mfma_f32_16x16x32_bf16(af[1], b0, accR[1][f], 0,0,0);
                accZ[0][f]  = __builtin_amdgcn_mfma_f32_16x16x32_bf16(af[0], b1, accZ[0][f], 0,0,0);
                accZ[1][f]  = __builtin_amdgcn_mfma_f32_16x16x32_bf16(af[1], b1, accZ[1][f], 0,0,0);
                accGN[0][f] = __builtin_amdgcn_mfma_f32_16x16x32_bf16(af[0], b2, accGN[0][f], 0,0,0);
                accGN[1][f] = __builtin_amdgcn_mfma_f32_16x16x32_bf16(af[1], b2, accGN[1][f], 0,0,0);
            }
        }
        __syncthreads();
    }
    // phase 2: k in [512,1024): A = r_in, third tile = Wghn -> accHN
    for (int it = 0; it < 16; ++it) {
        const int k0 = it * 32;
        {
            const float* p = r_in + (long)(m0 + r_st) * ND + k0 + k_st;
            f32x4 u0 = *(const f32x4*)p;
            f32x4 u1 = *(const f32x4*)(p + 4);
            s16x8 pk;
#pragma unroll
            for (int j = 0; j < 4; ++j) { pk[j] = (short)f2b(u0[j]); pk[4+j] = (short)f2b(u1[j]); }
            *(s16x8*)&As[r_st][k_st] = pk;
        }
        *(s16x8*)&Bs[0][r_st][k_st] = *(const s16x8*)&Wrz[(long)(n0 + r_st) * 1024 + ND + k0 + k_st];
        *(s16x8*)&Bs[1][r_st][k_st] = *(const s16x8*)&Wrz[(long)(ND + n0 + r_st) * 1024 + ND + k0 + k_st];
        *(s16x8*)&Bs[2][r_st][k_st] = *(const s16x8*)&Wghn[(long)(n0 + r_st) * ND + k0 + k_st];
        __syncthreads();
        {
            const int koff = (lane >> 4) * 8;
            s16x8 af[2];
            af[0] = *(s16x8*)&As[wm * 32 + (lane & 15)][koff];
            af[1] = *(s16x8*)&As[wm * 32 + 16 + (lane & 15)][koff];
#pragma unroll
            for (int f = 0; f < 2; ++f) {
                s16x8 b0 = *(s16x8*)&Bs[0][wn * 32 + f * 16 + (lane & 15)][koff];
                s16x8 b1 = *(s16x8*)&Bs[1][wn * 32 + f * 16 + (lane & 15)][koff];
                s16x8 b2 = *(s16x8*)&Bs[2][wn * 32 + f * 16 + (lane & 15)][koff];
                accR[0][f]  = __builtin_amdgcn_mfma_f32_16x16x32_bf16(af[0], b0, accR[0][f], 0,0,0);
                accR[1][f]  = __builtin_amdgcn_mfma_f32_16x16x32_bf16(af[1], b0, accR[1][f], 0,0,0);
                accZ[0][f]  = __builtin_amdgcn_mfma_f32_16x16x32_bf16(af[0], b1, accZ[0][f], 0,0,0);
                accZ[1][f]  = __builtin_amdgcn_mfma_f32_16x16x32_bf16(af[1], b1, accZ[1][f], 0,0,0);
                accHN[0][f] = __builtin_amdgcn_mfma_f32_16x16x32_bf16(af[0], b2, accHN[0][f], 0,0,0);
                accHN[1][f] = __builtin_amdgcn_mfma_f32_16x16x32_bf16(af[1], b2, accHN[1][f], 0,0,0);
            }
        }
        __syncthreads();
    }
#pragma unroll
    for (int fi = 0; fi < 2; ++fi)
#pragma unroll
        for (int fj = 0; fj < 2; ++fj)
#pragma unroll
            for (int rr = 0; rr < 4; ++rr) {
                int b = m0 + wm * 32 + fi * 16 + (lane >> 4) * 4 + rr;
                int d = n0 + wn * 32 + fj * 16 + (lane & 15);
                const float* ogib = OHGI_t + (long)b * G3;
                float sr = accR[fi][fj][rr] + ogib[d] + mbhh[d];
                float sz = accZ[fi][fj][rr] + ogib[ND + d] + mbhh[ND + d];
                float gin = accGN[fi][fj][rr] + ogib[2 * ND + d];
                float ghn = accHN[fi][fj][rr] + mbhh[2 * ND + d];
                float rg = fsigmoid(sr);
                float zg = fsigmoid(sz);
                float ng = ftanh(gin + rg * ghn);
                float rp = r_in[(long)b * ND + d];
                float rnew = (1.0f - zg) * ng + zg * rp;
                bool m = hyp[b * T_SZ + t] != 0;
                r_out[(long)b * ND + d] = m ? rnew : rp;
            }
}

// ---------------- fused attention (logits + softmax + weighted sum) ----------------
__global__ __launch_bounds__(256)
void attn_fused(const float* __restrict__ sbuf, const unsigned short* __restrict__ Yw_b,
                const unsigned short* __restrict__ Y_b, const float* __restrict__ Walpha,
                const int* __restrict__ prem, float* __restrict__ abuf)
{
    __shared__ float logits[T_SZ];
    __shared__ float red[2];
    const int b = blockIdx.x;
    const int tid = threadIdx.x;
    const int wv = tid >> 6, lane = tid & 63;
    const int nb = lane * 8;
    float sv[8], wa[8];
#pragma unroll
    for (int j = 0; j < 8; ++j) { sv[j] = sbuf[b * ND + nb + j]; wa[j] = Walpha[nb + j]; }
    for (int i = 0; i < 32; ++i) {
        int tp = i * 4 + wv;
        s16x8 yw = *(const s16x8*)&Yw_b[((long)tp * B_SZ + b) * ND + nb];
        float acc = 0.0f;
#pragma unroll
        for (int j = 0; j < 8; ++j)
            acc += ftanh(b2f((unsigned short)yw[j]) + sv[j]) * wa[j];
#pragma unroll
        for (int off = 32; off; off >>= 1) acc += __shfl_xor(acc, off);
        if (lane == 0) {
            float mm = (prem[b * T_SZ + tp] != 0) ? 0.0f : 1000.0f;
            logits[tp] = acc - mm;
        }
    }
    __syncthreads();
    if (tid < 64) {
        float v = fmaxf(logits[tid], logits[tid + 64]);
#pragma unroll
        for (int off = 32; off; off >>= 1) v = fmaxf(v, __shfl_xor(v, off));
        if (tid == 0) red[0] = v;
    }
    __syncthreads();
    float mx = red[0];
    if (tid < T_SZ) logits[tid] = __expf(logits[tid] - mx);
    __syncthreads();
    if (tid < 64) {
        float v = logits[tid] + logits[tid + 64];
#pragma unroll
        for (int off = 32; off; off >>= 1) v += __shfl_xor(v, off);
        if (tid == 0) red[1] = v;
    }
    __syncthreads();
    float inv = 1.0f / red[1];
    float a0 = 0.0f, a1 = 0.0f;
    for (int tp = 0; tp < T_SZ; ++tp) {
        float al = logits[tp] * inv;
        unsigned u = *(const unsigned*)&Y_b[((long)tp * B_SZ + b) * ND + tid * 2];
        a0 += al * __uint_as_float(u << 16);
        a1 += al * __uint_as_float(u & 0xffff0000u);
    }
    abuf[b * ND + tid * 2]     = a0;
    abuf[b * ND + tid * 2 + 1] = a1;
}

// ---------------- prep / misc ----------------
__global__ void prep_idx(const int* __restrict__ prem, const int* __restrict__ hyp,
                         int* __restrict__ idx_p, int* __restrict__ idx_h)
{
    int i = blockIdx.x * blockDim.x + threadIdx.x;
    if (i < B_SZ * T_SZ) {
        int t = i / B_SZ, b = i % B_SZ;
        idx_p[i] = prem[b * T_SZ + t];
        idx_h[i] = hyp[b * T_SZ + t];
    }
}

__global__ void conv_w(const float* __restrict__ in, unsigned short* __restrict__ out,
                       int N, int K, int Kpad, int ldIn, int colOff)
{
    int i = blockIdx.x * blockDim.x + threadIdx.x;
    if (i >= N * Kpad) return;
    int n = i / Kpad, k = i % Kpad;
    float v = (k < K) ? in[(long)n * ldIn + k + colOff] : 0.0f;
    out[i] = f2b(v);
}

__global__ void conv_wT(const float* __restrict__ in, unsigned short* __restrict__ out,
                        int N, int K, int Kpad, int ldIn)
{
    int i = blockIdx.x * blockDim.x + threadIdx.x;
    if (i >= N * Kpad) return;
    int n = i / Kpad, k = i % Kpad;
    float v = (k < K) ? in[(long)k * ldIn + n] : 0.0f;
    out[i] = f2b(v);
}

__global__ void conv_wrz(const float* __restrict__ mWih, const float* __restrict__ mWhh,
                         unsigned short* __restrict__ out)
{
    int i = blockIdx.x * blockDim.x + threadIdx.x;
    if (i >= 1024 * 1024) return;
    int j = i >> 10, k = i & 1023;
    float v = (k < ND) ? mWih[(long)j * 1024 + k] : mWhh[(long)j * ND + (k - ND)];
    out[i] = f2b(v);
}

__global__ void zero_kernel(float* __restrict__ p, int n)
{
    int i = blockIdx.x * blockDim.x + threadIdx.x;
    if (i < n) p[i] = 0.0f;
}

__global__ void final_logits(const float* __restrict__ r, const float* __restrict__ outW,
                             const float* __restrict__ outb, float* __restrict__ out)
{
    int b = blockIdx.x;
    int lane = threadIdx.x;
    float a0 = 0.0f, a1 = 0.0f, a2 = 0.0f;
    for (int k = lane; k < ND; k += 64) {
        float rv = r[b * ND + k];
        a0 += rv * outW[0 * ND + k];
        a1 += rv * outW[1 * ND + k];
        a2 += rv * outW[2 * ND + k];
    }
#pragma unroll
    for (int off = 32; off; off >>= 1) {
        a0 += __shfl_down(a0, off);
        a1 += __shfl_down(a1, off);
        a2 += __shfl_down(a2, off);
    }
    if (lane == 0) {
        float l0 = a0 + outb[0], l1 = a1 + outb[1], l2 = a2 + outb[2];
        float mx = fmaxf(l0, fmaxf(l1, l2));
        float se = expf(l0 - mx) + expf(l1 - mx) + expf(l2 - mx);
        float ls = mx + logf(se);
        out[b * 3 + 0] = l0 - ls;
        out[b * 3 + 1] = l1 - ls;
        out[b * 3 + 2] = l2 - ls;
    }
}

// ---------------- host ----------------
extern "C" void kernel_launch(void* const* d_in, const int* in_sizes, int n_in,
                              void* d_out, int out_size, void* d_ws, size_t ws_size,
                              hipStream_t stream)
{
    const int*   prem    = (const int*)d_in[0];
    const int*   hyp     = (const int*)d_in[1];
    const float* E       = (const float*)d_in[2];
    const float* p_Wih   = (const float*)d_in[3];
    const float* p_Whh   = (const float*)d_in[4];
    const float* p_bih   = (const float*)d_in[5];
    const float* p_bhh   = (const float*)d_in[6];
    const float* h_Wih   = (const float*)d_in[7];
    const float* h_Whh   = (const float*)d_in[8];
    const float* h_bih   = (const float*)d_in[9];
    const float* h_bhh   = (const float*)d_in[10];
    const float* m_Wih   = (const float*)d_in[11];
    const float* m_Whh   = (const float*)d_in[12];
    const float* m_bih   = (const float*)d_in[13];
    const float* m_bhh   = (const float*)d_in[14];
    const float* W_y     = (const float*)d_in[15];
    const float* W_h     = (const float*)d_in[16];
    const float* W_r     = (const float*)d_in[17];
    const float* W_alpha = (const float*)d_in[18];
    const float* out_W   = (const float*)d_in[19];
    const float* out_b   = (const float*)d_in[20];
    float* out = (float*)d_out;

    const int MB = T_SZ * B_SZ;  // 16384

    float* ws = (float*)d_ws;
    size_t off = 0;
    float* GI    = ws + off; off += (size_t)MB * G3;       // premise GI / hyp GI / OH_GI (fp32)
    float* OHWh  = ws + off; off += (size_t)MB * ND;
    float* h_pp0 = ws + off; off += (size_t)B_SZ * ND;
    float* h_pp1 = ws + off; off += (size_t)B_SZ * ND;
    float* r_pp0 = ws + off; off += (size_t)B_SZ * ND;
    float* r_pp1 = ws + off; off += (size_t)B_SZ * ND;
    float* sbuf  = ws + off; off += (size_t)B_SZ * ND;
    float* abuf  = ws + off; off += (size_t)B_SZ * ND;
    int* idx_p = (int*)(ws + off); off += (size_t)B_SZ * T_SZ;
    int* idx_h = (int*)(ws + off); off += (size_t)B_SZ * T_SZ;
    // bf16 buffers
    unsigned short* ub = (unsigned short*)(ws + off);
    size_t uoff = 0;
    unsigned short* o_p_b  = ub + uoff; uoff += (size_t)MB * ND;   // Y (bf16)
    unsigned short* o_h_b  = ub + uoff; uoff += (size_t)MB * ND;
    unsigned short* Yw_b   = ub + uoff; uoff += (size_t)MB * ND;
    unsigned short* pWih_b = ub + uoff; uoff += (size_t)G3 * 320;
    unsigned short* hWih_b = ub + uoff; uoff += (size_t)G3 * 320;
    unsigned short* pWhh_b = ub + uoff; uoff += (size_t)G3 * ND;
    unsigned short* hWhh_b = ub + uoff; uoff += (size_t)G3 * ND;
    unsigned short* mWihR  = ub + uoff; uoff += (size_t)G3 * ND;
    unsigned short* WyT_b  = ub + uoff; uoff += (size_t)ND * ND;
    unsigned short* WhT_b  = ub + uoff; uoff += (size_t)ND * ND;
    unsigned short* WrT_b  = ub + uoff; uoff += (size_t)ND * ND;
    unsigned short* Wrz    = ub + uoff; uoff += (size_t)1024 * 1024;
    unsigned short* Wgin   = ub + uoff; uoff += (size_t)ND * ND;
    unsigned short* Wghn   = ub + uoff; uoff += (size_t)ND * ND;
    off += (uoff + 1) / 2;
    if (ws_size < off * sizeof(float)) return;

    auto cblk = [](long n) { return (int)((n + 255) / 256); };

    // ---- prep ----
    prep_idx<<<cblk(MB), 256, 0, stream>>>(prem, hyp, idx_p, idx_h);
    conv_w <<<cblk((long)G3 * 320), 256, 0, stream>>>(p_Wih, pWih_b, G3, EMBD, 320, EMBD, 0);
    conv_w <<<cblk((long)G3 * 320), 256, 0, stream>>>(h_Wih, hWih_b, G3, EMBD, 320, EMBD, 0);
    conv_w <<<cblk((long)G3 * ND), 256, 0, stream>>>(p_Whh, pWhh_b, G3, ND, ND, ND, 0);
    conv_w <<<cblk((long)G3 * ND), 256, 0, stream>>>(h_Whh, hWhh_b, G3, ND, ND, ND, 0);
    conv_w <<<cblk((long)G3 * ND), 256, 0, stream>>>(m_Wih, mWihR, G3, ND, ND, 2 * ND, ND);
    conv_w <<<cblk((long)ND * ND), 256, 0, stream>>>(m_Wih + (size_t)1024 * 1024, Wgin, ND, ND, ND, 2 * ND, 0);
    conv_w <<<cblk((long)ND * ND), 256, 0, stream>>>(m_Whh + (size_t)1024 * ND, Wghn, ND, ND, ND, ND, 0);
    conv_wT<<<cblk((long)ND * ND), 256, 0, stream>>>(W_y, WyT_b, ND, ND, ND, ND);
    conv_wT<<<cblk((long)ND * ND), 256, 0, stream>>>(W_h, WhT_b, ND, ND, ND, ND);
    conv_wT<<<cblk((long)ND * ND), 256, 0, stream>>>(W_r, WrT_b, ND, ND, ND, ND);
    conv_wrz<<<cblk(1024L * 1024), 256, 0, stream>>>(m_Wih, m_Whh, Wrz);
    zero_kernel<<<cblk(B_SZ * ND), 256, 0, stream>>>(h_pp0, B_SZ * ND);
    zero_kernel<<<cblk(B_SZ * ND), 256, 0, stream>>>(r_pp0, B_SZ * ND);

    float* h_pp[2] = { h_pp0, h_pp1 };
    float* r_pp[2] = { r_pp0, r_pp1 };

    // ---- premise GI + GRU ----
    {
        dim3 g(G3 / 64, MB / 64);
        mfma_gemm<float, false><<<g, 256, 0, stream>>>(E, idx_p, pWih_b, p_bih, nullptr, GI,
                                                       MB, G3, EMBD, EMBD, 320, G3, 0);
    }
    for (int t = 0; t < T_SZ; ++t) {
        const unsigned short* oprev = (t == 0) ? o_p_b : o_p_b + (size_t)(t - 1) * B_SZ * ND;
        gru_step<<<dim3(8, 2), 256, 0, stream>>>(h_pp[t & 1], pWhh_b, GI + (size_t)t * B_SZ * G3,
                                                 p_bhh, prem, t, t == 0 ? 1 : 0, oprev,
                                                 h_pp[(t + 1) & 1], o_p_b + (size_t)t * B_SZ * ND);
    }

    // ---- hypothesis GI + GRU (h continues in h_pp[0]) ----
    {
        dim3 g(G3 / 64, MB / 64);
        mfma_gemm<float, false><<<g, 256, 0, stream>>>(E, idx_h, hWih_b, h_bih, nullptr, GI,
                                                       MB, G3, EMBD, EMBD, 320, G3, 0);
    }
    for (int t = 0; t < T_SZ; ++t) {
        const unsigned short* oprev = (t == 0) ? o_h_b : o_h_b + (size_t)(t - 1) * B_SZ * ND;
        gru_step<<<dim3(8, 2), 256, 0, stream>>>(h_pp[t & 1], hWhh_b, GI + (size_t)t * B_SZ * G3,
                                                 h_bhh, hyp, t, t == 0 ? 1 : 0, oprev,
                                                 h_pp[(t + 1) & 1], o_h_b + (size_t)t * B_SZ * ND);
    }

    // ---- attention precompute ----
    {
        dim3 g(ND / 64, MB / 64);
        mfma_gemm<unsigned short, true><<<g, 256, 0, stream>>>(o_p_b, nullptr, WyT_b, nullptr, nullptr,
                                                               Yw_b, MB, ND, ND, ND, ND, ND, 0);
        mfma_gemm<unsigned short, false><<<g, 256, 0, stream>>>(o_h_b, nullptr, WhT_b, nullptr, nullptr,
                                                                OHWh, MB, ND, ND, ND, ND, ND, 0);
        dim3 g2(G3 / 64, MB / 64);
        mfma_gemm<unsigned short, false><<<g2, 256, 0, stream>>>(o_h_b, nullptr, mWihR, m_bih, nullptr,
                                                                 GI, MB, G3, ND, ND, ND, G3, 0);
    }

    // ---- match loop ----
    for (int t = 0; t < T_SZ; ++t) {
        dim3 g(ND / 64, B_SZ / 64);
        mfma_gemm<float, false><<<g, 256, 0, stream>>>(r_pp[t & 1], nullptr, WrT_b, nullptr,
                                                       OHWh + (size_t)t * B_SZ * ND, sbuf,
                                                       B_SZ, ND, ND, ND, ND, ND, ND);
        attn_fused<<<B_SZ, 256, 0, stream>>>(sbuf, Yw_b, o_p_b, W_alpha, prem, abuf);
        match_step<<<dim3(8, 2), 256, 0, stream>>>(abuf, r_pp[t & 1], Wrz, Wgin, Wghn,
                                                   GI + (size_t)t * B_SZ * G3, m_bhh, hyp, t,
                                                   r_pp[(t + 1) & 1]);
    }

    final_logits<<<B_SZ, 64, 0, stream>>>(r_pp[0], out_W, out_b, out);
}

// Round 4
// 15085.684 us; speedup vs baseline: 1.1178x; 1.1178x over previous
//
#include <hip/hip_runtime.h>
#include <math.h>

#define B_SZ 128
#define T_SZ 128
#define EMBD 300
#define ND 512
#define G3 1536

typedef short s16x8 __attribute__((ext_vector_type(8)));
typedef float f32x4 __attribute__((ext_vector_type(4)));

__device__ __forceinline__ unsigned short f2b(float x) {
    unsigned u = __float_as_uint(x);
    unsigned r = (u + 0x7fff + ((u >> 16) & 1)) >> 16;  // RNE
    return (unsigned short)r;
}
__device__ __forceinline__ float b2f(unsigned short v) {
    return __uint_as_float(((unsigned)v) << 16);
}
__device__ __forceinline__ float fsigmoid(float x) { return 1.0f / (1.0f + __expf(-x)); }
__device__ __forceinline__ float ftanh(float x) { return 1.0f - 2.0f / (__expf(2.0f * x) + 1.0f); }

__device__ __forceinline__ f32x4 mfma16(s16x8 a, s16x8 b, f32x4 c) {
    return __builtin_amdgcn_mfma_f32_16x16x32_bf16(a, b, c, 0, 0, 0);
}

// ---- device-scope grid barrier (monotonic epoch, counter zeroed per launch) ----
__device__ __forceinline__ void gbar(unsigned* cnt, unsigned& target, int nb)
{
    __syncthreads();
    if (threadIdx.x == 0) {
        __threadfence();  // release: make our writes visible device-wide
        atomicAdd(cnt, 1u);
        target += (unsigned)nb;
        while (__hip_atomic_load(cnt, __ATOMIC_ACQUIRE, __HIP_MEMORY_SCOPE_AGENT) < target)
            __builtin_amdgcn_s_sleep(2);
        __threadfence();  // acquire: invalidate caches so fresh data is read
    }
    __syncthreads();
}

// ---------------- generic MFMA GEMM (precompute only) ----------------
// C[M,N] = gather(A,idxA) @ Wb^T (+bias) (+addC). Wb bf16 (N x Kpad).
// permC: output row m remapped to (m&127)*T_SZ + (m>>7)  ([t][b] -> [b][t])
template<typename AT, bool OB>
__global__ __launch_bounds__(256)
void mfma_gemm(const AT* __restrict__ A, const int* __restrict__ idxA,
               const unsigned short* __restrict__ Wb, const float* __restrict__ bias,
               const float* __restrict__ addC, void* __restrict__ Cv,
               int M, int N, int K, int ldA, int Kpad, int ldC, int ldAdd, int permC)
{
    __shared__ unsigned short As[64][40];
    __shared__ unsigned short Bs[64][40];
    const int tid = threadIdx.x;
    const int wv = tid >> 6, lane = tid & 63;
    const int wm = wv >> 1, wn = wv & 1;
    const int m0 = blockIdx.y * 64, n0 = blockIdx.x * 64;

    f32x4 acc[2][2] = {{{0.f,0.f,0.f,0.f},{0.f,0.f,0.f,0.f}},
                       {{0.f,0.f,0.f,0.f},{0.f,0.f,0.f,0.f}}};
    const int r_st = tid >> 2, k_st = (tid & 3) * 8;

    long arow = -1;
    {
        int gm = m0 + r_st;
        if (gm < M) arow = idxA ? (long)idxA[gm] : (long)gm;
    }

    const int kIters = (K + 31) / 32;
    for (int it = 0; it < kIters; ++it) {
        const int kg = it * 32 + k_st;
        {
            s16x8 pk = {0,0,0,0,0,0,0,0};
            if (arow >= 0) {
                if constexpr (sizeof(AT) == 2) {
                    if (kg + 8 <= K) {
                        pk = *(const s16x8*)((const unsigned short*)A + arow * (long)ldA + kg);
                    } else {
#pragma unroll
                        for (int j = 0; j < 8; ++j)
                            if (kg + j < K) pk[j] = (short)((const unsigned short*)A)[arow * (long)ldA + kg + j];
                    }
                } else {
                    if (kg + 8 <= K) {
                        const float* p = (const float*)A + arow * (long)ldA + kg;
                        f32x4 u0 = *(const f32x4*)p;
                        f32x4 u1 = *(const f32x4*)(p + 4);
#pragma unroll
                        for (int j = 0; j < 4; ++j) { pk[j] = (short)f2b(u0[j]); pk[4+j] = (short)f2b(u1[j]); }
                    } else {
#pragma unroll
                        for (int j = 0; j < 8; ++j) {
                            int kk = kg + j;
                            if (kk < K) pk[j] = (short)f2b(((const float*)A)[arow * (long)ldA + kk]);
                        }
                    }
                }
            }
            *(s16x8*)&As[r_st][k_st] = pk;
        }
        {
            int gn = n0 + r_st;
            s16x8 pk = {0,0,0,0,0,0,0,0};
            if (gn < N) pk = *(const s16x8*)&Wb[(long)gn * Kpad + kg];
            *(s16x8*)&Bs[r_st][k_st] = pk;
        }
        __syncthreads();
        {
            const int koff = (lane >> 4) * 8;
            s16x8 af[2], bfr[2];
#pragma unroll
            for (int f = 0; f < 2; ++f) {
                af[f]  = *(s16x8*)&As[wm * 32 + f * 16 + (lane & 15)][koff];
                bfr[f] = *(s16x8*)&Bs[wn * 32 + f * 16 + (lane & 15)][koff];
            }
#pragma unroll
            for (int fi = 0; fi < 2; ++fi)
#pragma unroll
                for (int fj = 0; fj < 2; ++fj)
                    acc[fi][fj] = mfma16(af[fi], bfr[fj], acc[fi][fj]);
        }
        __syncthreads();
    }
#pragma unroll
    for (int fi = 0; fi < 2; ++fi)
#pragma unroll
        for (int fj = 0; fj < 2; ++fj)
#pragma unroll
            for (int r = 0; r < 4; ++r) {
                int m = m0 + wm * 32 + fi * 16 + (lane >> 4) * 4 + r;
                int n = n0 + wn * 32 + fj * 16 + (lane & 15);
                if (m < M && n < N) {
                    float v = acc[fi][fj][r];
                    if (bias) v += bias[n];
                    if (addC) v += addC[(long)m * ldAdd + n];
                    long mo = permC ? ((long)(m & 127) * T_SZ + (m >> 7)) : (long)m;
                    if constexpr (OB) ((unsigned short*)Cv)[mo * ldC + n] = f2b(v);
                    else               ((float*)Cv)[mo * ldC + n] = v;
                }
            }
}

// ---------------- persistent GRU chain (128 steps, 1 launch) ----------------
// 64 blocks = 32 d-tiles x 2 b-halves. Whh resident in LDS. 1 grid barrier/step.
#define GRU_NB 64
__global__ __launch_bounds__(256, 1)
void gru_chain(const unsigned short* __restrict__ Whh_b, const float* __restrict__ GI,
               const float* __restrict__ bhh, const int* __restrict__ toks,
               float* __restrict__ h32a, float* __restrict__ h32b,
               unsigned short* __restrict__ h16a, unsigned short* __restrict__ h16b,
               unsigned short* __restrict__ o_tb, unsigned short* __restrict__ o_bt,
               unsigned* __restrict__ barcnt)
{
    __shared__ unsigned short wlds[3][16][512];   // 48 KB: frag-layout weights
    __shared__ unsigned short hs[2][64][40];      // 10 KB: staging dbuf
    const int tid = threadIdx.x;
    const int wv = tid >> 6, lane = tid & 63;
    const int dt = blockIdx.x & 31, bh = blockIdx.x >> 5;
    const int b0 = bh * 64;

    // load weights once (frag layout: [gate][kslice][lane*8])
    for (int s = 0; s < 12; ++s) {
        int slot = tid + s * 256;           // 3*16*64 = 3072
        int g = slot >> 10, rem = slot & 1023, ks = rem >> 6, ln = rem & 63;
        int row = g * ND + dt * 16 + (ln & 15);
        int k = ks * 32 + (ln >> 4) * 8;
        *(s16x8*)&wlds[g][ks][ln * 8] = *(const s16x8*)&Whh_b[(long)row * ND + k];
    }
    __syncthreads();

    const int st_r = tid >> 2, st_k = (tid & 3) * 8;
    const int d = dt * 16 + (lane & 15);
    const int brow = b0 + wv * 16 + (lane >> 4) * 4;

    float o_run[4] = {0.f, 0.f, 0.f, 0.f};
    unsigned target = 0;

    for (int t = 0; t < T_SZ; ++t) {
        const unsigned short* hin16 = (t & 1) ? h16b : h16a;
        const float*          hin32 = (t & 1) ? h32b : h32a;
        float*          hout32 = (t & 1) ? h32a : h32b;
        unsigned short* hout16 = (t & 1) ? h16a : h16b;

        f32x4 acc0 = {0,0,0,0}, acc1 = {0,0,0,0}, acc2 = {0,0,0,0};
        *(s16x8*)&hs[0][st_r][st_k] = *(const s16x8*)&hin16[(long)(b0 + st_r) * ND + st_k];
        for (int ks = 0; ks < 16; ++ks) {
            __syncthreads();
            if (ks < 15)
                *(s16x8*)&hs[(ks + 1) & 1][st_r][st_k] =
                    *(const s16x8*)&hin16[(long)(b0 + st_r) * ND + (ks + 1) * 32 + st_k];
            s16x8 a  = *(s16x8*)&hs[ks & 1][wv * 16 + (lane & 15)][(lane >> 4) * 8];
            s16x8 br = *(s16x8*)&wlds[0][ks][lane * 8];
            s16x8 bz = *(s16x8*)&wlds[1][ks][lane * 8];
            s16x8 bn = *(s16x8*)&wlds[2][ks][lane * 8];
            acc0 = mfma16(a, br, acc0);
            acc1 = mfma16(a, bz, acc1);
            acc2 = mfma16(a, bn, acc2);
        }

        const float* git = GI + (long)t * (B_SZ * G3);
#pragma unroll
        for (int rr = 0; rr < 4; ++rr) {
            int b = brow + rr;
            float gi_r = git[(long)b * G3 + d];
            float gi_z = git[(long)b * G3 + ND + d];
            float gi_n = git[(long)b * G3 + 2 * ND + d];
            float ghr = acc0[rr] + bhh[d];
            float ghz = acc1[rr] + bhh[ND + d];
            float ghn = acc2[rr] + bhh[2 * ND + d];
            float rg = fsigmoid(gi_r + ghr);
            float zg = fsigmoid(gi_z + ghz);
            float ng = ftanh(gi_n + rg * ghn);
            float hp = hin32[(long)b * ND + d];
            float hr = (1.0f - zg) * ng + zg * hp;
            bool mk = toks[b * T_SZ + t] != 0;
            float hn = mk ? hr : hp;
            hout32[(long)b * ND + d] = hn;
            hout16[(long)b * ND + d] = f2b(hn);
            o_run[rr] = (t == 0) ? hr : (mk ? hr : o_run[rr]);
            o_tb[((long)t * B_SZ + b) * ND + d] = f2b(o_run[rr]);
            if (o_bt) o_bt[((long)b * T_SZ + t) * ND + d] = f2b(o_run[rr]);
        }
        gbar(barcnt, target, GRU_NB);
    }
}

// ---------------- persistent match chain (128 steps, 1 launch) ----------------
// 128 blocks. Phases per step: 1) s=r@WrT^T+OHWh (blocks<64)  2) attn (1 b/block)
// 3a) gbuf=[a|r]@Wbig^T (16 cols/block)  3b) GRU combine. 4 barriers/step.
#define MAT_NB 128
__global__ __launch_bounds__(256, 1)
void match_chain(const unsigned short* __restrict__ WrT_b,
                 const unsigned short* __restrict__ Wbig,
                 const float* __restrict__ OHWh, const float* __restrict__ OHGI,
                 const float* __restrict__ m_bhh, const float* __restrict__ Walpha,
                 const unsigned short* __restrict__ Yw_bb,
                 const unsigned short* __restrict__ Y_bb,
                 const int* __restrict__ prem, const int* __restrict__ hyp,
                 float* __restrict__ r32, unsigned short* __restrict__ r16,
                 float* __restrict__ sbuf, float* __restrict__ gbuf,
                 unsigned short* __restrict__ a16,
                 unsigned* __restrict__ barcnt)
{
    __shared__ unsigned short w1[16][512];    // 16 KB (blocks < 64)
    __shared__ unsigned short w3[32][512];    // 32 KB (all blocks)
    __shared__ unsigned short stg[128][40];   // 10 KB staging
    __shared__ float lg[T_SZ];
    __shared__ float red[2];
    const int tid = threadIdx.x;
    const int wv = tid >> 6, lane = tid & 63;
    const int blk = blockIdx.x;
    const int st_r = tid >> 2, st_k = (tid & 3) * 8;

    if (blk < 64) {
        int nt = blk & 31;
        for (int s = 0; s < 4; ++s) {
            int slot = tid + s * 256;      // 16*64 = 1024
            int ks = slot >> 6, ln = slot & 63;
            *(s16x8*)&w1[ks][ln * 8] =
                *(const s16x8*)&WrT_b[(long)(nt * 16 + (ln & 15)) * ND + ks * 32 + (ln >> 4) * 8];
        }
    }
    for (int s = 0; s < 8; ++s) {
        int slot = tid + s * 256;          // 32*64 = 2048
        int ks = slot >> 6, ln = slot & 63;
        *(s16x8*)&w3[ks][ln * 8] =
            *(const s16x8*)&Wbig[(long)(blk * 16 + (ln & 15)) * 1024 + ks * 32 + (ln >> 4) * 8];
    }
    __syncthreads();

    unsigned target = 0;

    for (int t = 0; t < T_SZ; ++t) {
        // ---- phase 1 ----
        if (blk < 64) {
            int nt = blk & 31, bh = blk >> 5, b0 = bh * 64;
            f32x4 acc = {0,0,0,0};
            s16x8 pre = *(const s16x8*)&r16[(long)(b0 + st_r) * ND + st_k];
            for (int ks = 0; ks < 16; ++ks) {
                __syncthreads();
                *(s16x8*)&stg[st_r][st_k] = pre;
                __syncthreads();
                if (ks < 15)
                    pre = *(const s16x8*)&r16[(long)(b0 + st_r) * ND + (ks + 1) * 32 + st_k];
                s16x8 a  = *(s16x8*)&stg[wv * 16 + (lane & 15)][(lane >> 4) * 8];
                s16x8 bw = *(s16x8*)&w1[ks][lane * 8];
                acc = mfma16(a, bw, acc);
            }
            int n = nt * 16 + (lane & 15);
            int brow = b0 + wv * 16 + (lane >> 4) * 4;
#pragma unroll
            for (int rr = 0; rr < 4; ++rr) {
                int b = brow + rr;
                sbuf[(long)b * ND + n] = acc[rr] + OHWh[((long)t * B_SZ + b) * ND + n];
            }
        }
        gbar(barcnt, target, MAT_NB);

        // ---- phase 2: attention for b = blk ----
        {
            const int b = blk;
            float sv[8], wa[8];
#pragma unroll
            for (int j = 0; j < 8; ++j) {
                sv[j] = sbuf[(long)b * ND + lane * 8 + j];
                wa[j] = Walpha[lane * 8 + j];
            }
            for (int i = 0; i < 32; ++i) {
                int tp = i * 4 + wv;
                s16x8 yw = *(const s16x8*)&Yw_bb[((long)b * T_SZ + tp) * ND + lane * 8];
                float acc = 0.0f;
#pragma unroll
                for (int j = 0; j < 8; ++j)
                    acc += ftanh(b2f((unsigned short)yw[j]) + sv[j]) * wa[j];
#pragma unroll
                for (int off = 32; off; off >>= 1) acc += __shfl_xor(acc, off);
                if (lane == 0) {
                    float mm = (prem[b * T_SZ + tp] != 0) ? 0.0f : 1000.0f;
                    lg[tp] = acc - mm;
                }
            }
            __syncthreads();
            if (tid < 64) {
                float v = fmaxf(lg[tid], lg[tid + 64]);
#pragma unroll
                for (int off = 32; off; off >>= 1) v = fmaxf(v, __shfl_xor(v, off));
                if (tid == 0) red[0] = v;
            }
            __syncthreads();
            float mx = red[0];
            if (tid < T_SZ) lg[tid] = __expf(lg[tid] - mx);
            __syncthreads();
            if (tid < 64) {
                float v = lg[tid] + lg[tid + 64];
#pragma unroll
                for (int off = 32; off; off >>= 1) v += __shfl_xor(v, off);
                if (tid == 0) red[1] = v;
            }
            __syncthreads();
            float inv = 1.0f / red[1];
            int n2 = tid * 2;
            float a0 = 0.0f, a1 = 0.0f;
            for (int tp = 0; tp < T_SZ; ++tp) {
                float al = lg[tp] * inv;
                unsigned u = *(const unsigned*)&Y_bb[((long)b * T_SZ + tp) * ND + n2];
                a0 += al * __uint_as_float(u << 16);
                a1 += al * __uint_as_float(u & 0xffff0000u);
            }
            a16[(long)b * ND + n2]     = f2b(a0);
            a16[(long)b * ND + n2 + 1] = f2b(a1);
        }
        gbar(barcnt, target, MAT_NB);

        // ---- phase 3a: gbuf = [a|r] @ Wbig^T, 16 cols/block, M=128 ----
        {
            f32x4 accA = {0,0,0,0}, accB = {0,0,0,0};
            s16x8 preA = *(const s16x8*)&a16[(long)st_r * ND + st_k];
            s16x8 preB = *(const s16x8*)&a16[(long)(64 + st_r) * ND + st_k];
            for (int ks = 0; ks < 32; ++ks) {
                __syncthreads();
                *(s16x8*)&stg[st_r][st_k] = preA;
                *(s16x8*)&stg[64 + st_r][st_k] = preB;
                __syncthreads();
                if (ks < 31) {
                    const unsigned short* src = (ks + 1 < 16) ? a16 : r16;
                    int kk = ((ks + 1) & 15) * 32 + st_k;
                    preA = *(const s16x8*)&src[(long)st_r * ND + kk];
                    preB = *(const s16x8*)&src[(long)(64 + st_r) * ND + kk];
                }
                s16x8 a0f = *(s16x8*)&stg[wv * 16 + (lane & 15)][(lane >> 4) * 8];
                s16x8 a1f = *(s16x8*)&stg[64 + wv * 16 + (lane & 15)][(lane >> 4) * 8];
                s16x8 bw  = *(s16x8*)&w3[ks][lane * 8];
                accA = mfma16(a0f, bw, accA);
                accB = mfma16(a1f, bw, accB);
            }
            int col = blk * 16 + (lane & 15);
#pragma unroll
            for (int rr = 0; rr < 4; ++rr) {
                int b = wv * 16 + (lane >> 4) * 4 + rr;
                gbuf[(long)b * 2048 + col] = accA[rr];
                gbuf[(long)(b + 64) * 2048 + col] = accB[rr];
            }
        }
        gbar(barcnt, target, MAT_NB);

        // ---- phase 3b: combine ----
        {
#pragma unroll
            for (int e = 0; e < 2; ++e) {
                int i = blk * 512 + e * 256 + tid;
                int b = i >> 9, dd = i & 511;
                const float* og = OHGI + ((long)t * B_SZ + b) * G3;
                float sr  = gbuf[(long)b * 2048 + dd]         + og[dd]          + m_bhh[dd];
                float sz  = gbuf[(long)b * 2048 + 512 + dd]   + og[512 + dd]    + m_bhh[512 + dd];
                float gin = gbuf[(long)b * 2048 + 1024 + dd]  + og[1024 + dd];
                float ghn = gbuf[(long)b * 2048 + 1536 + dd]  + m_bhh[1024 + dd];
                float rg = fsigmoid(sr), zg = fsigmoid(sz);
                float ng = ftanh(gin + rg * ghn);
                float rp = r32[(long)b * ND + dd];
                float rn = (1.0f - zg) * ng + zg * rp;
                bool mk = hyp[b * T_SZ + t] != 0;
                float v = mk ? rn : rp;
                r32[(long)b * ND + dd] = v;
                r16[(long)b * ND + dd] = f2b(v);
            }
        }
        gbar(barcnt, target, MAT_NB);
    }
}

// ---------------- prep / misc ----------------
__global__ void prep_idx(const int* __restrict__ prem, const int* __restrict__ hyp,
                         int* __restrict__ idx_p, int* __restrict__ idx_h)
{
    int i = blockIdx.x * blockDim.x + threadIdx.x;
    if (i < B_SZ * T_SZ) {
        int t = i / B_SZ, b = i % B_SZ;
        idx_p[i] = prem[b * T_SZ + t];
        idx_h[i] = hyp[b * T_SZ + t];
    }
}

__global__ void conv_w(const float* __restrict__ in, unsigned short* __restrict__ out,
                       int N, int K, int Kpad, int ldIn, int colOff)
{
    long i = (long)blockIdx.x * blockDim.x + threadIdx.x;
    if (i >= (long)N * Kpad) return;
    int n = (int)(i / Kpad), k = (int)(i % Kpad);
    float v = (k < K) ? in[(long)n * ldIn + k + colOff] : 0.0f;
    out[i] = f2b(v);
}

__global__ void conv_wT(const float* __restrict__ in, unsigned short* __restrict__ out,
                        int N, int K, int Kpad, int ldIn)
{
    long i = (long)blockIdx.x * blockDim.x + threadIdx.x;
    if (i >= (long)N * Kpad) return;
    int n = (int)(i / Kpad), k = (int)(i % Kpad);
    float v = (k < K) ? in[(long)k * ldIn + n] : 0.0f;
    out[i] = f2b(v);
}

// Wbig (2048 x 1024): fam0 SR=[WihL_r|Whh_r], fam1 SZ, fam2 GIN=[WihL_n|0], fam3 GHN=[0|Whh_n]
__global__ void conv_wbig(const float* __restrict__ mWih, const float* __restrict__ mWhh,
                          unsigned short* __restrict__ out)
{
    long i = (long)blockIdx.x * blockDim.x + threadIdx.x;
    if (i >= 2048L * 1024) return;
    int j = (int)(i >> 10), k = (int)(i & 1023);
    int fam = j >> 9, d = j & 511;
    float v = 0.0f;
    if (fam == 0)      v = (k < 512) ? mWih[(long)d * 1024 + k]          : mWhh[(long)d * 512 + (k - 512)];
    else if (fam == 1) v = (k < 512) ? mWih[(long)(512 + d) * 1024 + k]  : mWhh[(long)(512 + d) * 512 + (k - 512)];
    else if (fam == 2) v = (k < 512) ? mWih[(long)(1024 + d) * 1024 + k] : 0.0f;
    else               v = (k < 512) ? 0.0f : mWhh[(long)(1024 + d) * 512 + (k - 512)];
    out[i] = f2b(v);
}

__global__ void zero_kernel(float* __restrict__ p, int n)
{
    int i = blockIdx.x * blockDim.x + threadIdx.x;
    if (i < n) p[i] = 0.0f;
}

__global__ void final_logits(const float* __restrict__ r, const float* __restrict__ outW,
                             const float* __restrict__ outb, float* __restrict__ out)
{
    int b = blockIdx.x;
    int lane = threadIdx.x;
    float a0 = 0.0f, a1 = 0.0f, a2 = 0.0f;
    for (int k = lane; k < ND; k += 64) {
        float rv = r[(long)b * ND + k];
        a0 += rv * outW[0 * ND + k];
        a1 += rv * outW[1 * ND + k];
        a2 += rv * outW[2 * ND + k];
    }
#pragma unroll
    for (int off = 32; off; off >>= 1) {
        a0 += __shfl_down(a0, off);
        a1 += __shfl_down(a1, off);
        a2 += __shfl_down(a2, off);
    }
    if (lane == 0) {
        float l0 = a0 + outb[0], l1 = a1 + outb[1], l2 = a2 + outb[2];
        float mx = fmaxf(l0, fmaxf(l1, l2));
        float se = expf(l0 - mx) + expf(l1 - mx) + expf(l2 - mx);
        float ls = mx + logf(se);
        out[b * 3 + 0] = l0 - ls;
        out[b * 3 + 1] = l1 - ls;
        out[b * 3 + 2] = l2 - ls;
    }
}

// ---------------- host ----------------
extern "C" void kernel_launch(void* const* d_in, const int* in_sizes, int n_in,
                              void* d_out, int out_size, void* d_ws, size_t ws_size,
                              hipStream_t stream)
{
    const int*   prem    = (const int*)d_in[0];
    const int*   hyp     = (const int*)d_in[1];
    const float* E       = (const float*)d_in[2];
    const float* p_Wih   = (const float*)d_in[3];
    const float* p_Whh   = (const float*)d_in[4];
    const float* p_bih   = (const float*)d_in[5];
    const float* p_bhh   = (const float*)d_in[6];
    const float* h_Wih   = (const float*)d_in[7];
    const float* h_Whh   = (const float*)d_in[8];
    const float* h_bih   = (const float*)d_in[9];
    const float* h_bhh   = (const float*)d_in[10];
    const float* m_Wih   = (const float*)d_in[11];
    const float* m_Whh   = (const float*)d_in[12];
    const float* m_bih   = (const float*)d_in[13];
    const float* m_bhh   = (const float*)d_in[14];
    const float* W_y     = (const float*)d_in[15];
    const float* W_h     = (const float*)d_in[16];
    const float* W_r     = (const float*)d_in[17];
    const float* W_alpha = (const float*)d_in[18];
    const float* out_W   = (const float*)d_in[19];
    const float* out_b   = (const float*)d_in[20];
    float* out = (float*)d_out;

    const int MB = T_SZ * B_SZ;  // 16384

    float* ws = (float*)d_ws;
    size_t off = 0;
    float* GI    = ws + off; off += (size_t)MB * G3;       // GI_p / GI_h / OHGI
    float* OHWh  = ws + off; off += (size_t)MB * ND;
    float* h32a  = ws + off; off += (size_t)B_SZ * ND;
    float* h32b  = ws + off; off += (size_t)B_SZ * ND;
    float* r32   = ws + off; off += (size_t)B_SZ * ND;
    float* sbuf  = ws + off; off += (size_t)B_SZ * ND;
    float* gbuf  = ws + off; off += (size_t)B_SZ * 2048;
    unsigned* bc = (unsigned*)(ws + off); off += 64;
    int* idx_p = (int*)(ws + off); off += (size_t)B_SZ * T_SZ;
    int* idx_h = (int*)(ws + off); off += (size_t)B_SZ * T_SZ;
    unsigned short* ub = (unsigned short*)(ws + off);
    size_t uoff = 0;
    unsigned short* o_p_tb = ub + uoff; uoff += (size_t)MB * ND;
    unsigned short* o_p_bt = ub + uoff; uoff += (size_t)MB * ND;   // Y_bb
    unsigned short* o_h_tb = ub + uoff; uoff += (size_t)MB * ND;
    unsigned short* Yw_bb  = ub + uoff; uoff += (size_t)MB * ND;
    unsigned short* h16a   = ub + uoff; uoff += (size_t)B_SZ * ND;
    unsigned short* h16b   = ub + uoff; uoff += (size_t)B_SZ * ND;
    unsigned short* r16    = ub + uoff; uoff += (size_t)B_SZ * ND;
    unsigned short* a16    = ub + uoff; uoff += (size_t)B_SZ * ND;
    unsigned short* pWih_b = ub + uoff; uoff += (size_t)G3 * 320;
    unsigned short* hWih_b = ub + uoff; uoff += (size_t)G3 * 320;
    unsigned short* pWhh_b = ub + uoff; uoff += (size_t)G3 * ND;
    unsigned short* hWhh_b = ub + uoff; uoff += (size_t)G3 * ND;
    unsigned short* mWihR  = ub + uoff; uoff += (size_t)G3 * ND;
    unsigned short* WyT_b  = ub + uoff; uoff += (size_t)ND * ND;
    unsigned short* WhT_b  = ub + uoff; uoff += (size_t)ND * ND;
    unsigned short* WrT_b  = ub + uoff; uoff += (size_t)ND * ND;
    unsigned short* Wbig   = ub + uoff; uoff += (size_t)2048 * 1024;
    off += (uoff + 1) / 2;
    if (ws_size < off * sizeof(float)) return;

    auto cblk = [](long n) { return (int)((n + 255) / 256); };

    // ---- prep ----
    prep_idx<<<cblk(MB), 256, 0, stream>>>(prem, hyp, idx_p, idx_h);
    conv_w <<<cblk((long)G3 * 320), 256, 0, stream>>>(p_Wih, pWih_b, G3, EMBD, 320, EMBD, 0);
    conv_w <<<cblk((long)G3 * 320), 256, 0, stream>>>(h_Wih, hWih_b, G3, EMBD, 320, EMBD, 0);
    conv_w <<<cblk((long)G3 * ND), 256, 0, stream>>>(p_Whh, pWhh_b, G3, ND, ND, ND, 0);
    conv_w <<<cblk((long)G3 * ND), 256, 0, stream>>>(h_Whh, hWhh_b, G3, ND, ND, ND, 0);
    conv_w <<<cblk((long)G3 * ND), 256, 0, stream>>>(m_Wih, mWihR, G3, ND, ND, 2 * ND, ND);
    conv_wT<<<cblk((long)ND * ND), 256, 0, stream>>>(W_y, WyT_b, ND, ND, ND, ND);
    conv_wT<<<cblk((long)ND * ND), 256, 0, stream>>>(W_h, WhT_b, ND, ND, ND, ND);
    conv_wT<<<cblk((long)ND * ND), 256, 0, stream>>>(W_r, WrT_b, ND, ND, ND, ND);
    conv_wbig<<<cblk(2048L * 1024), 256, 0, stream>>>(m_Wih, m_Whh, Wbig);
    zero_kernel<<<cblk(B_SZ * ND), 256, 0, stream>>>(h32a, B_SZ * ND);
    zero_kernel<<<cblk(B_SZ * ND / 2), 256, 0, stream>>>((float*)h16a, B_SZ * ND / 2);
    zero_kernel<<<cblk(B_SZ * ND), 256, 0, stream>>>(r32, B_SZ * ND);
    zero_kernel<<<cblk(B_SZ * ND / 2), 256, 0, stream>>>((float*)r16, B_SZ * ND / 2);
    zero_kernel<<<1, 64, 0, stream>>>((float*)bc, 64);

    // ---- premise ----
    {
        dim3 g(G3 / 64, MB / 64);
        mfma_gemm<float, false><<<g, 256, 0, stream>>>(E, idx_p, pWih_b, p_bih, nullptr, GI,
                                                       MB, G3, EMBD, EMBD, 320, G3, 0, 0);
    }
    gru_chain<<<GRU_NB, 256, 0, stream>>>(pWhh_b, GI, p_bhh, prem, h32a, h32b, h16a, h16b,
                                          o_p_tb, o_p_bt, &bc[0]);

    // ---- hypothesis ----
    {
        dim3 g(G3 / 64, MB / 64);
        mfma_gemm<float, false><<<g, 256, 0, stream>>>(E, idx_h, hWih_b, h_bih, nullptr, GI,
                                                       MB, G3, EMBD, EMBD, 320, G3, 0, 0);
    }
    gru_chain<<<GRU_NB, 256, 0, stream>>>(hWhh_b, GI, h_bhh, hyp, h32a, h32b, h16a, h16b,
                                          o_h_tb, nullptr, &bc[8]);

    // ---- attention precompute ----
    {
        dim3 g(ND / 64, MB / 64);
        mfma_gemm<unsigned short, true><<<g, 256, 0, stream>>>(o_p_tb, nullptr, WyT_b, nullptr, nullptr,
                                                               Yw_bb, MB, ND, ND, ND, ND, ND, 0, 1);
        mfma_gemm<unsigned short, false><<<g, 256, 0, stream>>>(o_h_tb, nullptr, WhT_b, nullptr, nullptr,
                                                                OHWh, MB, ND, ND, ND, ND, ND, 0, 0);
        dim3 g2(G3 / 64, MB / 64);
        mfma_gemm<unsigned short, false><<<g2, 256, 0, stream>>>(o_h_tb, nullptr, mWihR, m_bih, nullptr,
                                                                 GI, MB, G3, ND, ND, ND, G3, 0, 0);
    }

    // ---- match chain ----
    match_chain<<<MAT_NB, 256, 0, stream>>>(WrT_b, Wbig, OHWh, GI, m_bhh, W_alpha,
                                            Yw_bb, o_p_bt, prem, hyp, r32, r16,
                                            sbuf, gbuf, a16, &bc[16]);

    final_logits<<<B_SZ, 64, 0, stream>>>(r32, out_W, out_b, out);
}

// Round 5
// 14236.839 us; speedup vs baseline: 1.1844x; 1.0596x over previous
//
#include <hip/hip_runtime.h>
#include <math.h>

#define B_SZ 128
#define T_SZ 128
#define EMBD 300
#define ND 512
#define G3 1536

typedef short s16x8 __attribute__((ext_vector_type(8)));
typedef float f32x4 __attribute__((ext_vector_type(4)));

__device__ __forceinline__ unsigned short f2b(float x) {
    unsigned u = __float_as_uint(x);
    unsigned r = (u + 0x7fff + ((u >> 16) & 1)) >> 16;  // RNE
    return (unsigned short)r;
}
__device__ __forceinline__ float b2f(unsigned short v) {
    return __uint_as_float(((unsigned)v) << 16);
}
__device__ __forceinline__ float fsigmoid(float x) { return 1.0f / (1.0f + __expf(-x)); }
__device__ __forceinline__ float ftanh(float x) { return 1.0f - 2.0f / (__expf(2.0f * x) + 1.0f); }

__device__ __forceinline__ f32x4 mfma16(s16x8 a, s16x8 b, f32x4 c) {
    return __builtin_amdgcn_mfma_f32_16x16x32_bf16(a, b, c, 0, 0, 0);
}

// ---- flag-array grid barrier: store-release arrival, parallel poll, monotone epoch ----
__device__ __forceinline__ void fbar(unsigned* flags, int nb, unsigned ep)
{
    __syncthreads();
    if (threadIdx.x == 0)
        __hip_atomic_store(&flags[blockIdx.x], ep, __ATOMIC_RELEASE, __HIP_MEMORY_SCOPE_AGENT);
    if (threadIdx.x < 64) {
        for (int f = threadIdx.x; f < nb; f += 64) {
            while (__hip_atomic_load(&flags[f], __ATOMIC_ACQUIRE, __HIP_MEMORY_SCOPE_AGENT) < ep)
                __builtin_amdgcn_s_sleep(1);
        }
    }
    __syncthreads();
}

// ---------------- generic MFMA GEMM (precompute only) ----------------
template<typename AT, bool OB>
__global__ __launch_bounds__(256)
void mfma_gemm(const AT* __restrict__ A, const int* __restrict__ idxA,
               const unsigned short* __restrict__ Wb, const float* __restrict__ bias,
               const float* __restrict__ addC, void* __restrict__ Cv,
               int M, int N, int K, int ldA, int Kpad, int ldC, int ldAdd, int permC)
{
    __shared__ unsigned short As[64][40];
    __shared__ unsigned short Bs[64][40];
    const int tid = threadIdx.x;
    const int wv = tid >> 6, lane = tid & 63;
    const int wm = wv >> 1, wn = wv & 1;
    const int m0 = blockIdx.y * 64, n0 = blockIdx.x * 64;

    f32x4 acc[2][2] = {{{0.f,0.f,0.f,0.f},{0.f,0.f,0.f,0.f}},
                       {{0.f,0.f,0.f,0.f},{0.f,0.f,0.f,0.f}}};
    const int r_st = tid >> 2, k_st = (tid & 3) * 8;

    long arow = -1;
    {
        int gm = m0 + r_st;
        if (gm < M) arow = idxA ? (long)idxA[gm] : (long)gm;
    }

    const int kIters = (K + 31) / 32;
    for (int it = 0; it < kIters; ++it) {
        const int kg = it * 32 + k_st;
        {
            s16x8 pk = {0,0,0,0,0,0,0,0};
            if (arow >= 0) {
                if constexpr (sizeof(AT) == 2) {
                    if (kg + 8 <= K) {
                        pk = *(const s16x8*)((const unsigned short*)A + arow * (long)ldA + kg);
                    } else {
#pragma unroll
                        for (int j = 0; j < 8; ++j)
                            if (kg + j < K) pk[j] = (short)((const unsigned short*)A)[arow * (long)ldA + kg + j];
                    }
                } else {
                    if (kg + 8 <= K) {
                        const float* p = (const float*)A + arow * (long)ldA + kg;
                        f32x4 u0 = *(const f32x4*)p;
                        f32x4 u1 = *(const f32x4*)(p + 4);
#pragma unroll
                        for (int j = 0; j < 4; ++j) { pk[j] = (short)f2b(u0[j]); pk[4+j] = (short)f2b(u1[j]); }
                    } else {
#pragma unroll
                        for (int j = 0; j < 8; ++j) {
                            int kk = kg + j;
                            if (kk < K) pk[j] = (short)f2b(((const float*)A)[arow * (long)ldA + kk]);
                        }
                    }
                }
            }
            *(s16x8*)&As[r_st][k_st] = pk;
        }
        {
            int gn = n0 + r_st;
            s16x8 pk = {0,0,0,0,0,0,0,0};
            if (gn < N) pk = *(const s16x8*)&Wb[(long)gn * Kpad + kg];
            *(s16x8*)&Bs[r_st][k_st] = pk;
        }
        __syncthreads();
        {
            const int koff = (lane >> 4) * 8;
            s16x8 af[2], bfr[2];
#pragma unroll
            for (int f = 0; f < 2; ++f) {
                af[f]  = *(s16x8*)&As[wm * 32 + f * 16 + (lane & 15)][koff];
                bfr[f] = *(s16x8*)&Bs[wn * 32 + f * 16 + (lane & 15)][koff];
            }
#pragma unroll
            for (int fi = 0; fi < 2; ++fi)
#pragma unroll
                for (int fj = 0; fj < 2; ++fj)
                    acc[fi][fj] = mfma16(af[fi], bfr[fj], acc[fi][fj]);
        }
        __syncthreads();
    }
#pragma unroll
    for (int fi = 0; fi < 2; ++fi)
#pragma unroll
        for (int fj = 0; fj < 2; ++fj)
#pragma unroll
            for (int r = 0; r < 4; ++r) {
                int m = m0 + wm * 32 + fi * 16 + (lane >> 4) * 4 + r;
                int n = n0 + wn * 32 + fj * 16 + (lane & 15);
                if (m < M && n < N) {
                    float v = acc[fi][fj][r];
                    if (bias) v += bias[n];
                    if (addC) v += addC[(long)m * ldAdd + n];
                    long mo = permC ? ((long)(m & 127) * T_SZ + (m >> 7)) : (long)m;
                    if constexpr (OB) ((unsigned short*)Cv)[mo * ldC + n] = f2b(v);
                    else               ((float*)Cv)[mo * ldC + n] = v;
                }
            }
}

// ---------------- persistent GRU chain ----------------
// 64 blocks = 32 d-tiles x 2 b-halves. Whh + full h-panel in LDS. 1 barrier/step.
#define GRU_NB 64
__global__ __launch_bounds__(256, 1)
void gru_chain(const unsigned short* __restrict__ Whh_b, const float* __restrict__ GI,
               const float* __restrict__ bhh, const int* __restrict__ toks,
               float* __restrict__ h32a, float* __restrict__ h32b,
               unsigned short* __restrict__ h16a, unsigned short* __restrict__ h16b,
               unsigned short* __restrict__ o_tb, unsigned short* __restrict__ o_bt,
               unsigned* __restrict__ flags)
{
    __shared__ unsigned short wlds[3][16][512];   // 48 KB
    __shared__ unsigned short hs[64][520];        // 66.6 KB, pitch 520 (2-way max)
    const int tid = threadIdx.x;
    const int wv = tid >> 6, lane = tid & 63;
    const int dt = blockIdx.x & 31, bh = blockIdx.x >> 5;
    const int b0 = bh * 64;

    for (int s = 0; s < 12; ++s) {
        int slot = tid + s * 256;
        int g = slot >> 10, rem = slot & 1023, ks = rem >> 6, ln = rem & 63;
        int row = g * ND + dt * 16 + (ln & 15);
        int k = ks * 32 + (ln >> 4) * 8;
        *(s16x8*)&wlds[g][ks][ln * 8] = *(const s16x8*)&Whh_b[(long)row * ND + k];
    }

    const int d = dt * 16 + (lane & 15);
    const int brow = b0 + wv * 16 + (lane >> 4) * 4;

    float o_run[4] = {0.f, 0.f, 0.f, 0.f};
    unsigned ep = 0;
    __syncthreads();

    for (int t = 0; t < T_SZ; ++t) {
        const unsigned short* hin16 = (t & 1) ? h16b : h16a;
        const float*          hin32 = (t & 1) ? h32b : h32a;
        float*          hout32 = (t & 1) ? h32a : h32b;
        unsigned short* hout16 = (t & 1) ? h16a : h16b;

        // stage full h-panel (64 x 512) in one burst
        {
            s16x8 g[16];
#pragma unroll
            for (int cs = 0; cs < 16; ++cs) {
                int c = cs * 256 + tid;
                g[cs] = *(const s16x8*)&hin16[(long)(b0 + (c >> 6)) * ND + (c & 63) * 8];
            }
#pragma unroll
            for (int cs = 0; cs < 16; ++cs) {
                int c = cs * 256 + tid;
                *(s16x8*)&hs[c >> 6][(c & 63) * 8] = g[cs];
            }
        }
        // prefetch epilogue operands (independent of MFMA)
        const float* git = GI + (long)t * (B_SZ * G3);
        float gi_r[4], gi_z[4], gi_n[4], hp[4]; int mk[4];
#pragma unroll
        for (int rr = 0; rr < 4; ++rr) {
            int b = brow + rr;
            gi_r[rr] = git[(long)b * G3 + d];
            gi_z[rr] = git[(long)b * G3 + ND + d];
            gi_n[rr] = git[(long)b * G3 + 2 * ND + d];
            hp[rr]   = hin32[(long)b * ND + d];
            mk[rr]   = toks[b * T_SZ + t];
        }
        __syncthreads();

        f32x4 acc0 = {0,0,0,0}, acc1 = {0,0,0,0}, acc2 = {0,0,0,0};
#pragma unroll
        for (int ks = 0; ks < 16; ++ks) {
            s16x8 a  = *(s16x8*)&hs[wv * 16 + (lane & 15)][ks * 32 + (lane >> 4) * 8];
            s16x8 br = *(s16x8*)&wlds[0][ks][lane * 8];
            s16x8 bz = *(s16x8*)&wlds[1][ks][lane * 8];
            s16x8 bn = *(s16x8*)&wlds[2][ks][lane * 8];
            acc0 = mfma16(a, br, acc0);
            acc1 = mfma16(a, bz, acc1);
            acc2 = mfma16(a, bn, acc2);
        }

#pragma unroll
        for (int rr = 0; rr < 4; ++rr) {
            int b = brow + rr;
            float rg = fsigmoid(gi_r[rr] + acc0[rr] + bhh[d]);
            float zg = fsigmoid(gi_z[rr] + acc1[rr] + bhh[ND + d]);
            float ng = ftanh(gi_n[rr] + rg * (acc2[rr] + bhh[2 * ND + d]));
            float hr = (1.0f - zg) * ng + zg * hp[rr];
            bool m = mk[rr] != 0;
            float hn = m ? hr : hp[rr];
            hout32[(long)b * ND + d] = hn;
            hout16[(long)b * ND + d] = f2b(hn);
            o_run[rr] = (t == 0) ? hr : (m ? hr : o_run[rr]);
            o_tb[((long)t * B_SZ + b) * ND + d] = f2b(o_run[rr]);
            if (o_bt) o_bt[((long)b * T_SZ + t) * ND + d] = f2b(o_run[rr]);
        }
        fbar(flags, GRU_NB, ++ep);
    }
}

// ---------------- persistent match chain ----------------
// 128 blocks, 3 barriers/step.
// P1: s = r@WrT^T + OHWh[t]   (b-quarter x 16-col tile per block)
// P2: attention for b = blk
// P3: 16 fam-interleaved Wbig rows per block -> gates + combine (LDS bounce)
#define MAT_NB 128
__global__ __launch_bounds__(256, 1)
void match_chain(const unsigned short* __restrict__ WrT_b,
                 const unsigned short* __restrict__ Wbig,
                 const float* __restrict__ OHWh, const float* __restrict__ OHGI,
                 const float* __restrict__ m_bhh, const float* __restrict__ Walpha,
                 const unsigned short* __restrict__ Yw_bb,
                 const unsigned short* __restrict__ Y_bb,
                 const int* __restrict__ prem, const int* __restrict__ hyp,
                 float* __restrict__ r32, unsigned short* __restrict__ r16,
                 float* __restrict__ sbuf, unsigned short* __restrict__ a16,
                 unsigned* __restrict__ flags)
{
    __shared__ unsigned short w1[16][512];     // 16 KB
    __shared__ unsigned short w3[32][512];     // 32 KB
    __shared__ unsigned short buf[64][520];    // 66.6 KB staging
    __shared__ float bounce[128][17];          // 8.7 KB
    __shared__ float lg[T_SZ];
    __shared__ float red[2];
    const int tid = threadIdx.x;
    const int wv = tid >> 6, lane = tid & 63;
    const int blk = blockIdx.x;
    const int nt = blk & 31, bq = blk >> 5;

    for (int s = 0; s < 4; ++s) {
        int slot = tid + s * 256;
        int ks = slot >> 6, ln = slot & 63;
        *(s16x8*)&w1[ks][ln * 8] =
            *(const s16x8*)&WrT_b[(long)(nt * 16 + (ln & 15)) * ND + ks * 32 + (ln >> 4) * 8];
    }
    for (int s = 0; s < 8; ++s) {
        int slot = tid + s * 256;
        int ks = slot >> 6, ln = slot & 63;
        *(s16x8*)&w3[ks][ln * 8] =
            *(const s16x8*)&Wbig[(long)(blk * 16 + (ln & 15)) * 1024 + ks * 32 + (ln >> 4) * 8];
    }
    __syncthreads();

    auto stage64 = [&](const unsigned short* src, int rowoff) {
        s16x8 g[16];
#pragma unroll
        for (int cs = 0; cs < 16; ++cs) {
            int c = cs * 256 + tid;
            g[cs] = *(const s16x8*)&src[(long)(rowoff + (c >> 6)) * ND + (c & 63) * 8];
        }
#pragma unroll
        for (int cs = 0; cs < 16; ++cs) {
            int c = cs * 256 + tid;
            *(s16x8*)&buf[c >> 6][(c & 63) * 8] = g[cs];
        }
    };
    auto mq = [&](f32x4 acc, int ksb) -> f32x4 {
#pragma unroll
        for (int ks = 0; ks < 16; ++ks) {
            s16x8 a  = *(s16x8*)&buf[wv * 16 + (lane & 15)][ks * 32 + (lane >> 4) * 8];
            s16x8 bw = *(s16x8*)&w3[ksb + ks][lane * 8];
            acc = mfma16(a, bw, acc);
        }
        return acc;
    };

    unsigned ep = 0;

    for (int t = 0; t < T_SZ; ++t) {
        // ---- P1: s = r @ WrT^T + OHWh[t], M=32 (b-quarter), N=16 ----
        {
            int b0 = bq * 32;
            s16x8 g[8];
#pragma unroll
            for (int cs = 0; cs < 8; ++cs) {
                int c = cs * 256 + tid;
                g[cs] = *(const s16x8*)&r16[(long)(b0 + (c >> 6)) * ND + (c & 63) * 8];
            }
#pragma unroll
            for (int cs = 0; cs < 8; ++cs) {
                int c = cs * 256 + tid;
                *(s16x8*)&buf[c >> 6][(c & 63) * 8] = g[cs];
            }
            __syncthreads();
            if (wv < 2) {
                f32x4 acc = {0,0,0,0};
#pragma unroll
                for (int ks = 0; ks < 16; ++ks) {
                    s16x8 a  = *(s16x8*)&buf[wv * 16 + (lane & 15)][ks * 32 + (lane >> 4) * 8];
                    s16x8 bw = *(s16x8*)&w1[ks][lane * 8];
                    acc = mfma16(a, bw, acc);
                }
                int n = nt * 16 + (lane & 15);
                int brow = b0 + wv * 16 + (lane >> 4) * 4;
#pragma unroll
                for (int rr = 0; rr < 4; ++rr) {
                    int b = brow + rr;
                    sbuf[(long)b * ND + n] = acc[rr] + OHWh[((long)t * B_SZ + b) * ND + n];
                }
            }
        }
        fbar(flags, MAT_NB, ++ep);

        // ---- P2: attention for b = blk ----
        {
            const int b = blk;
            float sv[8], wa[8];
#pragma unroll
            for (int j = 0; j < 8; ++j) {
                sv[j] = sbuf[(long)b * ND + lane * 8 + j];
                wa[j] = Walpha[lane * 8 + j];
            }
            for (int i = 0; i < 32; ++i) {
                int tp = i * 4 + wv;
                s16x8 yw = *(const s16x8*)&Yw_bb[((long)b * T_SZ + tp) * ND + lane * 8];
                float acc = 0.0f;
#pragma unroll
                for (int j = 0; j < 8; ++j)
                    acc += ftanh(b2f((unsigned short)yw[j]) + sv[j]) * wa[j];
#pragma unroll
                for (int off = 32; off; off >>= 1) acc += __shfl_xor(acc, off);
                if (lane == 0) {
                    float mm = (prem[b * T_SZ + tp] != 0) ? 0.0f : 1000.0f;
                    lg[tp] = acc - mm;
                }
            }
            __syncthreads();
            if (tid < 64) {
                float v = fmaxf(lg[tid], lg[tid + 64]);
#pragma unroll
                for (int off = 32; off; off >>= 1) v = fmaxf(v, __shfl_xor(v, off));
                if (tid == 0) red[0] = v;
            }
            __syncthreads();
            float mx = red[0];
            if (tid < T_SZ) lg[tid] = __expf(lg[tid] - mx);
            __syncthreads();
            if (tid < 64) {
                float v = lg[tid] + lg[tid + 64];
#pragma unroll
                for (int off = 32; off; off >>= 1) v += __shfl_xor(v, off);
                if (tid == 0) red[1] = v;
            }
            __syncthreads();
            float inv = 1.0f / red[1];
            int n2 = tid * 2;
            float a0 = 0.0f, a1 = 0.0f;
            for (int tp = 0; tp < T_SZ; ++tp) {
                float al = lg[tp] * inv;
                unsigned u = *(const unsigned*)&Y_bb[((long)b * T_SZ + tp) * ND + n2];
                a0 += al * __uint_as_float(u << 16);
                a1 += al * __uint_as_float(u & 0xffff0000u);
            }
            a16[(long)b * ND + n2]     = f2b(a0);
            a16[(long)b * ND + n2 + 1] = f2b(a1);
        }
        fbar(flags, MAT_NB, ++ep);

        // ---- P3: gates (16 fam-interleaved cols) + combine ----
        {
            f32x4 accA = {0,0,0,0}, accB = {0,0,0,0};
            stage64(a16, 0);   __syncthreads(); accA = mq(accA, 0);  __syncthreads();
            stage64(a16, 64);  __syncthreads(); accB = mq(accB, 0);  __syncthreads();
            stage64(r16, 0);   __syncthreads(); accA = mq(accA, 16); __syncthreads();
            stage64(r16, 64);  __syncthreads(); accB = mq(accB, 16); __syncthreads();

#pragma unroll
            for (int rr = 0; rr < 4; ++rr) {
                bounce[wv * 16 + (lane >> 4) * 4 + rr][lane & 15] = accA[rr];
                bounce[64 + wv * 16 + (lane >> 4) * 4 + rr][lane & 15] = accB[rr];
            }
            __syncthreads();
#pragma unroll
            for (int e = 0; e < 2; ++e) {
                int i = e * 256 + tid;           // 0..511
                int b = i >> 2, dl = i & 3;
                int dd = blk * 4 + dl;
                const float* og = OHGI + ((long)t * B_SZ + b) * G3;
                float sr  = bounce[b][0 + dl]  + og[dd]          + m_bhh[dd];
                float sz  = bounce[b][4 + dl]  + og[ND + dd]     + m_bhh[ND + dd];
                float gin = bounce[b][8 + dl]  + og[2 * ND + dd];
                float ghn = bounce[b][12 + dl] + m_bhh[2 * ND + dd];
                float rg = fsigmoid(sr), zg = fsigmoid(sz);
                float ng = ftanh(gin + rg * ghn);
                float rp = r32[(long)b * ND + dd];
                float rn = (1.0f - zg) * ng + zg * rp;
                bool mkk = hyp[b * T_SZ + t] != 0;
                float v = mkk ? rn : rp;
                r32[(long)b * ND + dd] = v;
                r16[(long)b * ND + dd] = f2b(v);
            }
        }
        fbar(flags, MAT_NB, ++ep);
    }
}

// ---------------- prep / misc ----------------
__global__ void prep_idx(const int* __restrict__ prem, const int* __restrict__ hyp,
                         int* __restrict__ idx_p, int* __restrict__ idx_h)
{
    int i = blockIdx.x * blockDim.x + threadIdx.x;
    if (i < B_SZ * T_SZ) {
        int t = i / B_SZ, b = i % B_SZ;
        idx_p[i] = prem[b * T_SZ + t];
        idx_h[i] = hyp[b * T_SZ + t];
    }
}

__global__ void conv_w(const float* __restrict__ in, unsigned short* __restrict__ out,
                       int N, int K, int Kpad, int ldIn, int colOff)
{
    long i = (long)blockIdx.x * blockDim.x + threadIdx.x;
    if (i >= (long)N * Kpad) return;
    int n = (int)(i / Kpad), k = (int)(i % Kpad);
    float v = (k < K) ? in[(long)n * ldIn + k + colOff] : 0.0f;
    out[i] = f2b(v);
}

__global__ void conv_wT(const float* __restrict__ in, unsigned short* __restrict__ out,
                        int N, int K, int Kpad, int ldIn)
{
    long i = (long)blockIdx.x * blockDim.x + threadIdx.x;
    if (i >= (long)N * Kpad) return;
    int n = (int)(i / Kpad), k = (int)(i % Kpad);
    float v = (k < K) ? in[(long)k * ldIn + n] : 0.0f;
    out[i] = f2b(v);
}

// Wbig (2048 x 1024), rows fam-interleaved per block:
// row j = blk*16 + fam*4 + dl  represents (fam, d = blk*4+dl)
// fam0 SR=[WihL_r|Whh_r], fam1 SZ, fam2 GIN=[WihL_n|0], fam3 GHN=[0|Whh_n]
__global__ void conv_wbig(const float* __restrict__ mWih, const float* __restrict__ mWhh,
                          unsigned short* __restrict__ out)
{
    long i = (long)blockIdx.x * blockDim.x + threadIdx.x;
    if (i >= 2048L * 1024) return;
    int j = (int)(i >> 10), k = (int)(i & 1023);
    int blk = j >> 4, within = j & 15, fam = within >> 2, dl = within & 3;
    int d = blk * 4 + dl;
    float v = 0.0f;
    if (fam == 0)      v = (k < 512) ? mWih[(long)d * 1024 + k]          : mWhh[(long)d * 512 + (k - 512)];
    else if (fam == 1) v = (k < 512) ? mWih[(long)(512 + d) * 1024 + k]  : mWhh[(long)(512 + d) * 512 + (k - 512)];
    else if (fam == 2) v = (k < 512) ? mWih[(long)(1024 + d) * 1024 + k] : 0.0f;
    else               v = (k < 512) ? 0.0f : mWhh[(long)(1024 + d) * 512 + (k - 512)];
    out[i] = f2b(v);
}

__global__ void zero_kernel(float* __restrict__ p, int n)
{
    int i = blockIdx.x * blockDim.x + threadIdx.x;
    if (i < n) p[i] = 0.0f;
}

__global__ void final_logits(const float* __restrict__ r, const float* __restrict__ outW,
                             const float* __restrict__ outb, float* __restrict__ out)
{
    int b = blockIdx.x;
    int lane = threadIdx.x;
    float a0 = 0.0f, a1 = 0.0f, a2 = 0.0f;
    for (int k = lane; k < ND; k += 64) {
        float rv = r[(long)b * ND + k];
        a0 += rv * outW[0 * ND + k];
        a1 += rv * outW[1 * ND + k];
        a2 += rv * outW[2 * ND + k];
    }
#pragma unroll
    for (int off = 32; off; off >>= 1) {
        a0 += __shfl_down(a0, off);
        a1 += __shfl_down(a1, off);
        a2 += __shfl_down(a2, off);
    }
    if (lane == 0) {
        float l0 = a0 + outb[0], l1 = a1 + outb[1], l2 = a2 + outb[2];
        float mx = fmaxf(l0, fmaxf(l1, l2));
        float se = expf(l0 - mx) + expf(l1 - mx) + expf(l2 - mx);
        float ls = mx + logf(se);
        out[b * 3 + 0] = l0 - ls;
        out[b * 3 + 1] = l1 - ls;
        out[b * 3 + 2] = l2 - ls;
    }
}

// ---------------- host ----------------
extern "C" void kernel_launch(void* const* d_in, const int* in_sizes, int n_in,
                              void* d_out, int out_size, void* d_ws, size_t ws_size,
                              hipStream_t stream)
{
    const int*   prem    = (const int*)d_in[0];
    const int*   hyp     = (const int*)d_in[1];
    const float* E       = (const float*)d_in[2];
    const float* p_Wih   = (const float*)d_in[3];
    const float* p_Whh   = (const float*)d_in[4];
    const float* p_bih   = (const float*)d_in[5];
    const float* p_bhh   = (const float*)d_in[6];
    const float* h_Wih   = (const float*)d_in[7];
    const float* h_Whh   = (const float*)d_in[8];
    const float* h_bih   = (const float*)d_in[9];
    const float* h_bhh   = (const float*)d_in[10];
    const float* m_Wih   = (const float*)d_in[11];
    const float* m_Whh   = (const float*)d_in[12];
    const float* m_bih   = (const float*)d_in[13];
    const float* m_bhh   = (const float*)d_in[14];
    const float* W_y     = (const float*)d_in[15];
    const float* W_h     = (const float*)d_in[16];
    const float* W_r     = (const float*)d_in[17];
    const float* W_alpha = (const float*)d_in[18];
    const float* out_W   = (const float*)d_in[19];
    const float* out_b   = (const float*)d_in[20];
    float* out = (float*)d_out;

    const int MB = T_SZ * B_SZ;  // 16384

    float* ws = (float*)d_ws;
    size_t off = 0;
    float* GI    = ws + off; off += (size_t)MB * G3;       // GI_p / GI_h / OHGI
    float* OHWh  = ws + off; off += (size_t)MB * ND;
    float* h32a  = ws + off; off += (size_t)B_SZ * ND;
    float* h32b  = ws + off; off += (size_t)B_SZ * ND;
    float* r32   = ws + off; off += (size_t)B_SZ * ND;
    float* sbuf  = ws + off; off += (size_t)B_SZ * ND;
    unsigned* flags = (unsigned*)(ws + off); off += 256;   // [0:64) gru_p, [64:128) gru_h, [128:256) match
    int* idx_p = (int*)(ws + off); off += (size_t)B_SZ * T_SZ;
    int* idx_h = (int*)(ws + off); off += (size_t)B_SZ * T_SZ;
    unsigned short* ub = (unsigned short*)(ws + off);
    size_t uoff = 0;
    unsigned short* o_p_tb = ub + uoff; uoff += (size_t)MB * ND;
    unsigned short* o_p_bt = ub + uoff; uoff += (size_t)MB * ND;   // Y_bb
    unsigned short* o_h_tb = ub + uoff; uoff += (size_t)MB * ND;
    unsigned short* Yw_bb  = ub + uoff; uoff += (size_t)MB * ND;
    unsigned short* h16a   = ub + uoff; uoff += (size_t)B_SZ * ND;
    unsigned short* h16b   = ub + uoff; uoff += (size_t)B_SZ * ND;
    unsigned short* r16    = ub + uoff; uoff += (size_t)B_SZ * ND;
    unsigned short* a16    = ub + uoff; uoff += (size_t)B_SZ * ND;
    unsigned short* pWih_b = ub + uoff; uoff += (size_t)G3 * 320;
    unsigned short* hWih_b = ub + uoff; uoff += (size_t)G3 * 320;
    unsigned short* pWhh_b = ub + uoff; uoff += (size_t)G3 * ND;
    unsigned short* hWhh_b = ub + uoff; uoff += (size_t)G3 * ND;
    unsigned short* mWihR  = ub + uoff; uoff += (size_t)G3 * ND;
    unsigned short* WyT_b  = ub + uoff; uoff += (size_t)ND * ND;
    unsigned short* WhT_b  = ub + uoff; uoff += (size_t)ND * ND;
    unsigned short* WrT_b  = ub + uoff; uoff += (size_t)ND * ND;
    unsigned short* Wbig   = ub + uoff; uoff += (size_t)2048 * 1024;
    off += (uoff + 1) / 2;
    if (ws_size < off * sizeof(float)) return;

    auto cblk = [](long n) { return (int)((n + 255) / 256); };

    // ---- prep ----
    prep_idx<<<cblk(MB), 256, 0, stream>>>(prem, hyp, idx_p, idx_h);
    conv_w <<<cblk((long)G3 * 320), 256, 0, stream>>>(p_Wih, pWih_b, G3, EMBD, 320, EMBD, 0);
    conv_w <<<cblk((long)G3 * 320), 256, 0, stream>>>(h_Wih, hWih_b, G3, EMBD, 320, EMBD, 0);
    conv_w <<<cblk((long)G3 * ND), 256, 0, stream>>>(p_Whh, pWhh_b, G3, ND, ND, ND, 0);
    conv_w <<<cblk((long)G3 * ND), 256, 0, stream>>>(h_Whh, hWhh_b, G3, ND, ND, ND, 0);
    conv_w <<<cblk((long)G3 * ND), 256, 0, stream>>>(m_Wih, mWihR, G3, ND, ND, 2 * ND, ND);
    conv_wT<<<cblk((long)ND * ND), 256, 0, stream>>>(W_y, WyT_b, ND, ND, ND, ND);
    conv_wT<<<cblk((long)ND * ND), 256, 0, stream>>>(W_h, WhT_b, ND, ND, ND, ND);
    conv_wT<<<cblk((long)ND * ND), 256, 0, stream>>>(W_r, WrT_b, ND, ND, ND, ND);
    conv_wbig<<<cblk(2048L * 1024), 256, 0, stream>>>(m_Wih, m_Whh, Wbig);
    zero_kernel<<<cblk(B_SZ * ND), 256, 0, stream>>>(h32a, B_SZ * ND);
    zero_kernel<<<cblk(B_SZ * ND / 2), 256, 0, stream>>>((float*)h16a, B_SZ * ND / 2);
    zero_kernel<<<cblk(B_SZ * ND), 256, 0, stream>>>(r32, B_SZ * ND);
    zero_kernel<<<cblk(B_SZ * ND / 2), 256, 0, stream>>>((float*)r16, B_SZ * ND / 2);
    zero_kernel<<<1, 256, 0, stream>>>((float*)flags, 256);

    // ---- premise ----
    {
        dim3 g(G3 / 64, MB / 64);
        mfma_gemm<float, false><<<g, 256, 0, stream>>>(E, idx_p, pWih_b, p_bih, nullptr, GI,
                                                       MB, G3, EMBD, EMBD, 320, G3, 0, 0);
    }
    gru_chain<<<GRU_NB, 256, 0, stream>>>(pWhh_b, GI, p_bhh, prem, h32a, h32b, h16a, h16b,
                                          o_p_tb, o_p_bt, &flags[0]);

    // ---- hypothesis ----
    {
        dim3 g(G3 / 64, MB / 64);
        mfma_gemm<float, false><<<g, 256, 0, stream>>>(E, idx_h, hWih_b, h_bih, nullptr, GI,
                                                       MB, G3, EMBD, EMBD, 320, G3, 0, 0);
    }
    gru_chain<<<GRU_NB, 256, 0, stream>>>(hWhh_b, GI, h_bhh, hyp, h32a, h32b, h16a, h16b,
                                          o_h_tb, nullptr, &flags[64]);

    // ---- attention precompute ----
    {
        dim3 g(ND / 64, MB / 64);
        mfma_gemm<unsigned short, true><<<g, 256, 0, stream>>>(o_p_tb, nullptr, WyT_b, nullptr, nullptr,
                                                               Yw_bb, MB, ND, ND, ND, ND, ND, 0, 1);
        mfma_gemm<unsigned short, false><<<g, 256, 0, stream>>>(o_h_tb, nullptr, WhT_b, nullptr, nullptr,
                                                                OHWh, MB, ND, ND, ND, ND, ND, 0, 0);
        dim3 g2(G3 / 64, MB / 64);
        mfma_gemm<unsigned short, false><<<g2, 256, 0, stream>>>(o_h_tb, nullptr, mWihR, m_bih, nullptr,
                                                                 GI, MB, G3, ND, ND, ND, G3, 0, 0);
    }

    // ---- match chain ----
    match_chain<<<MAT_NB, 256, 0, stream>>>(WrT_b, Wbig, OHWh, GI, m_bhh, W_alpha,
                                            Yw_bb, o_p_bt, prem, hyp, r32, r16,
                                            sbuf, a16, &flags[128]);

    final_logits<<<B_SZ, 64, 0, stream>>>(r32, out_W, out_b, out);
}

// Round 6
// 11391.436 us; speedup vs baseline: 1.4803x; 1.2498x over previous
//
#include <hip/hip_runtime.h>
#include <math.h>

#define B_SZ 128
#define T_SZ 128
#define EMBD 300
#define ND 512
#define G3 1536

typedef short s16x8 __attribute__((ext_vector_type(8)));
typedef float f32x4 __attribute__((ext_vector_type(4)));
typedef unsigned long long u64;

__device__ __forceinline__ unsigned short f2b(float x) {
    unsigned u = __float_as_uint(x);
    unsigned r = (u + 0x7fff + ((u >> 16) & 1)) >> 16;  // RNE
    return (unsigned short)r;
}
__device__ __forceinline__ float b2f(unsigned short v) {
    return __uint_as_float(((unsigned)v) << 16);
}
__device__ __forceinline__ float fsigmoid(float x) { return 1.0f / (1.0f + __expf(-x)); }
__device__ __forceinline__ float ftanh(float x) { return 1.0f - 2.0f / (__expf(2.0f * x) + 1.0f); }

__device__ __forceinline__ f32x4 mfma16(s16x8 a, s16x8 b, f32x4 c) {
    return __builtin_amdgcn_mfma_f32_16x16x32_bf16(a, b, c, 0, 0, 0);
}

// ---- coherent (cache-bypassing, fence-free) access helpers ----
__device__ __forceinline__ u64 cld64(const void* p) {
    return __hip_atomic_load((const u64*)p, __ATOMIC_RELAXED, __HIP_MEMORY_SCOPE_AGENT);
}
__device__ __forceinline__ void cst64(void* p, u64 v) {
    __hip_atomic_store((u64*)p, v, __ATOMIC_RELAXED, __HIP_MEMORY_SCOPE_AGENT);
}
__device__ __forceinline__ unsigned cld32(const void* p) {
    return __hip_atomic_load((const unsigned*)p, __ATOMIC_RELAXED, __HIP_MEMORY_SCOPE_AGENT);
}
__device__ __forceinline__ void cst32(void* p, unsigned v) {
    __hip_atomic_store((unsigned*)p, v, __ATOMIC_RELAXED, __HIP_MEMORY_SCOPE_AGENT);
}
__device__ __forceinline__ s16x8 cld_frag(const unsigned short* p) {
    union { u64 q[2]; s16x8 v; } u;
    u.q[0] = cld64(p);
    u.q[1] = cld64(p + 4);
    return u.v;
}

// ---- fence-free grid barrier: syncthreads drains vmcnt (sc1 stores then visible),
// flag store + parallel poll, monotone epoch, NO cache-maintenance ops ----
__device__ __forceinline__ void fbar(unsigned* flags, int nb, unsigned ep)
{
    __syncthreads();   // compiler emits s_waitcnt vmcnt(0) before s_barrier for every wave
    if (threadIdx.x == 0)
        cst32(&flags[blockIdx.x], ep);
    if (threadIdx.x < 64) {
#pragma unroll 1
        for (int f = threadIdx.x; f < nb; f += 64)
            while (cld32(&flags[f]) < ep)
                __builtin_amdgcn_s_sleep(1);
    }
    __syncthreads();
}

// ---------------- generic MFMA GEMM (precompute only) ----------------
template<typename AT, bool OB>
__global__ __launch_bounds__(256)
void mfma_gemm(const AT* __restrict__ A, const int* __restrict__ idxA,
               const unsigned short* __restrict__ Wb, const float* __restrict__ bias,
               const float* __restrict__ addC, void* __restrict__ Cv,
               int M, int N, int K, int ldA, int Kpad, int ldC, int ldAdd, int permC)
{
    __shared__ unsigned short As[64][40];
    __shared__ unsigned short Bs[64][40];
    const int tid = threadIdx.x;
    const int wv = tid >> 6, lane = tid & 63;
    const int wm = wv >> 1, wn = wv & 1;
    const int m0 = blockIdx.y * 64, n0 = blockIdx.x * 64;

    f32x4 acc[2][2] = {{{0.f,0.f,0.f,0.f},{0.f,0.f,0.f,0.f}},
                       {{0.f,0.f,0.f,0.f},{0.f,0.f,0.f,0.f}}};
    const int r_st = tid >> 2, k_st = (tid & 3) * 8;

    long arow = -1;
    {
        int gm = m0 + r_st;
        if (gm < M) arow = idxA ? (long)idxA[gm] : (long)gm;
    }

    const int kIters = (K + 31) / 32;
    for (int it = 0; it < kIters; ++it) {
        const int kg = it * 32 + k_st;
        {
            s16x8 pk = {0,0,0,0,0,0,0,0};
            if (arow >= 0) {
                if constexpr (sizeof(AT) == 2) {
                    if (kg + 8 <= K) {
                        pk = *(const s16x8*)((const unsigned short*)A + arow * (long)ldA + kg);
                    } else {
#pragma unroll
                        for (int j = 0; j < 8; ++j)
                            if (kg + j < K) pk[j] = (short)((const unsigned short*)A)[arow * (long)ldA + kg + j];
                    }
                } else {
                    if (kg + 8 <= K) {
                        const float* p = (const float*)A + arow * (long)ldA + kg;
                        f32x4 u0 = *(const f32x4*)p;
                        f32x4 u1 = *(const f32x4*)(p + 4);
#pragma unroll
                        for (int j = 0; j < 4; ++j) { pk[j] = (short)f2b(u0[j]); pk[4+j] = (short)f2b(u1[j]); }
                    } else {
#pragma unroll
                        for (int j = 0; j < 8; ++j) {
                            int kk = kg + j;
                            if (kk < K) pk[j] = (short)f2b(((const float*)A)[arow * (long)ldA + kk]);
                        }
                    }
                }
            }
            *(s16x8*)&As[r_st][k_st] = pk;
        }
        {
            int gn = n0 + r_st;
            s16x8 pk = {0,0,0,0,0,0,0,0};
            if (gn < N) pk = *(const s16x8*)&Wb[(long)gn * Kpad + kg];
            *(s16x8*)&Bs[r_st][k_st] = pk;
        }
        __syncthreads();
        {
            const int koff = (lane >> 4) * 8;
            s16x8 af[2], bfr[2];
#pragma unroll
            for (int f = 0; f < 2; ++f) {
                af[f]  = *(s16x8*)&As[wm * 32 + f * 16 + (lane & 15)][koff];
                bfr[f] = *(s16x8*)&Bs[wn * 32 + f * 16 + (lane & 15)][koff];
            }
#pragma unroll
            for (int fi = 0; fi < 2; ++fi)
#pragma unroll
                for (int fj = 0; fj < 2; ++fj)
                    acc[fi][fj] = mfma16(af[fi], bfr[fj], acc[fi][fj]);
        }
        __syncthreads();
    }
#pragma unroll
    for (int fi = 0; fi < 2; ++fi)
#pragma unroll
        for (int fj = 0; fj < 2; ++fj)
#pragma unroll
            for (int r = 0; r < 4; ++r) {
                int m = m0 + wm * 32 + fi * 16 + (lane >> 4) * 4 + r;
                int n = n0 + wn * 32 + fj * 16 + (lane & 15);
                if (m < M && n < N) {
                    float v = acc[fi][fj][r];
                    if (bias) v += bias[n];
                    if (addC) v += addC[(long)m * ldAdd + n];
                    long mo = permC ? ((long)(m & 127) * T_SZ + (m >> 7)) : (long)m;
                    if constexpr (OB) ((unsigned short*)Cv)[mo * ldC + n] = f2b(v);
                    else               ((float*)Cv)[mo * ldC + n] = v;
                }
            }
}

// ---------------- persistent GRU chain ----------------
// 64 blocks = 32 d-tiles x 2 b-halves. Whh in LDS; h16 via coherent direct-to-frag loads.
#define GRU_NB 64
__global__ __launch_bounds__(256, 1)
void gru_chain(const unsigned short* __restrict__ Whh_b, const float* __restrict__ GI,
               const float* __restrict__ bhh, const int* __restrict__ toks,
               float* __restrict__ h32a, float* __restrict__ h32b,
               unsigned short* __restrict__ h16a, unsigned short* __restrict__ h16b,
               unsigned short* __restrict__ o_tb, unsigned short* __restrict__ o_bt,
               unsigned* __restrict__ flags)
{
    __shared__ unsigned short wlds[3][16][512];   // 48 KB
    __shared__ unsigned short ht[64][20];         // 2.5 KB transpose buffer
    const int tid = threadIdx.x;
    const int wv = tid >> 6, lane = tid & 63;
    const int dt = blockIdx.x & 31, bh = blockIdx.x >> 5;
    const int b0 = bh * 64;

    for (int s = 0; s < 12; ++s) {
        int slot = tid + s * 256;
        int g = slot >> 10, rem = slot & 1023, ks = rem >> 6, ln = rem & 63;
        int row = g * ND + dt * 16 + (ln & 15);
        int k = ks * 32 + (ln >> 4) * 8;
        *(s16x8*)&wlds[g][ks][ln * 8] = *(const s16x8*)&Whh_b[(long)row * ND + k];
    }
    __syncthreads();

    const int d = dt * 16 + (lane & 15);
    const int brow = b0 + wv * 16 + (lane >> 4) * 4;
    const int arow = b0 + wv * 16 + (lane & 15);
    const int akoff = (lane >> 4) * 8;

    float o_run[4] = {0.f, 0.f, 0.f, 0.f};
    unsigned ep = 0;

    for (int t = 0; t < T_SZ; ++t) {
        const unsigned short* hin16 = (t & 1) ? h16b : h16a;
        const float*          hin32 = (t & 1) ? h32b : h32a;
        float*          hout32 = (t & 1) ? h32a : h32b;
        unsigned short* hout16 = (t & 1) ? h16a : h16b;

        // prefetch epilogue operands (normal cached)
        const float* git = GI + (long)t * (B_SZ * G3);
        float gi_r[4], gi_z[4], gi_n[4], hp[4]; int mk[4];
#pragma unroll
        for (int rr = 0; rr < 4; ++rr) {
            int b = brow + rr;
            gi_r[rr] = git[(long)b * G3 + d];
            gi_z[rr] = git[(long)b * G3 + ND + d];
            gi_n[rr] = git[(long)b * G3 + 2 * ND + d];
            hp[rr]   = hin32[(long)b * ND + d];
            mk[rr]   = toks[b * T_SZ + t];
        }

        f32x4 acc0 = {0,0,0,0}, acc1 = {0,0,0,0}, acc2 = {0,0,0,0};
#pragma unroll
        for (int ks = 0; ks < 16; ++ks) {
            s16x8 a  = cld_frag(&hin16[(long)arow * ND + ks * 32 + akoff]);
            s16x8 br = *(s16x8*)&wlds[0][ks][lane * 8];
            s16x8 bz = *(s16x8*)&wlds[1][ks][lane * 8];
            s16x8 bn = *(s16x8*)&wlds[2][ks][lane * 8];
            acc0 = mfma16(a, br, acc0);
            acc1 = mfma16(a, bz, acc1);
            acc2 = mfma16(a, bn, acc2);
        }

#pragma unroll
        for (int rr = 0; rr < 4; ++rr) {
            int b = brow + rr;
            float rg = fsigmoid(gi_r[rr] + acc0[rr] + bhh[d]);
            float zg = fsigmoid(gi_z[rr] + acc1[rr] + bhh[ND + d]);
            float ng = ftanh(gi_n[rr] + rg * (acc2[rr] + bhh[2 * ND + d]));
            float hr = (1.0f - zg) * ng + zg * hp[rr];
            bool m = mk[rr] != 0;
            float hn = m ? hr : hp[rr];
            hout32[(long)b * ND + d] = hn;              // self-consumed: normal
            ht[b - b0][lane & 15] = f2b(hn);
            o_run[rr] = (t == 0) ? hr : (m ? hr : o_run[rr]);
            o_tb[((long)t * B_SZ + b) * ND + d] = f2b(o_run[rr]);   // later kernels: normal
            if (o_bt) o_bt[((long)b * T_SZ + t) * ND + d] = f2b(o_run[rr]);
        }
        __syncthreads();
        {
            int bl = tid & 63, dq = tid >> 6;
            u64 v = *(u64*)&ht[bl][dq * 4];
            cst64(&hout16[(long)(b0 + bl) * ND + dt * 16 + dq * 4], v);   // coherent
        }
        fbar(flags, GRU_NB, ++ep);
    }
}

// ---------------- persistent match chain ----------------
// 128 blocks, 3 barriers/step. Cross-block data coherent; read-only streams cached.
#define MAT_NB 128
__global__ __launch_bounds__(256, 1)
void match_chain(const unsigned short* __restrict__ WrT_b,
                 const unsigned short* __restrict__ Wbig,
                 const float* __restrict__ OHWh, const float* __restrict__ OHGI,
                 const float* __restrict__ m_bhh, const float* __restrict__ Walpha,
                 const unsigned short* __restrict__ Yw_bb,
                 const unsigned short* __restrict__ Y_bb,
                 const int* __restrict__ prem, const int* __restrict__ hyp,
                 float* __restrict__ r32, unsigned short* __restrict__ r16,
                 float* __restrict__ sbuf, unsigned short* __restrict__ a16,
                 unsigned* __restrict__ flags)
{
    __shared__ unsigned short w1[16][512];     // 16 KB
    __shared__ unsigned short w3[32][512];     // 32 KB
    __shared__ float sb_lds[32][18];           // 2.3 KB
    __shared__ float bounce[128][17];          // 8.7 KB
    __shared__ float lg[T_SZ];
    __shared__ float red[2];
    const int tid = threadIdx.x;
    const int wv = tid >> 6, lane = tid & 63;
    const int blk = blockIdx.x;
    const int nt = blk & 31, bq = blk >> 5;
    const int akoff = (lane >> 4) * 8;

    for (int s = 0; s < 4; ++s) {
        int slot = tid + s * 256;
        int ks = slot >> 6, ln = slot & 63;
        *(s16x8*)&w1[ks][ln * 8] =
            *(const s16x8*)&WrT_b[(long)(nt * 16 + (ln & 15)) * ND + ks * 32 + (ln >> 4) * 8];
    }
    for (int s = 0; s < 8; ++s) {
        int slot = tid + s * 256;
        int ks = slot >> 6, ln = slot & 63;
        *(s16x8*)&w3[ks][ln * 8] =
            *(const s16x8*)&Wbig[(long)(blk * 16 + (ln & 15)) * 1024 + ks * 32 + (ln >> 4) * 8];
    }
    __syncthreads();

    unsigned ep = 0;

    for (int t = 0; t < T_SZ; ++t) {
        // ---- P1: s = r @ WrT^T + OHWh[t]; 32 b-rows x 16 cols, 2 waves ----
        if (wv < 2) {
            f32x4 acc = {0,0,0,0};
            int arow1 = bq * 32 + wv * 16 + (lane & 15);
#pragma unroll
            for (int ks = 0; ks < 16; ++ks) {
                s16x8 a = cld_frag(&r16[(long)arow1 * ND + ks * 32 + akoff]);
                acc = mfma16(a, *(s16x8*)&w1[ks][lane * 8], acc);
            }
            int nl = lane & 15;
            int browl = wv * 16 + (lane >> 4) * 4;
#pragma unroll
            for (int rr = 0; rr < 4; ++rr) {
                int bl = browl + rr;
                sb_lds[bl][nl] = acc[rr] +
                    OHWh[((long)t * B_SZ + bq * 32 + bl) * ND + nt * 16 + nl];
            }
        }
        __syncthreads();
        {
            int bl = tid >> 3, u = tid & 7;
            union { float f[2]; u64 q; } uu;
            uu.f[0] = sb_lds[bl][u * 2];
            uu.f[1] = sb_lds[bl][u * 2 + 1];
            cst64(&sbuf[(long)(bq * 32 + bl) * ND + nt * 16 + u * 2], uu.q);
        }
        fbar(flags, MAT_NB, ++ep);

        // ---- P2: attention for b = blk ----
        {
            const int b = blk;
            float sv[8], wa[8];
#pragma unroll
            for (int j = 0; j < 4; ++j) {
                u64 q = cld64(&sbuf[(long)b * ND + lane * 8 + j * 2]);
                sv[j * 2]     = __uint_as_float((unsigned)q);
                sv[j * 2 + 1] = __uint_as_float((unsigned)(q >> 32));
            }
#pragma unroll
            for (int j = 0; j < 8; ++j) wa[j] = Walpha[lane * 8 + j];
            for (int i = 0; i < 32; ++i) {
                int tp = i * 4 + wv;
                s16x8 yw = *(const s16x8*)&Yw_bb[((long)b * T_SZ + tp) * ND + lane * 8];
                float acc = 0.0f;
#pragma unroll
                for (int j = 0; j < 8; ++j)
                    acc += ftanh(b2f((unsigned short)yw[j]) + sv[j]) * wa[j];
#pragma unroll
                for (int off = 32; off; off >>= 1) acc += __shfl_xor(acc, off);
                if (lane == 0) {
                    float mm = (prem[b * T_SZ + tp] != 0) ? 0.0f : 1000.0f;
                    lg[tp] = acc - mm;
                }
            }
            __syncthreads();
            if (tid < 64) {
                float v = fmaxf(lg[tid], lg[tid + 64]);
#pragma unroll
                for (int off = 32; off; off >>= 1) v = fmaxf(v, __shfl_xor(v, off));
                if (tid == 0) red[0] = v;
            }
            __syncthreads();
            float mx = red[0];
            if (tid < T_SZ) lg[tid] = __expf(lg[tid] - mx);
            __syncthreads();
            if (tid < 64) {
                float v = lg[tid] + lg[tid + 64];
#pragma unroll
                for (int off = 32; off; off >>= 1) v += __shfl_xor(v, off);
                if (tid == 0) red[1] = v;
            }
            __syncthreads();
            float inv = 1.0f / red[1];
            int n2 = tid * 2;
            float a0 = 0.0f, a1 = 0.0f;
#pragma unroll 4
            for (int tp = 0; tp < T_SZ; ++tp) {
                float al = lg[tp] * inv;
                unsigned u = *(const unsigned*)&Y_bb[((long)b * T_SZ + tp) * ND + n2];
                a0 += al * __uint_as_float(u << 16);
                a1 += al * __uint_as_float(u & 0xffff0000u);
            }
            unsigned pack = (unsigned)f2b(a0) | ((unsigned)f2b(a1) << 16);
            cst32(&a16[(long)b * ND + n2], pack);
        }
        fbar(flags, MAT_NB, ++ep);

        // ---- P3: gates via direct-to-frag coherent loads + combine ----
        {
            f32x4 accA = {0,0,0,0}, accB = {0,0,0,0};
            int ar = wv * 16 + (lane & 15);
#pragma unroll
            for (int ks = 0; ks < 16; ++ks) {
                s16x8 a = cld_frag(&a16[(long)ar * ND + ks * 32 + akoff]);
                accA = mfma16(a, *(s16x8*)&w3[ks][lane * 8], accA);
            }
#pragma unroll
            for (int ks = 0; ks < 16; ++ks) {
                s16x8 a = cld_frag(&r16[(long)ar * ND + ks * 32 + akoff]);
                accA = mfma16(a, *(s16x8*)&w3[16 + ks][lane * 8], accA);
            }
#pragma unroll
            for (int ks = 0; ks < 16; ++ks) {
                s16x8 a = cld_frag(&a16[(long)(64 + ar) * ND + ks * 32 + akoff]);
                accB = mfma16(a, *(s16x8*)&w3[ks][lane * 8], accB);
            }
#pragma unroll
            for (int ks = 0; ks < 16; ++ks) {
                s16x8 a = cld_frag(&r16[(long)(64 + ar) * ND + ks * 32 + akoff]);
                accB = mfma16(a, *(s16x8*)&w3[16 + ks][lane * 8], accB);
            }
#pragma unroll
            for (int rr = 0; rr < 4; ++rr) {
                bounce[wv * 16 + (lane >> 4) * 4 + rr][lane & 15] = accA[rr];
                bounce[64 + wv * 16 + (lane >> 4) * 4 + rr][lane & 15] = accB[rr];
            }
        }
        __syncthreads();
        if (tid < 128) {
            int b = tid;
            const float* og = OHGI + ((long)t * B_SZ + b) * G3;
            f32x4 rp4 = *(const f32x4*)&r32[(long)b * ND + blk * 4];
            unsigned short o4[4];
            bool mkk = hyp[b * T_SZ + t] != 0;
#pragma unroll
            for (int dl = 0; dl < 4; ++dl) {
                int dd = blk * 4 + dl;
                float sr  = bounce[b][0 + dl]  + og[dd]          + m_bhh[dd];
                float sz  = bounce[b][4 + dl]  + og[ND + dd]     + m_bhh[ND + dd];
                float gin = bounce[b][8 + dl]  + og[2 * ND + dd];
                float ghn = bounce[b][12 + dl] + m_bhh[2 * ND + dd];
                float rg = fsigmoid(sr), zg = fsigmoid(sz);
                float ng = ftanh(gin + rg * ghn);
                float rn = (1.0f - zg) * ng + zg * rp4[dl];
                float v = mkk ? rn : rp4[dl];
                rp4[dl] = v;
                o4[dl] = f2b(v);
            }
            *(f32x4*)&r32[(long)b * ND + blk * 4] = rp4;   // self-consumed: normal
            u64 q = (u64)o4[0] | ((u64)o4[1] << 16) | ((u64)o4[2] << 32) | ((u64)o4[3] << 48);
            cst64(&r16[(long)b * ND + blk * 4], q);        // coherent
        }
        fbar(flags, MAT_NB, ++ep);
    }
}

// ---------------- prep / misc ----------------
__global__ void prep_idx(const int* __restrict__ prem, const int* __restrict__ hyp,
                         int* __restrict__ idx_p, int* __restrict__ idx_h)
{
    int i = blockIdx.x * blockDim.x + threadIdx.x;
    if (i < B_SZ * T_SZ) {
        int t = i / B_SZ, b = i % B_SZ;
        idx_p[i] = prem[b * T_SZ + t];
        idx_h[i] = hyp[b * T_SZ + t];
    }
}

__global__ void conv_w(const float* __restrict__ in, unsigned short* __restrict__ out,
                       int N, int K, int Kpad, int ldIn, int colOff)
{
    long i = (long)blockIdx.x * blockDim.x + threadIdx.x;
    if (i >= (long)N * Kpad) return;
    int n = (int)(i / Kpad), k = (int)(i % Kpad);
    float v = (k < K) ? in[(long)n * ldIn + k + colOff] : 0.0f;
    out[i] = f2b(v);
}

__global__ void conv_wT(const float* __restrict__ in, unsigned short* __restrict__ out,
                        int N, int K, int Kpad, int ldIn)
{
    long i = (long)blockIdx.x * blockDim.x + threadIdx.x;
    if (i >= (long)N * Kpad) return;
    int n = (int)(i / Kpad), k = (int)(i % Kpad);
    float v = (k < K) ? in[(long)k * ldIn + n] : 0.0f;
    out[i] = f2b(v);
}

// Wbig (2048 x 1024), rows fam-interleaved per block:
// row j = blk*16 + fam*4 + dl  represents (fam, d = blk*4+dl)
__global__ void conv_wbig(const float* __restrict__ mWih, const float* __restrict__ mWhh,
                          unsigned short* __restrict__ out)
{
    long i = (long)blockIdx.x * blockDim.x + threadIdx.x;
    if (i >= 2048L * 1024) return;
    int j = (int)(i >> 10), k = (int)(i & 1023);
    int blk = j >> 4, within = j & 15, fam = within >> 2, dl = within & 3;
    int d = blk * 4 + dl;
    float v = 0.0f;
    if (fam == 0)      v = (k < 512) ? mWih[(long)d * 1024 + k]          : mWhh[(long)d * 512 + (k - 512)];
    else if (fam == 1) v = (k < 512) ? mWih[(long)(512 + d) * 1024 + k]  : mWhh[(long)(512 + d) * 512 + (k - 512)];
    else if (fam == 2) v = (k < 512) ? mWih[(long)(1024 + d) * 1024 + k] : 0.0f;
    else               v = (k < 512) ? 0.0f : mWhh[(long)(1024 + d) * 512 + (k - 512)];
    out[i] = f2b(v);
}

__global__ void zero_kernel(float* __restrict__ p, int n)
{
    int i = blockIdx.x * blockDim.x + threadIdx.x;
    if (i < n) p[i] = 0.0f;
}

__global__ void final_logits(const float* __restrict__ r, const float* __restrict__ outW,
                             const float* __restrict__ outb, float* __restrict__ out)
{
    int b = blockIdx.x;
    int lane = threadIdx.x;
    float a0 = 0.0f, a1 = 0.0f, a2 = 0.0f;
    for (int k = lane; k < ND; k += 64) {
        float rv = r[(long)b * ND + k];
        a0 += rv * outW[0 * ND + k];
        a1 += rv * outW[1 * ND + k];
        a2 += rv * outW[2 * ND + k];
    }
#pragma unroll
    for (int off = 32; off; off >>= 1) {
        a0 += __shfl_down(a0, off);
        a1 += __shfl_down(a1, off);
        a2 += __shfl_down(a2, off);
    }
    if (lane == 0) {
        float l0 = a0 + outb[0], l1 = a1 + outb[1], l2 = a2 + outb[2];
        float mx = fmaxf(l0, fmaxf(l1, l2));
        float se = expf(l0 - mx) + expf(l1 - mx) + expf(l2 - mx);
        float ls = mx + logf(se);
        out[b * 3 + 0] = l0 - ls;
        out[b * 3 + 1] = l1 - ls;
        out[b * 3 + 2] = l2 - ls;
    }
}

// ---------------- host ----------------
extern "C" void kernel_launch(void* const* d_in, const int* in_sizes, int n_in,
                              void* d_out, int out_size, void* d_ws, size_t ws_size,
                              hipStream_t stream)
{
    const int*   prem    = (const int*)d_in[0];
    const int*   hyp     = (const int*)d_in[1];
    const float* E       = (const float*)d_in[2];
    const float* p_Wih   = (const float*)d_in[3];
    const float* p_Whh   = (const float*)d_in[4];
    const float* p_bih   = (const float*)d_in[5];
    const float* p_bhh   = (const float*)d_in[6];
    const float* h_Wih   = (const float*)d_in[7];
    const float* h_Whh   = (const float*)d_in[8];
    const float* h_bih   = (const float*)d_in[9];
    const float* h_bhh   = (const float*)d_in[10];
    const float* m_Wih   = (const float*)d_in[11];
    const float* m_Whh   = (const float*)d_in[12];
    const float* m_bih   = (const float*)d_in[13];
    const float* m_bhh   = (const float*)d_in[14];
    const float* W_y     = (const float*)d_in[15];
    const float* W_h     = (const float*)d_in[16];
    const float* W_r     = (const float*)d_in[17];
    const float* W_alpha = (const float*)d_in[18];
    const float* out_W   = (const float*)d_in[19];
    const float* out_b   = (const float*)d_in[20];
    float* out = (float*)d_out;

    const int MB = T_SZ * B_SZ;  // 16384

    float* ws = (float*)d_ws;
    size_t off = 0;
    float* GI    = ws + off; off += (size_t)MB * G3;       // GI_p / GI_h / OHGI
    float* OHWh  = ws + off; off += (size_t)MB * ND;
    float* h32a  = ws + off; off += (size_t)B_SZ * ND;
    float* h32b  = ws + off; off += (size_t)B_SZ * ND;
    float* r32   = ws + off; off += (size_t)B_SZ * ND;
    float* sbuf  = ws + off; off += (size_t)B_SZ * ND;
    unsigned* flags = (unsigned*)(ws + off); off += 256;   // [0:64) gru_p, [64:128) gru_h, [128:256) match
    int* idx_p = (int*)(ws + off); off += (size_t)B_SZ * T_SZ;
    int* idx_h = (int*)(ws + off); off += (size_t)B_SZ * T_SZ;
    unsigned short* ub = (unsigned short*)(ws + off);
    size_t uoff = 0;
    unsigned short* o_p_tb = ub + uoff; uoff += (size_t)MB * ND;
    unsigned short* o_p_bt = ub + uoff; uoff += (size_t)MB * ND;   // Y_bb
    unsigned short* o_h_tb = ub + uoff; uoff += (size_t)MB * ND;
    unsigned short* Yw_bb  = ub + uoff; uoff += (size_t)MB * ND;
    unsigned short* h16a   = ub + uoff; uoff += (size_t)B_SZ * ND;
    unsigned short* h16b   = ub + uoff; uoff += (size_t)B_SZ * ND;
    unsigned short* r16    = ub + uoff; uoff += (size_t)B_SZ * ND;
    unsigned short* a16    = ub + uoff; uoff += (size_t)B_SZ * ND;
    unsigned short* pWih_b = ub + uoff; uoff += (size_t)G3 * 320;
    unsigned short* hWih_b = ub + uoff; uoff += (size_t)G3 * 320;
    unsigned short* pWhh_b = ub + uoff; uoff += (size_t)G3 * ND;
    unsigned short* hWhh_b = ub + uoff; uoff += (size_t)G3 * ND;
    unsigned short* mWihR  = ub + uoff; uoff += (size_t)G3 * ND;
    unsigned short* WyT_b  = ub + uoff; uoff += (size_t)ND * ND;
    unsigned short* WhT_b  = ub + uoff; uoff += (size_t)ND * ND;
    unsigned short* WrT_b  = ub + uoff; uoff += (size_t)ND * ND;
    unsigned short* Wbig   = ub + uoff; uoff += (size_t)2048 * 1024;
    off += (uoff + 1) / 2;
    if (ws_size < off * sizeof(float)) return;

    auto cblk = [](long n) { return (int)((n + 255) / 256); };

    // ---- prep ----
    prep_idx<<<cblk(MB), 256, 0, stream>>>(prem, hyp, idx_p, idx_h);
    conv_w <<<cblk((long)G3 * 320), 256, 0, stream>>>(p_Wih, pWih_b, G3, EMBD, 320, EMBD, 0);
    conv_w <<<cblk((long)G3 * 320), 256, 0, stream>>>(h_Wih, hWih_b, G3, EMBD, 320, EMBD, 0);
    conv_w <<<cblk((long)G3 * ND), 256, 0, stream>>>(p_Whh, pWhh_b, G3, ND, ND, ND, 0);
    conv_w <<<cblk((long)G3 * ND), 256, 0, stream>>>(h_Whh, hWhh_b, G3, ND, ND, ND, 0);
    conv_w <<<cblk((long)G3 * ND), 256, 0, stream>>>(m_Wih, mWihR, G3, ND, ND, 2 * ND, ND);
    conv_wT<<<cblk((long)ND * ND), 256, 0, stream>>>(W_y, WyT_b, ND, ND, ND, ND);
    conv_wT<<<cblk((long)ND * ND), 256, 0, stream>>>(W_h, WhT_b, ND, ND, ND, ND);
    conv_wT<<<cblk((long)ND * ND), 256, 0, stream>>>(W_r, WrT_b, ND, ND, ND, ND);
    conv_wbig<<<cblk(2048L * 1024), 256, 0, stream>>>(m_Wih, m_Whh, Wbig);
    zero_kernel<<<cblk(B_SZ * ND), 256, 0, stream>>>(h32a, B_SZ * ND);
    zero_kernel<<<cblk(B_SZ * ND / 2), 256, 0, stream>>>((float*)h16a, B_SZ * ND / 2);
    zero_kernel<<<cblk(B_SZ * ND), 256, 0, stream>>>(r32, B_SZ * ND);
    zero_kernel<<<cblk(B_SZ * ND / 2), 256, 0, stream>>>((float*)r16, B_SZ * ND / 2);
    zero_kernel<<<1, 256, 0, stream>>>((float*)flags, 256);

    // ---- premise ----
    {
        dim3 g(G3 / 64, MB / 64);
        mfma_gemm<float, false><<<g, 256, 0, stream>>>(E, idx_p, pWih_b, p_bih, nullptr, GI,
                                                       MB, G3, EMBD, EMBD, 320, G3, 0, 0);
    }
    gru_chain<<<GRU_NB, 256, 0, stream>>>(pWhh_b, GI, p_bhh, prem, h32a, h32b, h16a, h16b,
                                          o_p_tb, o_p_bt, &flags[0]);

    // ---- hypothesis ----
    {
        dim3 g(G3 / 64, MB / 64);
        mfma_gemm<float, false><<<g, 256, 0, stream>>>(E, idx_h, hWih_b, h_bih, nullptr, GI,
                                                       MB, G3, EMBD, EMBD, 320, G3, 0, 0);
    }
    gru_chain<<<GRU_NB, 256, 0, stream>>>(hWhh_b, GI, h_bhh, hyp, h32a, h32b, h16a, h16b,
                                          o_h_tb, nullptr, &flags[64]);

    // ---- attention precompute ----
    {
        dim3 g(ND / 64, MB / 64);
        mfma_gemm<unsigned short, true><<<g, 256, 0, stream>>>(o_p_tb, nullptr, WyT_b, nullptr, nullptr,
                                                               Yw_bb, MB, ND, ND, ND, ND, ND, 0, 1);
        mfma_gemm<unsigned short, false><<<g, 256, 0, stream>>>(o_h_tb, nullptr, WhT_b, nullptr, nullptr,
                                                                OHWh, MB, ND, ND, ND, ND, ND, 0, 0);
        dim3 g2(G3 / 64, MB / 64);
        mfma_gemm<unsigned short, false><<<g2, 256, 0, stream>>>(o_h_tb, nullptr, mWihR, m_bih, nullptr,
                                                                 GI, MB, G3, ND, ND, ND, G3, 0, 0);
    }

    // ---- match chain ----
    match_chain<<<MAT_NB, 256, 0, stream>>>(WrT_b, Wbig, OHWh, GI, m_bhh, W_alpha,
                                            Yw_bb, o_p_bt, prem, hyp, r32, r16,
                                            sbuf, a16, &flags[128]);

    final_logits<<<B_SZ, 64, 0, stream>>>(r32, out_W, out_b, out);
}

// Round 7
// 11381.818 us; speedup vs baseline: 1.4815x; 1.0008x over previous
//
#include <hip/hip_runtime.h>
#include <math.h>

#define B_SZ 128
#define T_SZ 128
#define EMBD 300
#define ND 512
#define G3 1536

typedef short s16x8 __attribute__((ext_vector_type(8)));
typedef float f32x4 __attribute__((ext_vector_type(4)));
typedef unsigned long long u64;

__device__ __forceinline__ unsigned short f2b(float x) {
    unsigned u = __float_as_uint(x);
    unsigned r = (u + 0x7fff + ((u >> 16) & 1)) >> 16;  // RNE
    return (unsigned short)r;
}
__device__ __forceinline__ float b2f(unsigned short v) {
    return __uint_as_float(((unsigned)v) << 16);
}
__device__ __forceinline__ float fsigmoid(float x) { return 1.0f / (1.0f + __expf(-x)); }
__device__ __forceinline__ float ftanh(float x) { return 1.0f - 2.0f / (__expf(2.0f * x) + 1.0f); }

__device__ __forceinline__ f32x4 mfma16(s16x8 a, s16x8 b, f32x4 c) {
    return __builtin_amdgcn_mfma_f32_16x16x32_bf16(a, b, c, 0, 0, 0);
}

// ---- coherent (LLC-point, fence-free) access helpers ----
__device__ __forceinline__ u64 cld64(const void* p) {
    return __hip_atomic_load((const u64*)p, __ATOMIC_RELAXED, __HIP_MEMORY_SCOPE_AGENT);
}
__device__ __forceinline__ void cst64(void* p, u64 v) {
    __hip_atomic_store((u64*)p, v, __ATOMIC_RELAXED, __HIP_MEMORY_SCOPE_AGENT);
}
__device__ __forceinline__ unsigned cld32(const void* p) {
    return __hip_atomic_load((const unsigned*)p, __ATOMIC_RELAXED, __HIP_MEMORY_SCOPE_AGENT);
}
__device__ __forceinline__ void cst32(void* p, unsigned v) {
    __hip_atomic_store((unsigned*)p, v, __ATOMIC_RELAXED, __HIP_MEMORY_SCOPE_AGENT);
}
__device__ __forceinline__ s16x8 cld_frag(const unsigned short* p) {
    union { u64 q[2]; s16x8 v; } u;
    u.q[0] = cld64(p);
    u.q[1] = cld64(p + 4);
    return u.v;
}

// ---- full-grid fence-free barrier (gru chains) ----
__device__ __forceinline__ void fbar(unsigned* flags, int nb, unsigned ep)
{
    __syncthreads();   // drains vmcnt per wave before s_barrier
    if (threadIdx.x == 0)
        cst32(&flags[blockIdx.x], ep);
    if (threadIdx.x < 64) {
#pragma unroll 1
        for (int f = threadIdx.x; f < nb; f += 64)
            while (cld32(&flags[f]) < ep)
                __builtin_amdgcn_s_sleep(1);
    }
    __syncthreads();
}

// ---------------- generic MFMA GEMM (precompute only) ----------------
template<typename AT, bool OB>
__global__ __launch_bounds__(256)
void mfma_gemm(const AT* __restrict__ A, const int* __restrict__ idxA,
               const unsigned short* __restrict__ Wb, const float* __restrict__ bias,
               void* __restrict__ Cv,
               int M, int N, int K, int ldA, int Kpad, int ldC)
{
    __shared__ unsigned short As[64][40];
    __shared__ unsigned short Bs[64][40];
    const int tid = threadIdx.x;
    const int wv = tid >> 6, lane = tid & 63;
    const int wm = wv >> 1, wn = wv & 1;
    const int m0 = blockIdx.y * 64, n0 = blockIdx.x * 64;

    f32x4 acc[2][2] = {{{0.f,0.f,0.f,0.f},{0.f,0.f,0.f,0.f}},
                       {{0.f,0.f,0.f,0.f},{0.f,0.f,0.f,0.f}}};
    const int r_st = tid >> 2, k_st = (tid & 3) * 8;

    long arow = -1;
    {
        int gm = m0 + r_st;
        if (gm < M) arow = idxA ? (long)idxA[gm] : (long)gm;
    }

    const int kIters = (K + 31) / 32;
    for (int it = 0; it < kIters; ++it) {
        const int kg = it * 32 + k_st;
        {
            s16x8 pk = {0,0,0,0,0,0,0,0};
            if (arow >= 0) {
                if constexpr (sizeof(AT) == 2) {
                    if (kg + 8 <= K) {
                        pk = *(const s16x8*)((const unsigned short*)A + arow * (long)ldA + kg);
                    } else {
#pragma unroll
                        for (int j = 0; j < 8; ++j)
                            if (kg + j < K) pk[j] = (short)((const unsigned short*)A)[arow * (long)ldA + kg + j];
                    }
                } else {
                    if (kg + 8 <= K) {
                        const float* p = (const float*)A + arow * (long)ldA + kg;
                        f32x4 u0 = *(const f32x4*)p;
                        f32x4 u1 = *(const f32x4*)(p + 4);
#pragma unroll
                        for (int j = 0; j < 4; ++j) { pk[j] = (short)f2b(u0[j]); pk[4+j] = (short)f2b(u1[j]); }
                    } else {
#pragma unroll
                        for (int j = 0; j < 8; ++j) {
                            int kk = kg + j;
                            if (kk < K) pk[j] = (short)f2b(((const float*)A)[arow * (long)ldA + kk]);
                        }
                    }
                }
            }
            *(s16x8*)&As[r_st][k_st] = pk;
        }
        {
            int gn = n0 + r_st;
            s16x8 pk = {0,0,0,0,0,0,0,0};
            if (gn < N) pk = *(const s16x8*)&Wb[(long)gn * Kpad + kg];
            *(s16x8*)&Bs[r_st][k_st] = pk;
        }
        __syncthreads();
        {
            const int koff = (lane >> 4) * 8;
            s16x8 af[2], bfr[2];
#pragma unroll
            for (int f = 0; f < 2; ++f) {
                af[f]  = *(s16x8*)&As[wm * 32 + f * 16 + (lane & 15)][koff];
                bfr[f] = *(s16x8*)&Bs[wn * 32 + f * 16 + (lane & 15)][koff];
            }
#pragma unroll
            for (int fi = 0; fi < 2; ++fi)
#pragma unroll
                for (int fj = 0; fj < 2; ++fj)
                    acc[fi][fj] = mfma16(af[fi], bfr[fj], acc[fi][fj]);
        }
        __syncthreads();
    }
#pragma unroll
    for (int fi = 0; fi < 2; ++fi)
#pragma unroll
        for (int fj = 0; fj < 2; ++fj)
#pragma unroll
            for (int r = 0; r < 4; ++r) {
                int m = m0 + wm * 32 + fi * 16 + (lane >> 4) * 4 + r;
                int n = n0 + wn * 32 + fj * 16 + (lane & 15);
                if (m < M && n < N) {
                    float v = acc[fi][fj][r];
                    if (bias) v += bias[n];
                    if constexpr (OB) ((unsigned short*)Cv)[(long)m * ldC + n] = f2b(v);
                    else               ((float*)Cv)[(long)m * ldC + n] = v;
                }
            }
}

// ---------------- persistent GRU chain ----------------
#define GRU_NB 64
__global__ __launch_bounds__(256, 1)
void gru_chain(const unsigned short* __restrict__ Whh_b, const float* __restrict__ GI,
               const float* __restrict__ bhh, const int* __restrict__ toks,
               float* __restrict__ h32a, float* __restrict__ h32b,
               unsigned short* __restrict__ h16a, unsigned short* __restrict__ h16b,
               unsigned short* __restrict__ o_bt,
               unsigned* __restrict__ flags)
{
    __shared__ unsigned short wlds[3][16][512];   // 48 KB
    __shared__ unsigned short ht[64][20];         // transpose buffer
    const int tid = threadIdx.x;
    const int wv = tid >> 6, lane = tid & 63;
    const int dt = blockIdx.x & 31, bh = blockIdx.x >> 5;
    const int b0 = bh * 64;

    for (int s = 0; s < 12; ++s) {
        int slot = tid + s * 256;
        int g = slot >> 10, rem = slot & 1023, ks = rem >> 6, ln = rem & 63;
        int row = g * ND + dt * 16 + (ln & 15);
        int k = ks * 32 + (ln >> 4) * 8;
        *(s16x8*)&wlds[g][ks][ln * 8] = *(const s16x8*)&Whh_b[(long)row * ND + k];
    }
    __syncthreads();

    const int d = dt * 16 + (lane & 15);
    const int brow = b0 + wv * 16 + (lane >> 4) * 4;
    const int arow = b0 + wv * 16 + (lane & 15);
    const int akoff = (lane >> 4) * 8;

    float o_run[4] = {0.f, 0.f, 0.f, 0.f};
    unsigned ep = 0;

    for (int t = 0; t < T_SZ; ++t) {
        const unsigned short* hin16 = (t & 1) ? h16b : h16a;
        const float*          hin32 = (t & 1) ? h32b : h32a;
        float*          hout32 = (t & 1) ? h32a : h32b;
        unsigned short* hout16 = (t & 1) ? h16a : h16b;

        const float* git = GI + (long)t * (B_SZ * G3);
        float gi_r[4], gi_z[4], gi_n[4], hp[4]; int mk[4];
#pragma unroll
        for (int rr = 0; rr < 4; ++rr) {
            int b = brow + rr;
            gi_r[rr] = git[(long)b * G3 + d];
            gi_z[rr] = git[(long)b * G3 + ND + d];
            gi_n[rr] = git[(long)b * G3 + 2 * ND + d];
            hp[rr]   = hin32[(long)b * ND + d];
            mk[rr]   = toks[b * T_SZ + t];
        }

        f32x4 acc0 = {0,0,0,0}, acc1 = {0,0,0,0}, acc2 = {0,0,0,0};
#pragma unroll
        for (int ks = 0; ks < 16; ++ks) {
            s16x8 a  = cld_frag(&hin16[(long)arow * ND + ks * 32 + akoff]);
            s16x8 br = *(s16x8*)&wlds[0][ks][lane * 8];
            s16x8 bz = *(s16x8*)&wlds[1][ks][lane * 8];
            s16x8 bn = *(s16x8*)&wlds[2][ks][lane * 8];
            acc0 = mfma16(a, br, acc0);
            acc1 = mfma16(a, bz, acc1);
            acc2 = mfma16(a, bn, acc2);
        }

#pragma unroll
        for (int rr = 0; rr < 4; ++rr) {
            int b = brow + rr;
            float rg = fsigmoid(gi_r[rr] + acc0[rr] + bhh[d]);
            float zg = fsigmoid(gi_z[rr] + acc1[rr] + bhh[ND + d]);
            float ng = ftanh(gi_n[rr] + rg * (acc2[rr] + bhh[2 * ND + d]));
            float hr = (1.0f - zg) * ng + zg * hp[rr];
            bool m = mk[rr] != 0;
            float hn = m ? hr : hp[rr];
            hout32[(long)b * ND + d] = hn;              // block-private: normal
            ht[b - b0][lane & 15] = f2b(hn);
            o_run[rr] = (t == 0) ? hr : (m ? hr : o_run[rr]);
            o_bt[((long)b * T_SZ + t) * ND + d] = f2b(o_run[rr]);  // later launches: normal
        }
        __syncthreads();
        {
            int bl = tid & 63, dq = tid >> 6;
            u64 v = *(u64*)&ht[bl][dq * 4];
            cst64(&hout16[(long)(b0 + bl) * ND + dt * 16 + dq * 4], v);   // coherent
        }
        fbar(flags, GRU_NB, ++ep);
    }
}

// ---------------- persistent match chain: 256 blocks, role-split ----------------
// LOW (0..127):  b = blk. LDS-resident Yw[b] (128KB). Per step: s-GEMV (VALU) ->
//                attention (LDS Yw + L2 Y) -> a16 coherent. Signal lflags.
// UP (128..255): ug = blk-128. P3: gates = [a|r] @ Wbig^T (16 fam-interleaved rows,
//                LDS) + combine -> 4 cols of r. Signal uflags. r16 double-buffered.
__global__ __launch_bounds__(256, 1)
void match_chain(const unsigned short* __restrict__ WrT_b,
                 const unsigned short* __restrict__ Wbig,
                 const unsigned short* __restrict__ OHWh_bt,
                 const unsigned short* __restrict__ OHGI_bt,
                 const float* __restrict__ m_bhh, const float* __restrict__ Walpha,
                 const unsigned short* __restrict__ Yw_bb,
                 const unsigned short* __restrict__ Y_bb,
                 const int* __restrict__ prem, const int* __restrict__ hyp,
                 float* __restrict__ r32,
                 unsigned short* __restrict__ r16a, unsigned short* __restrict__ r16b,
                 unsigned short* __restrict__ a16,
                 unsigned* __restrict__ lflags, unsigned* __restrict__ uflags)
{
    __shared__ __align__(16) unsigned char smem[135744];
    const int tid = threadIdx.x;
    const int wv = tid >> 6, lane = tid & 63;

    if (blockIdx.x < 128) {
        // ================= LOW =================
        const int b = blockIdx.x;
        unsigned short (*ywl)[ND] = (unsigned short(*)[ND])smem;             // 128 KB
        float* rrow = (float*)(smem + 131072);                               // 2 KB
        float* sarr = (float*)(smem + 131072 + 2048);                        // 2 KB
        float* lg   = (float*)(smem + 131072 + 4096);                        // 512 B
        float* red  = (float*)(smem + 131072 + 4608);

        for (int s = 0; s < 32; ++s) {
            int c = s * 256 + tid;   // frag id 0..8191
            *(s16x8*)&ywl[c >> 6][(c & 63) * 8] =
                *(const s16x8*)&Yw_bb[((long)b * T_SZ + (c >> 6)) * ND + (c & 63) * 8];
        }
        float wa[8];
#pragma unroll
        for (int j = 0; j < 8; ++j) wa[j] = Walpha[lane * 8 + j];
        __syncthreads();

        for (int t = 0; t < T_SZ; ++t) {
            if (t > 0) {
                if (tid < 128)
                    while (cld32(&uflags[tid]) < (unsigned)t) __builtin_amdgcn_s_sleep(1);
            }
            __syncthreads();
            const unsigned short* r16rd = (t & 1) ? r16b : r16a;

            // (a) r-row -> LDS f32
            if (tid < 64) {
                s16x8 rv = cld_frag(&r16rd[(long)b * ND + tid * 8]);
#pragma unroll
                for (int j = 0; j < 8; ++j) rrow[tid * 8 + j] = b2f((unsigned short)rv[j]);
            }
            __syncthreads();
            // s-GEMV: 2 cols per thread
            {
                int n0 = tid * 2;
                float s0 = 0.f, s1 = 0.f;
#pragma unroll 4
                for (int ks = 0; ks < 64; ++ks) {
                    s16x8 w0 = *(const s16x8*)&WrT_b[(long)n0 * ND + ks * 8];
                    s16x8 w1 = *(const s16x8*)&WrT_b[((long)n0 + 1) * ND + ks * 8];
#pragma unroll
                    for (int j = 0; j < 8; ++j) {
                        float rk = rrow[ks * 8 + j];
                        s0 += rk * b2f((unsigned short)w0[j]);
                        s1 += rk * b2f((unsigned short)w1[j]);
                    }
                }
                unsigned q = *(const unsigned*)&OHWh_bt[((long)b * T_SZ + t) * ND + n0];
                sarr[n0]     = s0 + b2f((unsigned short)(q & 0xffffu));
                sarr[n0 + 1] = s1 + b2f((unsigned short)(q >> 16));
            }
            __syncthreads();
            // (b) logits
            float sv[8];
#pragma unroll
            for (int j = 0; j < 8; ++j) sv[j] = sarr[lane * 8 + j];
            for (int i = 0; i < 32; ++i) {
                int tp = i * 4 + wv;
                s16x8 yw = *(s16x8*)&ywl[tp][lane * 8];
                float acc = 0.f;
#pragma unroll
                for (int j = 0; j < 8; ++j)
                    acc += ftanh(b2f((unsigned short)yw[j]) + sv[j]) * wa[j];
#pragma unroll
                for (int off = 32; off; off >>= 1) acc += __shfl_xor(acc, off);
                if (lane == 0) {
                    float mm = (prem[b * T_SZ + tp] != 0) ? 0.f : 1000.f;
                    lg[tp] = acc - mm;
                }
            }
            __syncthreads();
            if (tid < 64) {
                float v = fmaxf(lg[tid], lg[tid + 64]);
#pragma unroll
                for (int off = 32; off; off >>= 1) v = fmaxf(v, __shfl_xor(v, off));
                if (tid == 0) red[0] = v;
            }
            __syncthreads();
            float mx = red[0];
            if (tid < T_SZ) lg[tid] = __expf(lg[tid] - mx);
            __syncthreads();
            if (tid < 64) {
                float v = lg[tid] + lg[tid + 64];
#pragma unroll
                for (int off = 32; off; off >>= 1) v += __shfl_xor(v, off);
                if (tid == 0) red[1] = v;
            }
            __syncthreads();
            // (c) weighted sum over Y (L2-resident)
            float inv = 1.0f / red[1];
            int n2 = tid * 2;
            float a0 = 0.f, a1 = 0.f;
#pragma unroll 8
            for (int tp = 0; tp < T_SZ; ++tp) {
                float al = lg[tp] * inv;
                unsigned u = *(const unsigned*)&Y_bb[((long)b * T_SZ + tp) * ND + n2];
                a0 += al * __uint_as_float(u << 16);
                a1 += al * __uint_as_float(u & 0xffff0000u);
            }
            unsigned pack = (unsigned)f2b(a0) | ((unsigned)f2b(a1) << 16);
            cst32(&a16[(long)b * ND + n2], pack);
            __syncthreads();
            if (tid == 0) cst32(&lflags[b], (unsigned)(t + 1));
        }
    } else {
        // ================= UP =================
        const int ug = blockIdx.x - 128;
        unsigned short (*w3)[ND] = (unsigned short(*)[ND])smem;              // 32 KB
        float (*bounce)[17] = (float(*)[17])(smem + 32768);                  // 8.7 KB
        for (int s = 0; s < 8; ++s) {
            int slot = tid + s * 256;
            int ks = slot >> 6, ln = slot & 63;
            *(s16x8*)&w3[ks][ln * 8] =
                *(const s16x8*)&Wbig[(long)(ug * 16 + (ln & 15)) * 1024 + ks * 32 + (ln >> 4) * 8];
        }
        __syncthreads();
        const int akoff = (lane >> 4) * 8;
        const int ar = wv * 16 + (lane & 15);

        for (int t = 0; t < T_SZ; ++t) {
            if (tid < 128)
                while (cld32(&lflags[tid]) < (unsigned)(t + 1)) __builtin_amdgcn_s_sleep(1);
            __syncthreads();
            const unsigned short* r16rd = (t & 1) ? r16b : r16a;
            unsigned short*       r16wr = (t & 1) ? r16a : r16b;

            f32x4 accA = {0,0,0,0}, accB = {0,0,0,0};
#pragma unroll
            for (int ks = 0; ks < 16; ++ks) {
                s16x8 a = cld_frag(&a16[(long)ar * ND + ks * 32 + akoff]);
                accA = mfma16(a, *(s16x8*)&w3[ks][lane * 8], accA);
            }
#pragma unroll
            for (int ks = 0; ks < 16; ++ks) {
                s16x8 a = cld_frag(&r16rd[(long)ar * ND + ks * 32 + akoff]);
                accA = mfma16(a, *(s16x8*)&w3[16 + ks][lane * 8], accA);
            }
#pragma unroll
            for (int ks = 0; ks < 16; ++ks) {
                s16x8 a = cld_frag(&a16[(long)(64 + ar) * ND + ks * 32 + akoff]);
                accB = mfma16(a, *(s16x8*)&w3[ks][lane * 8], accB);
            }
#pragma unroll
            for (int ks = 0; ks < 16; ++ks) {
                s16x8 a = cld_frag(&r16rd[(long)(64 + ar) * ND + ks * 32 + akoff]);
                accB = mfma16(a, *(s16x8*)&w3[16 + ks][lane * 8], accB);
            }
#pragma unroll
            for (int rr = 0; rr < 4; ++rr) {
                bounce[wv * 16 + (lane >> 4) * 4 + rr][lane & 15] = accA[rr];
                bounce[64 + wv * 16 + (lane >> 4) * 4 + rr][lane & 15] = accB[rr];
            }
            __syncthreads();
            if (tid < 128) {
                int b = tid;
                const unsigned short* og = OHGI_bt + ((long)b * T_SZ + t) * G3;
                u64 q0 = *(const u64*)&og[ug * 4];
                u64 q1 = *(const u64*)&og[512 + ug * 4];
                u64 q2 = *(const u64*)&og[1024 + ug * 4];
                f32x4 rp4 = *(const f32x4*)&r32[(long)b * ND + ug * 4];
                bool mkk = hyp[b * T_SZ + t] != 0;
                unsigned short o4[4];
#pragma unroll
                for (int dl = 0; dl < 4; ++dl) {
                    int dd = ug * 4 + dl;
                    float sr  = bounce[b][0 + dl]  + b2f((unsigned short)(q0 >> (16 * dl))) + m_bhh[dd];
                    float sz  = bounce[b][4 + dl]  + b2f((unsigned short)(q1 >> (16 * dl))) + m_bhh[ND + dd];
                    float gin = bounce[b][8 + dl]  + b2f((unsigned short)(q2 >> (16 * dl)));
                    float ghn = bounce[b][12 + dl] + m_bhh[2 * ND + dd];
                    float rg = fsigmoid(sr), zg = fsigmoid(sz);
                    float ng = ftanh(gin + rg * ghn);
                    float rn = (1.0f - zg) * ng + zg * rp4[dl];
                    float v = mkk ? rn : rp4[dl];
                    rp4[dl] = v;
                    o4[dl] = f2b(v);
                }
                *(f32x4*)&r32[(long)b * ND + ug * 4] = rp4;   // block-private: normal
                u64 q = (u64)o4[0] | ((u64)o4[1] << 16) | ((u64)o4[2] << 32) | ((u64)o4[3] << 48);
                cst64(&r16wr[(long)b * ND + ug * 4], q);      // coherent, double-buffered
            }
            __syncthreads();
            if (tid == 0) cst32(&uflags[ug], (unsigned)(t + 1));
        }
    }
}

// ---------------- prep / misc ----------------
__global__ void prep_idx(const int* __restrict__ prem, const int* __restrict__ hyp,
                         int* __restrict__ idx_p, int* __restrict__ idx_h)
{
    int i = blockIdx.x * blockDim.x + threadIdx.x;
    if (i < B_SZ * T_SZ) {
        int t = i / B_SZ, b = i % B_SZ;
        idx_p[i] = prem[b * T_SZ + t];
        idx_h[i] = hyp[b * T_SZ + t];
    }
}

__global__ void conv_w(const float* __restrict__ in, unsigned short* __restrict__ out,
                       int N, int K, int Kpad, int ldIn, int colOff)
{
    long i = (long)blockIdx.x * blockDim.x + threadIdx.x;
    if (i >= (long)N * Kpad) return;
    int n = (int)(i / Kpad), k = (int)(i % Kpad);
    float v = (k < K) ? in[(long)n * ldIn + k + colOff] : 0.0f;
    out[i] = f2b(v);
}

__global__ void conv_wT(const float* __restrict__ in, unsigned short* __restrict__ out,
                        int N, int K, int Kpad, int ldIn)
{
    long i = (long)blockIdx.x * blockDim.x + threadIdx.x;
    if (i >= (long)N * Kpad) return;
    int n = (int)(i / Kpad), k = (int)(i % Kpad);
    float v = (k < K) ? in[(long)k * ldIn + n] : 0.0f;
    out[i] = f2b(v);
}

// Wbig (2048 x 1024), rows fam-interleaved per UP block:
// row j = ug*16 + fam*4 + dl  represents (fam, d = ug*4+dl)
__global__ void conv_wbig(const float* __restrict__ mWih, const float* __restrict__ mWhh,
                          unsigned short* __restrict__ out)
{
    long i = (long)blockIdx.x * blockDim.x + threadIdx.x;
    if (i >= 2048L * 1024) return;
    int j = (int)(i >> 10), k = (int)(i & 1023);
    int ug = j >> 4, within = j & 15, fam = within >> 2, dl = within & 3;
    int d = ug * 4 + dl;
    float v = 0.0f;
    if (fam == 0)      v = (k < 512) ? mWih[(long)d * 1024 + k]          : mWhh[(long)d * 512 + (k - 512)];
    else if (fam == 1) v = (k < 512) ? mWih[(long)(512 + d) * 1024 + k]  : mWhh[(long)(512 + d) * 512 + (k - 512)];
    else if (fam == 2) v = (k < 512) ? mWih[(long)(1024 + d) * 1024 + k] : 0.0f;
    else               v = (k < 512) ? 0.0f : mWhh[(long)(1024 + d) * 512 + (k - 512)];
    out[i] = f2b(v);
}

__global__ void zero_kernel(float* __restrict__ p, int n)
{
    int i = blockIdx.x * blockDim.x + threadIdx.x;
    if (i < n) p[i] = 0.0f;
}

__global__ void final_logits(const float* __restrict__ r, const float* __restrict__ outW,
                             const float* __restrict__ outb, float* __restrict__ out)
{
    int b = blockIdx.x;
    int lane = threadIdx.x;
    float a0 = 0.0f, a1 = 0.0f, a2 = 0.0f;
    for (int k = lane; k < ND; k += 64) {
        float rv = r[(long)b * ND + k];
        a0 += rv * outW[0 * ND + k];
        a1 += rv * outW[1 * ND + k];
        a2 += rv * outW[2 * ND + k];
    }
#pragma unroll
    for (int off = 32; off; off >>= 1) {
        a0 += __shfl_down(a0, off);
        a1 += __shfl_down(a1, off);
        a2 += __shfl_down(a2, off);
    }
    if (lane == 0) {
        float l0 = a0 + outb[0], l1 = a1 + outb[1], l2 = a2 + outb[2];
        float mx = fmaxf(l0, fmaxf(l1, l2));
        float se = expf(l0 - mx) + expf(l1 - mx) + expf(l2 - mx);
        float ls = mx + logf(se);
        out[b * 3 + 0] = l0 - ls;
        out[b * 3 + 1] = l1 - ls;
        out[b * 3 + 2] = l2 - ls;
    }
}

// ---------------- host ----------------
extern "C" void kernel_launch(void* const* d_in, const int* in_sizes, int n_in,
                              void* d_out, int out_size, void* d_ws, size_t ws_size,
                              hipStream_t stream)
{
    const int*   prem    = (const int*)d_in[0];
    const int*   hyp     = (const int*)d_in[1];
    const float* E       = (const float*)d_in[2];
    const float* p_Wih   = (const float*)d_in[3];
    const float* p_Whh   = (const float*)d_in[4];
    const float* p_bih   = (const float*)d_in[5];
    const float* p_bhh   = (const float*)d_in[6];
    const float* h_Wih   = (const float*)d_in[7];
    const float* h_Whh   = (const float*)d_in[8];
    const float* h_bih   = (const float*)d_in[9];
    const float* h_bhh   = (const float*)d_in[10];
    const float* m_Wih   = (const float*)d_in[11];
    const float* m_Whh   = (const float*)d_in[12];
    const float* m_bih   = (const float*)d_in[13];
    const float* m_bhh   = (const float*)d_in[14];
    const float* W_y     = (const float*)d_in[15];
    const float* W_h     = (const float*)d_in[16];
    const float* W_r     = (const float*)d_in[17];
    const float* W_alpha = (const float*)d_in[18];
    const float* out_W   = (const float*)d_in[19];
    const float* out_b   = (const float*)d_in[20];
    float* out = (float*)d_out;

    const int MB = T_SZ * B_SZ;  // 16384

    float* ws = (float*)d_ws;
    size_t off = 0;
    float* GI    = ws + off; off += (size_t)MB * G3;       // fp32, both GRU phases
    float* h32a  = ws + off; off += (size_t)B_SZ * ND;
    float* h32b  = ws + off; off += (size_t)B_SZ * ND;
    float* r32   = ws + off; off += (size_t)B_SZ * ND;
    unsigned* flags = (unsigned*)(ws + off); off += 384;   // [0:64) gruP, [64:128) gruH, [128:256) lflags, [256:384) uflags
    int* idx_p = (int*)(ws + off); off += (size_t)B_SZ * T_SZ;
    int* idx_h = (int*)(ws + off); off += (size_t)B_SZ * T_SZ;
    unsigned short* ub = (unsigned short*)(ws + off);
    size_t uoff = 0;
    unsigned short* o_p_bt = ub + uoff; uoff += (size_t)MB * ND;   // Y_bb
    unsigned short* o_h_bt = ub + uoff; uoff += (size_t)MB * ND;
    unsigned short* Yw_bb  = ub + uoff; uoff += (size_t)MB * ND;
    unsigned short* OHWh_bt= ub + uoff; uoff += (size_t)MB * ND;
    unsigned short* OHGI_bt= ub + uoff; uoff += (size_t)MB * G3;
    unsigned short* h16a   = ub + uoff; uoff += (size_t)B_SZ * ND;
    unsigned short* h16b   = ub + uoff; uoff += (size_t)B_SZ * ND;
    unsigned short* r16a   = ub + uoff; uoff += (size_t)B_SZ * ND;
    unsigned short* r16b   = ub + uoff; uoff += (size_t)B_SZ * ND;
    unsigned short* a16    = ub + uoff; uoff += (size_t)B_SZ * ND;
    unsigned short* pWih_b = ub + uoff; uoff += (size_t)G3 * 320;
    unsigned short* hWih_b = ub + uoff; uoff += (size_t)G3 * 320;
    unsigned short* pWhh_b = ub + uoff; uoff += (size_t)G3 * ND;
    unsigned short* hWhh_b = ub + uoff; uoff += (size_t)G3 * ND;
    unsigned short* mWihR  = ub + uoff; uoff += (size_t)G3 * ND;
    unsigned short* WyT_b  = ub + uoff; uoff += (size_t)ND * ND;
    unsigned short* WhT_b  = ub + uoff; uoff += (size_t)ND * ND;
    unsigned short* WrT_b  = ub + uoff; uoff += (size_t)ND * ND;
    unsigned short* Wbig   = ub + uoff; uoff += (size_t)2048 * 1024;
    off += (uoff + 1) / 2;
    if (ws_size < off * sizeof(float)) return;

    auto cblk = [](long n) { return (int)((n + 255) / 256); };

    // ---- prep ----
    prep_idx<<<cblk(MB), 256, 0, stream>>>(prem, hyp, idx_p, idx_h);
    conv_w <<<cblk((long)G3 * 320), 256, 0, stream>>>(p_Wih, pWih_b, G3, EMBD, 320, EMBD, 0);
    conv_w <<<cblk((long)G3 * 320), 256, 0, stream>>>(h_Wih, hWih_b, G3, EMBD, 320, EMBD, 0);
    conv_w <<<cblk((long)G3 * ND), 256, 0, stream>>>(p_Whh, pWhh_b, G3, ND, ND, ND, 0);
    conv_w <<<cblk((long)G3 * ND), 256, 0, stream>>>(h_Whh, hWhh_b, G3, ND, ND, ND, 0);
    conv_w <<<cblk((long)G3 * ND), 256, 0, stream>>>(m_Wih, mWihR, G3, ND, ND, 2 * ND, ND);
    conv_wT<<<cblk((long)ND * ND), 256, 0, stream>>>(W_y, WyT_b, ND, ND, ND, ND);
    conv_wT<<<cblk((long)ND * ND), 256, 0, stream>>>(W_h, WhT_b, ND, ND, ND, ND);
    conv_wT<<<cblk((long)ND * ND), 256, 0, stream>>>(W_r, WrT_b, ND, ND, ND, ND);
    conv_wbig<<<cblk(2048L * 1024), 256, 0, stream>>>(m_Wih, m_Whh, Wbig);
    zero_kernel<<<cblk(B_SZ * ND), 256, 0, stream>>>(h32a, B_SZ * ND);
    zero_kernel<<<cblk(B_SZ * ND / 2), 256, 0, stream>>>((float*)h16a, B_SZ * ND / 2);
    zero_kernel<<<cblk(B_SZ * ND), 256, 0, stream>>>(r32, B_SZ * ND);
    zero_kernel<<<cblk(B_SZ * ND / 2), 256, 0, stream>>>((float*)r16a, B_SZ * ND / 2);
    zero_kernel<<<cblk(B_SZ * ND / 2), 256, 0, stream>>>((float*)r16b, B_SZ * ND / 2);
    zero_kernel<<<1, 384, 0, stream>>>((float*)flags, 384);

    // ---- premise ----
    {
        dim3 g(G3 / 64, MB / 64);
        mfma_gemm<float, false><<<g, 256, 0, stream>>>(E, idx_p, pWih_b, p_bih, GI,
                                                       MB, G3, EMBD, EMBD, 320, G3);
    }
    gru_chain<<<GRU_NB, 256, 0, stream>>>(pWhh_b, GI, p_bhh, prem, h32a, h32b, h16a, h16b,
                                          o_p_bt, &flags[0]);

    // ---- hypothesis ----
    {
        dim3 g(G3 / 64, MB / 64);
        mfma_gemm<float, false><<<g, 256, 0, stream>>>(E, idx_h, hWih_b, h_bih, GI,
                                                       MB, G3, EMBD, EMBD, 320, G3);
    }
    gru_chain<<<GRU_NB, 256, 0, stream>>>(hWhh_b, GI, h_bhh, hyp, h32a, h32b, h16a, h16b,
                                          o_h_bt, &flags[64]);

    // ---- attention precompute (all [b][t]-row GEMMs, bf16 outputs) ----
    {
        dim3 g(ND / 64, MB / 64);
        mfma_gemm<unsigned short, true><<<g, 256, 0, stream>>>(o_p_bt, nullptr, WyT_b, nullptr,
                                                               Yw_bb, MB, ND, ND, ND, ND, ND);
        mfma_gemm<unsigned short, true><<<g, 256, 0, stream>>>(o_h_bt, nullptr, WhT_b, nullptr,
                                                               OHWh_bt, MB, ND, ND, ND, ND, ND);
        dim3 g2(G3 / 64, MB / 64);
        mfma_gemm<unsigned short, true><<<g2, 256, 0, stream>>>(o_h_bt, nullptr, mWihR, m_bih,
                                                                OHGI_bt, MB, G3, ND, ND, ND, G3);
    }

    // ---- match chain (256 blocks, role-split, 2 partial barriers/step) ----
    match_chain<<<256, 256, 0, stream>>>(WrT_b, Wbig, OHWh_bt, OHGI_bt, m_bhh, W_alpha,
                                         Yw_bb, o_p_bt, prem, hyp, r32, r16a, r16b, a16,
                                         &flags[128], &flags[256]);

    final_logits<<<B_SZ, 64, 0, stream>>>(r32, out_W, out_b, out);
}

// Round 8
// 8892.929 us; speedup vs baseline: 1.8962x; 1.2799x over previous
//
#include <hip/hip_runtime.h>
#include <math.h>

#define B_SZ 128
#define T_SZ 128
#define EMBD 300
#define ND 512
#define G3 1536
#define FPAD 32   // flag padding stride (u32s) = 128 B

typedef short s16x8 __attribute__((ext_vector_type(8)));
typedef float f32x4 __attribute__((ext_vector_type(4)));
typedef unsigned long long u64;

__device__ __forceinline__ unsigned short f2b(float x) {
    unsigned u = __float_as_uint(x);
    unsigned r = (u + 0x7fff + ((u >> 16) & 1)) >> 16;  // RNE
    return (unsigned short)r;
}
__device__ __forceinline__ float b2f(unsigned short v) {
    return __uint_as_float(((unsigned)v) << 16);
}
__device__ __forceinline__ float fsigmoid(float x) { return 1.0f / (1.0f + __expf(-x)); }
__device__ __forceinline__ float ftanh(float x) { return 1.0f - 2.0f / (__expf(2.0f * x) + 1.0f); }

__device__ __forceinline__ f32x4 mfma16(s16x8 a, s16x8 b, f32x4 c) {
    return __builtin_amdgcn_mfma_f32_16x16x32_bf16(a, b, c, 0, 0, 0);
}

// ---- coherent (LLC-point, fence-free) access helpers ----
__device__ __forceinline__ u64 cld64(const void* p) {
    return __hip_atomic_load((const u64*)p, __ATOMIC_RELAXED, __HIP_MEMORY_SCOPE_AGENT);
}
__device__ __forceinline__ void cst64(void* p, u64 v) {
    __hip_atomic_store((u64*)p, v, __ATOMIC_RELAXED, __HIP_MEMORY_SCOPE_AGENT);
}
__device__ __forceinline__ unsigned cld32(const void* p) {
    return __hip_atomic_load((const unsigned*)p, __ATOMIC_RELAXED, __HIP_MEMORY_SCOPE_AGENT);
}
__device__ __forceinline__ void cst32(void* p, unsigned v) {
    __hip_atomic_store((unsigned*)p, v, __ATOMIC_RELAXED, __HIP_MEMORY_SCOPE_AGENT);
}
__device__ __forceinline__ s16x8 cld_frag(const unsigned short* p) {
    union { u64 q[2]; s16x8 v; } u;
    u.q[0] = cld64(p);
    u.q[1] = cld64(p + 4);
    return u.v;
}

// ---- wave-0-only flag wait (flags padded: id i at f[i*FPAD]) ----
__device__ __forceinline__ void waitflags(const unsigned* f, int n, unsigned ep)
{
    if (threadIdx.x < 64) {
#pragma unroll 1
        for (int i = threadIdx.x; i < n; i += 64)
            while (cld32(&f[(long)i * FPAD]) < ep)
                __builtin_amdgcn_s_sleep(8);
    }
    __syncthreads();
}

// ---- full-grid fence-free barrier (gru chains) ----
__device__ __forceinline__ void fbar(unsigned* flags, int nb, unsigned ep)
{
    __syncthreads();   // drains vmcnt per wave before s_barrier
    if (threadIdx.x == 0)
        cst32(&flags[(long)blockIdx.x * FPAD], ep);
    waitflags(flags, nb, ep);
}

// ---------------- generic MFMA GEMM (precompute only) ----------------
template<typename AT, bool OB>
__global__ __launch_bounds__(256)
void mfma_gemm(const AT* __restrict__ A, const int* __restrict__ idxA,
               const unsigned short* __restrict__ Wb, const float* __restrict__ bias,
               void* __restrict__ Cv,
               int M, int N, int K, int ldA, int Kpad, int ldC)
{
    __shared__ unsigned short As[64][40];
    __shared__ unsigned short Bs[64][40];
    const int tid = threadIdx.x;
    const int wv = tid >> 6, lane = tid & 63;
    const int wm = wv >> 1, wn = wv & 1;
    const int m0 = blockIdx.y * 64, n0 = blockIdx.x * 64;

    f32x4 acc[2][2] = {{{0.f,0.f,0.f,0.f},{0.f,0.f,0.f,0.f}},
                       {{0.f,0.f,0.f,0.f},{0.f,0.f,0.f,0.f}}};
    const int r_st = tid >> 2, k_st = (tid & 3) * 8;

    long arow = -1;
    {
        int gm = m0 + r_st;
        if (gm < M) arow = idxA ? (long)idxA[gm] : (long)gm;
    }

    const int kIters = (K + 31) / 32;
    for (int it = 0; it < kIters; ++it) {
        const int kg = it * 32 + k_st;
        {
            s16x8 pk = {0,0,0,0,0,0,0,0};
            if (arow >= 0) {
                if constexpr (sizeof(AT) == 2) {
                    if (kg + 8 <= K) {
                        pk = *(const s16x8*)((const unsigned short*)A + arow * (long)ldA + kg);
                    } else {
#pragma unroll
                        for (int j = 0; j < 8; ++j)
                            if (kg + j < K) pk[j] = (short)((const unsigned short*)A)[arow * (long)ldA + kg + j];
                    }
                } else {
                    if (kg + 8 <= K) {
                        const float* p = (const float*)A + arow * (long)ldA + kg;
                        f32x4 u0 = *(const f32x4*)p;
                        f32x4 u1 = *(const f32x4*)(p + 4);
#pragma unroll
                        for (int j = 0; j < 4; ++j) { pk[j] = (short)f2b(u0[j]); pk[4+j] = (short)f2b(u1[j]); }
                    } else {
#pragma unroll
                        for (int j = 0; j < 8; ++j) {
                            int kk = kg + j;
                            if (kk < K) pk[j] = (short)f2b(((const float*)A)[arow * (long)ldA + kk]);
                        }
                    }
                }
            }
            *(s16x8*)&As[r_st][k_st] = pk;
        }
        {
            int gn = n0 + r_st;
            s16x8 pk = {0,0,0,0,0,0,0,0};
            if (gn < N) pk = *(const s16x8*)&Wb[(long)gn * Kpad + kg];
            *(s16x8*)&Bs[r_st][k_st] = pk;
        }
        __syncthreads();
        {
            const int koff = (lane >> 4) * 8;
            s16x8 af[2], bfr[2];
#pragma unroll
            for (int f = 0; f < 2; ++f) {
                af[f]  = *(s16x8*)&As[wm * 32 + f * 16 + (lane & 15)][koff];
                bfr[f] = *(s16x8*)&Bs[wn * 32 + f * 16 + (lane & 15)][koff];
            }
#pragma unroll
            for (int fi = 0; fi < 2; ++fi)
#pragma unroll
                for (int fj = 0; fj < 2; ++fj)
                    acc[fi][fj] = mfma16(af[fi], bfr[fj], acc[fi][fj]);
        }
        __syncthreads();
    }
#pragma unroll
    for (int fi = 0; fi < 2; ++fi)
#pragma unroll
        for (int fj = 0; fj < 2; ++fj)
#pragma unroll
            for (int r = 0; r < 4; ++r) {
                int m = m0 + wm * 32 + fi * 16 + (lane >> 4) * 4 + r;
                int n = n0 + wn * 32 + fj * 16 + (lane & 15);
                if (m < M && n < N) {
                    float v = acc[fi][fj][r];
                    if (bias) v += bias[n];
                    if constexpr (OB) ((unsigned short*)Cv)[(long)m * ldC + n] = f2b(v);
                    else               ((float*)Cv)[(long)m * ldC + n] = v;
                }
            }
}

// ---------------- persistent GRU chain ----------------
#define GRU_NB 64
__global__ __launch_bounds__(256, 1)
void gru_chain(const unsigned short* __restrict__ Whh_b, const float* __restrict__ GI,
               const float* __restrict__ bhh, const int* __restrict__ toks,
               float* __restrict__ h32a, float* __restrict__ h32b,
               unsigned short* __restrict__ h16a, unsigned short* __restrict__ h16b,
               unsigned short* __restrict__ o_bt,
               unsigned* __restrict__ flags)
{
    __shared__ unsigned short wlds[3][16][512];   // 48 KB
    __shared__ unsigned short ht[64][20];         // transpose buffer
    const int tid = threadIdx.x;
    const int wv = tid >> 6, lane = tid & 63;
    const int dt = blockIdx.x & 31, bh = blockIdx.x >> 5;
    const int b0 = bh * 64;

    for (int s = 0; s < 12; ++s) {
        int slot = tid + s * 256;
        int g = slot >> 10, rem = slot & 1023, ks = rem >> 6, ln = rem & 63;
        int row = g * ND + dt * 16 + (ln & 15);
        int k = ks * 32 + (ln >> 4) * 8;
        *(s16x8*)&wlds[g][ks][ln * 8] = *(const s16x8*)&Whh_b[(long)row * ND + k];
    }
    __syncthreads();

    const int d = dt * 16 + (lane & 15);
    const int brow = b0 + wv * 16 + (lane >> 4) * 4;
    const int arow = b0 + wv * 16 + (lane & 15);
    const int akoff = (lane >> 4) * 8;

    float o_run[4] = {0.f, 0.f, 0.f, 0.f};
    unsigned ep = 0;

    for (int t = 0; t < T_SZ; ++t) {
        const unsigned short* hin16 = (t & 1) ? h16b : h16a;
        const float*          hin32 = (t & 1) ? h32b : h32a;
        float*          hout32 = (t & 1) ? h32a : h32b;
        unsigned short* hout16 = (t & 1) ? h16a : h16b;

        const float* git = GI + (long)t * (B_SZ * G3);
        float gi_r[4], gi_z[4], gi_n[4], hp[4]; int mk[4];
#pragma unroll
        for (int rr = 0; rr < 4; ++rr) {
            int b = brow + rr;
            gi_r[rr] = git[(long)b * G3 + d];
            gi_z[rr] = git[(long)b * G3 + ND + d];
            gi_n[rr] = git[(long)b * G3 + 2 * ND + d];
            hp[rr]   = hin32[(long)b * ND + d];
            mk[rr]   = toks[b * T_SZ + t];
        }

        f32x4 acc0 = {0,0,0,0}, acc1 = {0,0,0,0}, acc2 = {0,0,0,0};
#pragma unroll
        for (int ks = 0; ks < 16; ++ks) {
            s16x8 a  = cld_frag(&hin16[(long)arow * ND + ks * 32 + akoff]);
            s16x8 br = *(s16x8*)&wlds[0][ks][lane * 8];
            s16x8 bz = *(s16x8*)&wlds[1][ks][lane * 8];
            s16x8 bn = *(s16x8*)&wlds[2][ks][lane * 8];
            acc0 = mfma16(a, br, acc0);
            acc1 = mfma16(a, bz, acc1);
            acc2 = mfma16(a, bn, acc2);
        }

#pragma unroll
        for (int rr = 0; rr < 4; ++rr) {
            int b = brow + rr;
            float rg = fsigmoid(gi_r[rr] + acc0[rr] + bhh[d]);
            float zg = fsigmoid(gi_z[rr] + acc1[rr] + bhh[ND + d]);
            float ng = ftanh(gi_n[rr] + rg * (acc2[rr] + bhh[2 * ND + d]));
            float hr = (1.0f - zg) * ng + zg * hp[rr];
            bool m = mk[rr] != 0;
            float hn = m ? hr : hp[rr];
            hout32[(long)b * ND + d] = hn;              // block-private: normal
            ht[b - b0][lane & 15] = f2b(hn);
            o_run[rr] = (t == 0) ? hr : (m ? hr : o_run[rr]);
            o_bt[((long)b * T_SZ + t) * ND + d] = f2b(o_run[rr]);  // later launches: normal
        }
        __syncthreads();
        {
            int bl = tid & 63, dq = tid >> 6;
            u64 v = *(u64*)&ht[bl][dq * 4];
            cst64(&hout16[(long)(b0 + bl) * ND + dt * 16 + dq * 4], v);   // coherent
        }
        fbar(flags, GRU_NB, ++ep);
    }
}

// ---------------- persistent match chain: 256 blocks, role-split ----------------
__global__ __launch_bounds__(256, 1)
void match_chain(const unsigned short* __restrict__ WrT_b,
                 const unsigned short* __restrict__ Wbig,
                 const unsigned short* __restrict__ OHWh_bt,
                 const unsigned short* __restrict__ OHGI_bt,
                 const float* __restrict__ m_bhh, const float* __restrict__ Walpha,
                 const unsigned short* __restrict__ Yw_bb,
                 const unsigned short* __restrict__ Y_bb,
                 const int* __restrict__ prem, const int* __restrict__ hyp,
                 float* __restrict__ r32,
                 unsigned short* __restrict__ r16a, unsigned short* __restrict__ r16b,
                 unsigned short* __restrict__ a16,
                 unsigned* __restrict__ lflags, unsigned* __restrict__ uflags)
{
    __shared__ __align__(16) unsigned char smem[135744];
    const int tid = threadIdx.x;
    const int wv = tid >> 6, lane = tid & 63;

    if (blockIdx.x < 128) {
        // ================= LOW: attention for b = blockIdx.x =================
        const int b = blockIdx.x;
        unsigned short (*ywl)[ND] = (unsigned short(*)[ND])smem;             // 128 KB
        float* rrow = (float*)(smem + 131072);                               // 2 KB
        float* sarr = (float*)(smem + 131072 + 2048);                        // 2 KB
        float* lg   = (float*)(smem + 131072 + 4096);                        // 512 B
        float* red  = (float*)(smem + 131072 + 4608);

        for (int s = 0; s < 32; ++s) {
            int c = s * 256 + tid;
            *(s16x8*)&ywl[c >> 6][(c & 63) * 8] =
                *(const s16x8*)&Yw_bb[((long)b * T_SZ + (c >> 6)) * ND + (c & 63) * 8];
        }
        float wa[8];
#pragma unroll
        for (int j = 0; j < 8; ++j) wa[j] = Walpha[lane * 8 + j];
        __syncthreads();

        for (int t = 0; t < T_SZ; ++t) {
            waitflags(uflags, 128, (unsigned)t);   // UP peers finished step t-1
            const unsigned short* r16rd = (t & 1) ? r16b : r16a;

            // (a) r-row -> LDS f32
            if (tid < 64) {
                s16x8 rv = cld_frag(&r16rd[(long)b * ND + tid * 8]);
#pragma unroll
                for (int j = 0; j < 8; ++j) rrow[tid * 8 + j] = b2f((unsigned short)rv[j]);
            }
            __syncthreads();
            // s-GEMV: 2 cols per thread
            {
                int n0 = tid * 2;
                float s0 = 0.f, s1 = 0.f;
#pragma unroll 4
                for (int ks = 0; ks < 64; ++ks) {
                    s16x8 w0 = *(const s16x8*)&WrT_b[(long)n0 * ND + ks * 8];
                    s16x8 w1 = *(const s16x8*)&WrT_b[((long)n0 + 1) * ND + ks * 8];
#pragma unroll
                    for (int j = 0; j < 8; ++j) {
                        float rk = rrow[ks * 8 + j];
                        s0 += rk * b2f((unsigned short)w0[j]);
                        s1 += rk * b2f((unsigned short)w1[j]);
                    }
                }
                unsigned q = *(const unsigned*)&OHWh_bt[((long)b * T_SZ + t) * ND + n0];
                sarr[n0]     = s0 + b2f((unsigned short)(q & 0xffffu));
                sarr[n0 + 1] = s1 + b2f((unsigned short)(q >> 16));
            }
            __syncthreads();
            // (b) logits
            float sv[8];
#pragma unroll
            for (int j = 0; j < 8; ++j) sv[j] = sarr[lane * 8 + j];
            for (int i = 0; i < 32; ++i) {
                int tp = i * 4 + wv;
                s16x8 yw = *(s16x8*)&ywl[tp][lane * 8];
                float acc = 0.f;
#pragma unroll
                for (int j = 0; j < 8; ++j)
                    acc += ftanh(b2f((unsigned short)yw[j]) + sv[j]) * wa[j];
#pragma unroll
                for (int off = 32; off; off >>= 1) acc += __shfl_xor(acc, off);
                if (lane == 0) {
                    float mm = (prem[b * T_SZ + tp] != 0) ? 0.f : 1000.f;
                    lg[tp] = acc - mm;
                }
            }
            __syncthreads();
            if (tid < 64) {
                float v = fmaxf(lg[tid], lg[tid + 64]);
#pragma unroll
                for (int off = 32; off; off >>= 1) v = fmaxf(v, __shfl_xor(v, off));
                if (tid == 0) red[0] = v;
            }
            __syncthreads();
            float mx = red[0];
            if (tid < T_SZ) lg[tid] = __expf(lg[tid] - mx);
            __syncthreads();
            if (tid < 64) {
                float v = lg[tid] + lg[tid + 64];
#pragma unroll
                for (int off = 32; off; off >>= 1) v += __shfl_xor(v, off);
                if (tid == 0) red[1] = v;
            }
            __syncthreads();
            // (c) weighted sum over Y: tp-halves split across thread groups, 8-B loads
            float inv = 1.0f / red[1];
            int g = tid >> 7, lt = tid & 127, n4 = lt * 4;
            f32x4 acw = {0.f, 0.f, 0.f, 0.f};
#pragma unroll 8
            for (int i = 0; i < 64; ++i) {
                int tp = g * 64 + i;
                float al = lg[tp] * inv;
                u64 q = *(const u64*)&Y_bb[((long)b * T_SZ + tp) * ND + n4];
                acw[0] += al * b2f((unsigned short)q);
                acw[1] += al * b2f((unsigned short)(q >> 16));
                acw[2] += al * b2f((unsigned short)(q >> 32));
                acw[3] += al * b2f((unsigned short)(q >> 48));
            }
            if (g == 1) *(f32x4*)&sarr[n4] = acw;
            __syncthreads();
            if (g == 0) {
                f32x4 o = *(f32x4*)&sarr[n4];
                u64 pk = (u64)f2b(acw[0] + o[0]) | ((u64)f2b(acw[1] + o[1]) << 16)
                       | ((u64)f2b(acw[2] + o[2]) << 32) | ((u64)f2b(acw[3] + o[3]) << 48);
                cst64(&a16[(long)b * ND + n4], pk);
            }
            __syncthreads();
            if (tid == 0) cst32(&lflags[(long)b * FPAD], (unsigned)(t + 1));
        }
    } else {
        // ================= UP: gates + combine, 16 fam-rows per block =================
        const int ug = blockIdx.x - 128;
        unsigned short (*w3)[ND] = (unsigned short(*)[ND])smem;              // 32 KB
        float (*bounce)[17] = (float(*)[17])(smem + 32768);                  // 8.7 KB
        for (int s = 0; s < 8; ++s) {
            int slot = tid + s * 256;
            int ks = slot >> 6, ln = slot & 63;
            *(s16x8*)&w3[ks][ln * 8] =
                *(const s16x8*)&Wbig[(long)(ug * 16 + (ln & 15)) * 1024 + ks * 32 + (ln >> 4) * 8];
        }
        __syncthreads();
        const int akoff = (lane >> 4) * 8;
        const int ar = wv * 16 + (lane & 15);

        for (int t = 0; t < T_SZ; ++t) {
            // r16rd ready once UP peers finished t-1 -> r-part first (overlap with LOW)
            waitflags(uflags, 128, (unsigned)t);
            const unsigned short* r16rd = (t & 1) ? r16b : r16a;
            unsigned short*       r16wr = (t & 1) ? r16a : r16b;

            f32x4 accA = {0,0,0,0}, accB = {0,0,0,0};
#pragma unroll
            for (int ks = 0; ks < 16; ++ks) {
                s16x8 a = cld_frag(&r16rd[(long)ar * ND + ks * 32 + akoff]);
                accA = mfma16(a, *(s16x8*)&w3[16 + ks][lane * 8], accA);
            }
#pragma unroll
            for (int ks = 0; ks < 16; ++ks) {
                s16x8 a = cld_frag(&r16rd[(long)(64 + ar) * ND + ks * 32 + akoff]);
                accB = mfma16(a, *(s16x8*)&w3[16 + ks][lane * 8], accB);
            }
            // a-part needs LOW's step-t a16
            waitflags(lflags, 128, (unsigned)(t + 1));
#pragma unroll
            for (int ks = 0; ks < 16; ++ks) {
                s16x8 a = cld_frag(&a16[(long)ar * ND + ks * 32 + akoff]);
                accA = mfma16(a, *(s16x8*)&w3[ks][lane * 8], accA);
            }
#pragma unroll
            for (int ks = 0; ks < 16; ++ks) {
                s16x8 a = cld_frag(&a16[(long)(64 + ar) * ND + ks * 32 + akoff]);
                accB = mfma16(a, *(s16x8*)&w3[ks][lane * 8], accB);
            }
#pragma unroll
            for (int rr = 0; rr < 4; ++rr) {
                bounce[wv * 16 + (lane >> 4) * 4 + rr][lane & 15] = accA[rr];
                bounce[64 + wv * 16 + (lane >> 4) * 4 + rr][lane & 15] = accB[rr];
            }
            __syncthreads();
            if (tid < 128) {
                int b = tid;
                const unsigned short* og = OHGI_bt + ((long)b * T_SZ + t) * G3;
                u64 q0 = *(const u64*)&og[ug * 4];
                u64 q1 = *(const u64*)&og[512 + ug * 4];
                u64 q2 = *(const u64*)&og[1024 + ug * 4];
                f32x4 rp4 = *(const f32x4*)&r32[(long)b * ND + ug * 4];
                bool mkk = hyp[b * T_SZ + t] != 0;
                unsigned short o4[4];
#pragma unroll
                for (int dl = 0; dl < 4; ++dl) {
                    int dd = ug * 4 + dl;
                    float sr  = bounce[b][0 + dl]  + b2f((unsigned short)(q0 >> (16 * dl))) + m_bhh[dd];
                    float sz  = bounce[b][4 + dl]  + b2f((unsigned short)(q1 >> (16 * dl))) + m_bhh[ND + dd];
                    float gin = bounce[b][8 + dl]  + b2f((unsigned short)(q2 >> (16 * dl)));
                    float ghn = bounce[b][12 + dl] + m_bhh[2 * ND + dd];
                    float rg = fsigmoid(sr), zg = fsigmoid(sz);
                    float ng = ftanh(gin + rg * ghn);
                    float rn = (1.0f - zg) * ng + zg * rp4[dl];
                    float v = mkk ? rn : rp4[dl];
                    rp4[dl] = v;
                    o4[dl] = f2b(v);
                }
                *(f32x4*)&r32[(long)b * ND + ug * 4] = rp4;   // block-private: normal
                u64 q = (u64)o4[0] | ((u64)o4[1] << 16) | ((u64)o4[2] << 32) | ((u64)o4[3] << 48);
                cst64(&r16wr[(long)b * ND + ug * 4], q);      // coherent, double-buffered
            }
            __syncthreads();
            if (tid == 0) cst32(&uflags[(long)ug * FPAD], (unsigned)(t + 1));
        }
    }
}

// ---------------- prep / misc ----------------
__global__ void prep_idx(const int* __restrict__ prem, const int* __restrict__ hyp,
                         int* __restrict__ idx_p, int* __restrict__ idx_h)
{
    int i = blockIdx.x * blockDim.x + threadIdx.x;
    if (i < B_SZ * T_SZ) {
        int t = i / B_SZ, b = i % B_SZ;
        idx_p[i] = prem[b * T_SZ + t];
        idx_h[i] = hyp[b * T_SZ + t];
    }
}

__global__ void conv_w(const float* __restrict__ in, unsigned short* __restrict__ out,
                       int N, int K, int Kpad, int ldIn, int colOff)
{
    long i = (long)blockIdx.x * blockDim.x + threadIdx.x;
    if (i >= (long)N * Kpad) return;
    int n = (int)(i / Kpad), k = (int)(i % Kpad);
    float v = (k < K) ? in[(long)n * ldIn + k + colOff] : 0.0f;
    out[i] = f2b(v);
}

__global__ void conv_wT(const float* __restrict__ in, unsigned short* __restrict__ out,
                        int N, int K, int Kpad, int ldIn)
{
    long i = (long)blockIdx.x * blockDim.x + threadIdx.x;
    if (i >= (long)N * Kpad) return;
    int n = (int)(i / Kpad), k = (int)(i % Kpad);
    float v = (k < K) ? in[(long)k * ldIn + n] : 0.0f;
    out[i] = f2b(v);
}

// Wbig (2048 x 1024), rows fam-interleaved per UP block:
// row j = ug*16 + fam*4 + dl  represents (fam, d = ug*4+dl)
__global__ void conv_wbig(const float* __restrict__ mWih, const float* __restrict__ mWhh,
                          unsigned short* __restrict__ out)
{
    long i = (long)blockIdx.x * blockDim.x + threadIdx.x;
    if (i >= 2048L * 1024) return;
    int j = (int)(i >> 10), k = (int)(i & 1023);
    int ug = j >> 4, within = j & 15, fam = within >> 2, dl = within & 3;
    int d = ug * 4 + dl;
    float v = 0.0f;
    if (fam == 0)      v = (k < 512) ? mWih[(long)d * 1024 + k]          : mWhh[(long)d * 512 + (k - 512)];
    else if (fam == 1) v = (k < 512) ? mWih[(long)(512 + d) * 1024 + k]  : mWhh[(long)(512 + d) * 512 + (k - 512)];
    else if (fam == 2) v = (k < 512) ? mWih[(long)(1024 + d) * 1024 + k] : 0.0f;
    else               v = (k < 512) ? 0.0f : mWhh[(long)(1024 + d) * 512 + (k - 512)];
    out[i] = f2b(v);
}

__global__ void zero_kernel(float* __restrict__ p, int n)
{
    int i = blockIdx.x * blockDim.x + threadIdx.x;
    if (i < n) p[i] = 0.0f;
}

__global__ void final_logits(const float* __restrict__ r, const float* __restrict__ outW,
                             const float* __restrict__ outb, float* __restrict__ out)
{
    int b = blockIdx.x;
    int lane = threadIdx.x;
    float a0 = 0.0f, a1 = 0.0f, a2 = 0.0f;
    for (int k = lane; k < ND; k += 64) {
        float rv = r[(long)b * ND + k];
        a0 += rv * outW[0 * ND + k];
        a1 += rv * outW[1 * ND + k];
        a2 += rv * outW[2 * ND + k];
    }
#pragma unroll
    for (int off = 32; off; off >>= 1) {
        a0 += __shfl_down(a0, off);
        a1 += __shfl_down(a1, off);
        a2 += __shfl_down(a2, off);
    }
    if (lane == 0) {
        float l0 = a0 + outb[0], l1 = a1 + outb[1], l2 = a2 + outb[2];
        float mx = fmaxf(l0, fmaxf(l1, l2));
        float se = expf(l0 - mx) + expf(l1 - mx) + expf(l2 - mx);
        float ls = mx + logf(se);
        out[b * 3 + 0] = l0 - ls;
        out[b * 3 + 1] = l1 - ls;
        out[b * 3 + 2] = l2 - ls;
    }
}

// ---------------- host ----------------
extern "C" void kernel_launch(void* const* d_in, const int* in_sizes, int n_in,
                              void* d_out, int out_size, void* d_ws, size_t ws_size,
                              hipStream_t stream)
{
    const int*   prem    = (const int*)d_in[0];
    const int*   hyp     = (const int*)d_in[1];
    const float* E       = (const float*)d_in[2];
    const float* p_Wih   = (const float*)d_in[3];
    const float* p_Whh   = (const float*)d_in[4];
    const float* p_bih   = (const float*)d_in[5];
    const float* p_bhh   = (const float*)d_in[6];
    const float* h_Wih   = (const float*)d_in[7];
    const float* h_Whh   = (const float*)d_in[8];
    const float* h_bih   = (const float*)d_in[9];
    const float* h_bhh   = (const float*)d_in[10];
    const float* m_Wih   = (const float*)d_in[11];
    const float* m_Whh   = (const float*)d_in[12];
    const float* m_bih   = (const float*)d_in[13];
    const float* m_bhh   = (const float*)d_in[14];
    const float* W_y     = (const float*)d_in[15];
    const float* W_h     = (const float*)d_in[16];
    const float* W_r     = (const float*)d_in[17];
    const float* W_alpha = (const float*)d_in[18];
    const float* out_W   = (const float*)d_in[19];
    const float* out_b   = (const float*)d_in[20];
    float* out = (float*)d_out;

    const int MB = T_SZ * B_SZ;  // 16384
    const int NFLAGS = 384 * FPAD;  // padded flag words

    float* ws = (float*)d_ws;
    size_t off = 0;
    float* GI    = ws + off; off += (size_t)MB * G3;       // fp32, both GRU phases
    float* h32a  = ws + off; off += (size_t)B_SZ * ND;
    float* h32b  = ws + off; off += (size_t)B_SZ * ND;
    float* r32   = ws + off; off += (size_t)B_SZ * ND;
    unsigned* flags = (unsigned*)(ws + off); off += NFLAGS;
    int* idx_p = (int*)(ws + off); off += (size_t)B_SZ * T_SZ;
    int* idx_h = (int*)(ws + off); off += (size_t)B_SZ * T_SZ;
    unsigned short* ub = (unsigned short*)(ws + off);
    size_t uoff = 0;
    unsigned short* o_p_bt = ub + uoff; uoff += (size_t)MB * ND;   // Y_bb
    unsigned short* o_h_bt = ub + uoff; uoff += (size_t)MB * ND;
    unsigned short* Yw_bb  = ub + uoff; uoff += (size_t)MB * ND;
    unsigned short* OHWh_bt= ub + uoff; uoff += (size_t)MB * ND;
    unsigned short* OHGI_bt= ub + uoff; uoff += (size_t)MB * G3;
    unsigned short* h16a   = ub + uoff; uoff += (size_t)B_SZ * ND;
    unsigned short* h16b   = ub + uoff; uoff += (size_t)B_SZ * ND;
    unsigned short* r16a   = ub + uoff; uoff += (size_t)B_SZ * ND;
    unsigned short* r16b   = ub + uoff; uoff += (size_t)B_SZ * ND;
    unsigned short* a16    = ub + uoff; uoff += (size_t)B_SZ * ND;
    unsigned short* pWih_b = ub + uoff; uoff += (size_t)G3 * 320;
    unsigned short* hWih_b = ub + uoff; uoff += (size_t)G3 * 320;
    unsigned short* pWhh_b = ub + uoff; uoff += (size_t)G3 * ND;
    unsigned short* hWhh_b = ub + uoff; uoff += (size_t)G3 * ND;
    unsigned short* mWihR  = ub + uoff; uoff += (size_t)G3 * ND;
    unsigned short* WyT_b  = ub + uoff; uoff += (size_t)ND * ND;
    unsigned short* WhT_b  = ub + uoff; uoff += (size_t)ND * ND;
    unsigned short* WrT_b  = ub + uoff; uoff += (size_t)ND * ND;
    unsigned short* Wbig   = ub + uoff; uoff += (size_t)2048 * 1024;
    off += (uoff + 1) / 2;
    if (ws_size < off * sizeof(float)) return;

    auto cblk = [](long n) { return (int)((n + 255) / 256); };

    // ---- prep ----
    prep_idx<<<cblk(MB), 256, 0, stream>>>(prem, hyp, idx_p, idx_h);
    conv_w <<<cblk((long)G3 * 320), 256, 0, stream>>>(p_Wih, pWih_b, G3, EMBD, 320, EMBD, 0);
    conv_w <<<cblk((long)G3 * 320), 256, 0, stream>>>(h_Wih, hWih_b, G3, EMBD, 320, EMBD, 0);
    conv_w <<<cblk((long)G3 * ND), 256, 0, stream>>>(p_Whh, pWhh_b, G3, ND, ND, ND, 0);
    conv_w <<<cblk((long)G3 * ND), 256, 0, stream>>>(h_Whh, hWhh_b, G3, ND, ND, ND, 0);
    conv_w <<<cblk((long)G3 * ND), 256, 0, stream>>>(m_Wih, mWihR, G3, ND, ND, 2 * ND, ND);
    conv_wT<<<cblk((long)ND * ND), 256, 0, stream>>>(W_y, WyT_b, ND, ND, ND, ND);
    conv_wT<<<cblk((long)ND * ND), 256, 0, stream>>>(W_h, WhT_b, ND, ND, ND, ND);
    conv_wT<<<cblk((long)ND * ND), 256, 0, stream>>>(W_r, WrT_b, ND, ND, ND, ND);
    conv_wbig<<<cblk(2048L * 1024), 256, 0, stream>>>(m_Wih, m_Whh, Wbig);
    zero_kernel<<<cblk(B_SZ * ND), 256, 0, stream>>>(h32a, B_SZ * ND);
    zero_kernel<<<cblk(B_SZ * ND / 2), 256, 0, stream>>>((float*)h16a, B_SZ * ND / 2);
    zero_kernel<<<cblk(B_SZ * ND), 256, 0, stream>>>(r32, B_SZ * ND);
    zero_kernel<<<cblk(B_SZ * ND / 2), 256, 0, stream>>>((float*)r16a, B_SZ * ND / 2);
    zero_kernel<<<cblk(B_SZ * ND / 2), 256, 0, stream>>>((float*)r16b, B_SZ * ND / 2);
    zero_kernel<<<cblk(NFLAGS), 256, 0, stream>>>((float*)flags, NFLAGS);

    // ---- premise ----
    {
        dim3 g(G3 / 64, MB / 64);
        mfma_gemm<float, false><<<g, 256, 0, stream>>>(E, idx_p, pWih_b, p_bih, GI,
                                                       MB, G3, EMBD, EMBD, 320, G3);
    }
    gru_chain<<<GRU_NB, 256, 0, stream>>>(pWhh_b, GI, p_bhh, prem, h32a, h32b, h16a, h16b,
                                          o_p_bt, &flags[0]);

    // ---- hypothesis ----
    {
        dim3 g(G3 / 64, MB / 64);
        mfma_gemm<float, false><<<g, 256, 0, stream>>>(E, idx_h, hWih_b, h_bih, GI,
                                                       MB, G3, EMBD, EMBD, 320, G3);
    }
    gru_chain<<<GRU_NB, 256, 0, stream>>>(hWhh_b, GI, h_bhh, hyp, h32a, h32b, h16a, h16b,
                                          o_h_bt, &flags[64 * FPAD]);

    // ---- attention precompute (all [b][t]-row GEMMs, bf16 outputs) ----
    {
        dim3 g(ND / 64, MB / 64);
        mfma_gemm<unsigned short, true><<<g, 256, 0, stream>>>(o_p_bt, nullptr, WyT_b, nullptr,
                                                               Yw_bb, MB, ND, ND, ND, ND, ND);
        mfma_gemm<unsigned short, true><<<g, 256, 0, stream>>>(o_h_bt, nullptr, WhT_b, nullptr,
                                                               OHWh_bt, MB, ND, ND, ND, ND, ND);
        dim3 g2(G3 / 64, MB / 64);
        mfma_gemm<unsigned short, true><<<g2, 256, 0, stream>>>(o_h_bt, nullptr, mWihR, m_bih,
                                                                OHGI_bt, MB, G3, ND, ND, ND, G3);
    }

    // ---- match chain (256 blocks, role-split, padded flags, wave-0 polling) ----
    match_chain<<<256, 256, 0, stream>>>(WrT_b, Wbig, OHWh_bt, OHGI_bt, m_bhh, W_alpha,
                                         Yw_bb, o_p_bt, prem, hyp, r32, r16a, r16b, a16,
                                         &flags[128 * FPAD], &flags[256 * FPAD]);

    final_logits<<<B_SZ, 64, 0, stream>>>(r32, out_W, out_b, out);
}

// Round 9
// 8298.165 us; speedup vs baseline: 2.0321x; 1.0717x over previous
//
#include <hip/hip_runtime.h>
#include <math.h>

#define B_SZ 128
#define T_SZ 128
#define EMBD 300
#define ND 512
#define G3 1536
#define FPAD 32   // flag padding stride (u32s) = 128 B

typedef short s16x8 __attribute__((ext_vector_type(8)));
typedef float f32x4 __attribute__((ext_vector_type(4)));
typedef unsigned long long u64;

__device__ __forceinline__ unsigned short f2b(float x) {
    unsigned u = __float_as_uint(x);
    unsigned r = (u + 0x7fff + ((u >> 16) & 1)) >> 16;  // RNE
    return (unsigned short)r;
}
__device__ __forceinline__ float b2f(unsigned short v) {
    return __uint_as_float(((unsigned)v) << 16);
}
__device__ __forceinline__ float fsigmoid(float x) { return 1.0f / (1.0f + __expf(-x)); }
__device__ __forceinline__ float ftanh(float x) { return 1.0f - 2.0f / (__expf(2.0f * x) + 1.0f); }

__device__ __forceinline__ f32x4 mfma16(s16x8 a, s16x8 b, f32x4 c) {
    return __builtin_amdgcn_mfma_f32_16x16x32_bf16(a, b, c, 0, 0, 0);
}

// ---- coherent (LLC-point, fence-free) access helpers ----
__device__ __forceinline__ u64 cld64(const void* p) {
    return __hip_atomic_load((const u64*)p, __ATOMIC_RELAXED, __HIP_MEMORY_SCOPE_AGENT);
}
__device__ __forceinline__ void cst64(void* p, u64 v) {
    __hip_atomic_store((u64*)p, v, __ATOMIC_RELAXED, __HIP_MEMORY_SCOPE_AGENT);
}
__device__ __forceinline__ unsigned cld32(const void* p) {
    return __hip_atomic_load((const unsigned*)p, __ATOMIC_RELAXED, __HIP_MEMORY_SCOPE_AGENT);
}
__device__ __forceinline__ void cst32(void* p, unsigned v) {
    __hip_atomic_store((unsigned*)p, v, __ATOMIC_RELAXED, __HIP_MEMORY_SCOPE_AGENT);
}
__device__ __forceinline__ s16x8 cld_frag(const unsigned short* p) {
    union { u64 q[2]; s16x8 v; } u;
    u.q[0] = cld64(p);
    u.q[1] = cld64(p + 4);
    return u.v;
}

// ---- wave-0-only flag wait (flags padded: id i at f[i*FPAD]) ----
__device__ __forceinline__ void waitflags(const unsigned* f, int n, unsigned ep)
{
    if (threadIdx.x < 64) {
#pragma unroll 1
        for (int i = threadIdx.x; i < n; i += 64)
            while (cld32(&f[(long)i * FPAD]) < ep)
                __builtin_amdgcn_s_sleep(8);
    }
    __syncthreads();
}

// ---- full-grid fence-free barrier (gru chains) ----
__device__ __forceinline__ void fbar(unsigned* flags, int nb, unsigned ep)
{
    __syncthreads();   // drains vmcnt per wave before s_barrier
    if (threadIdx.x == 0)
        cst32(&flags[(long)blockIdx.x * FPAD], ep);
    waitflags(flags, nb, ep);
}

// ---------------- generic MFMA GEMM (precompute only) ----------------
template<typename AT, bool OB>
__global__ __launch_bounds__(256)
void mfma_gemm(const AT* __restrict__ A, const int* __restrict__ idxA,
               const unsigned short* __restrict__ Wb, const float* __restrict__ bias,
               void* __restrict__ Cv,
               int M, int N, int K, int ldA, int Kpad, int ldC)
{
    __shared__ unsigned short As[64][40];
    __shared__ unsigned short Bs[64][40];
    const int tid = threadIdx.x;
    const int wv = tid >> 6, lane = tid & 63;
    const int wm = wv >> 1, wn = wv & 1;
    const int m0 = blockIdx.y * 64, n0 = blockIdx.x * 64;

    f32x4 acc[2][2] = {{{0.f,0.f,0.f,0.f},{0.f,0.f,0.f,0.f}},
                       {{0.f,0.f,0.f,0.f},{0.f,0.f,0.f,0.f}}};
    const int r_st = tid >> 2, k_st = (tid & 3) * 8;

    long arow = -1;
    {
        int gm = m0 + r_st;
        if (gm < M) arow = idxA ? (long)idxA[gm] : (long)gm;
    }

    const int kIters = (K + 31) / 32;
    for (int it = 0; it < kIters; ++it) {
        const int kg = it * 32 + k_st;
        {
            s16x8 pk = {0,0,0,0,0,0,0,0};
            if (arow >= 0) {
                if constexpr (sizeof(AT) == 2) {
                    if (kg + 8 <= K) {
                        pk = *(const s16x8*)((const unsigned short*)A + arow * (long)ldA + kg);
                    } else {
#pragma unroll
                        for (int j = 0; j < 8; ++j)
                            if (kg + j < K) pk[j] = (short)((const unsigned short*)A)[arow * (long)ldA + kg + j];
                    }
                } else {
                    if (kg + 8 <= K) {
                        const float* p = (const float*)A + arow * (long)ldA + kg;
                        f32x4 u0 = *(const f32x4*)p;
                        f32x4 u1 = *(const f32x4*)(p + 4);
#pragma unroll
                        for (int j = 0; j < 4; ++j) { pk[j] = (short)f2b(u0[j]); pk[4+j] = (short)f2b(u1[j]); }
                    } else {
#pragma unroll
                        for (int j = 0; j < 8; ++j) {
                            int kk = kg + j;
                            if (kk < K) pk[j] = (short)f2b(((const float*)A)[arow * (long)ldA + kk]);
                        }
                    }
                }
            }
            *(s16x8*)&As[r_st][k_st] = pk;
        }
        {
            int gn = n0 + r_st;
            s16x8 pk = {0,0,0,0,0,0,0,0};
            if (gn < N) pk = *(const s16x8*)&Wb[(long)gn * Kpad + kg];
            *(s16x8*)&Bs[r_st][k_st] = pk;
        }
        __syncthreads();
        {
            const int koff = (lane >> 4) * 8;
            s16x8 af[2], bfr[2];
#pragma unroll
            for (int f = 0; f < 2; ++f) {
                af[f]  = *(s16x8*)&As[wm * 32 + f * 16 + (lane & 15)][koff];
                bfr[f] = *(s16x8*)&Bs[wn * 32 + f * 16 + (lane & 15)][koff];
            }
#pragma unroll
            for (int fi = 0; fi < 2; ++fi)
#pragma unroll
                for (int fj = 0; fj < 2; ++fj)
                    acc[fi][fj] = mfma16(af[fi], bfr[fj], acc[fi][fj]);
        }
        __syncthreads();
    }
#pragma unroll
    for (int fi = 0; fi < 2; ++fi)
#pragma unroll
        for (int fj = 0; fj < 2; ++fj)
#pragma unroll
            for (int r = 0; r < 4; ++r) {
                int m = m0 + wm * 32 + fi * 16 + (lane >> 4) * 4 + r;
                int n = n0 + wn * 32 + fj * 16 + (lane & 15);
                if (m < M && n < N) {
                    float v = acc[fi][fj][r];
                    if (bias) v += bias[n];
                    if constexpr (OB) ((unsigned short*)Cv)[(long)m * ldC + n] = f2b(v);
                    else               ((float*)Cv)[(long)m * ldC + n] = v;
                }
            }
}

// ---------------- persistent GRU chain ----------------
#define GRU_NB 64
__global__ __launch_bounds__(256, 1)
void gru_chain(const unsigned short* __restrict__ Whh_b, const float* __restrict__ GI,
               const float* __restrict__ bhh, const int* __restrict__ toks,
               float* __restrict__ h32a, float* __restrict__ h32b,
               unsigned short* __restrict__ h16a, unsigned short* __restrict__ h16b,
               unsigned short* __restrict__ o_bt,
               unsigned* __restrict__ flags)
{
    __shared__ unsigned short wlds[3][16][512];   // 48 KB
    __shared__ unsigned short ht[64][20];         // transpose buffer
    const int tid = threadIdx.x;
    const int wv = tid >> 6, lane = tid & 63;
    const int dt = blockIdx.x & 31, bh = blockIdx.x >> 5;
    const int b0 = bh * 64;

    for (int s = 0; s < 12; ++s) {
        int slot = tid + s * 256;
        int g = slot >> 10, rem = slot & 1023, ks = rem >> 6, ln = rem & 63;
        int row = g * ND + dt * 16 + (ln & 15);
        int k = ks * 32 + (ln >> 4) * 8;
        *(s16x8*)&wlds[g][ks][ln * 8] = *(const s16x8*)&Whh_b[(long)row * ND + k];
    }
    __syncthreads();

    const int d = dt * 16 + (lane & 15);
    const int brow = b0 + wv * 16 + (lane >> 4) * 4;
    const int arow = b0 + wv * 16 + (lane & 15);
    const int akoff = (lane >> 4) * 8;

    float o_run[4] = {0.f, 0.f, 0.f, 0.f};
    unsigned ep = 0;

    for (int t = 0; t < T_SZ; ++t) {
        const unsigned short* hin16 = (t & 1) ? h16b : h16a;
        const float*          hin32 = (t & 1) ? h32b : h32a;
        float*          hout32 = (t & 1) ? h32a : h32b;
        unsigned short* hout16 = (t & 1) ? h16a : h16b;

        const float* git = GI + (long)t * (B_SZ * G3);
        float gi_r[4], gi_z[4], gi_n[4], hp[4]; int mk[4];
#pragma unroll
        for (int rr = 0; rr < 4; ++rr) {
            int b = brow + rr;
            gi_r[rr] = git[(long)b * G3 + d];
            gi_z[rr] = git[(long)b * G3 + ND + d];
            gi_n[rr] = git[(long)b * G3 + 2 * ND + d];
            hp[rr]   = hin32[(long)b * ND + d];
            mk[rr]   = toks[b * T_SZ + t];
        }

        f32x4 acc0 = {0,0,0,0}, acc1 = {0,0,0,0}, acc2 = {0,0,0,0};
#pragma unroll
        for (int ks = 0; ks < 16; ++ks) {
            s16x8 a  = cld_frag(&hin16[(long)arow * ND + ks * 32 + akoff]);
            s16x8 br = *(s16x8*)&wlds[0][ks][lane * 8];
            s16x8 bz = *(s16x8*)&wlds[1][ks][lane * 8];
            s16x8 bn = *(s16x8*)&wlds[2][ks][lane * 8];
            acc0 = mfma16(a, br, acc0);
            acc1 = mfma16(a, bz, acc1);
            acc2 = mfma16(a, bn, acc2);
        }

#pragma unroll
        for (int rr = 0; rr < 4; ++rr) {
            int b = brow + rr;
            float rg = fsigmoid(gi_r[rr] + acc0[rr] + bhh[d]);
            float zg = fsigmoid(gi_z[rr] + acc1[rr] + bhh[ND + d]);
            float ng = ftanh(gi_n[rr] + rg * (acc2[rr] + bhh[2 * ND + d]));
            float hr = (1.0f - zg) * ng + zg * hp[rr];
            bool m = mk[rr] != 0;
            float hn = m ? hr : hp[rr];
            hout32[(long)b * ND + d] = hn;              // block-private: normal
            ht[b - b0][lane & 15] = f2b(hn);
            o_run[rr] = (t == 0) ? hr : (m ? hr : o_run[rr]);
            o_bt[((long)b * T_SZ + t) * ND + d] = f2b(o_run[rr]);  // later launches: normal
        }
        __syncthreads();
        {
            int bl = tid & 63, dq = tid >> 6;
            u64 v = *(u64*)&ht[bl][dq * 4];
            cst64(&hout16[(long)(b0 + bl) * ND + dt * 16 + dq * 4], v);   // coherent
        }
        fbar(flags, GRU_NB, ++ep);
    }
}

// ---------------- persistent match chain: 160 blocks, role-split ----------------
// LOW (0..127):  b = blk. LDS-resident Yw[b]. Per step: wait sflags -> read s16[b]
//                -> logits+softmax+wsum -> a16, lflag.
// UP (128..159): ug = blk-128, owns d = ug*16..+16. Per step: wait uflags(peers) ->
//                r-phase {SR,SZ,GHN,S} over r16 -> s16=S+OHWh, sflag ->
//                wait lflags -> a-phase {SR,SZ,GIN} over a16 -> combine -> r16, uflag.
#define UP_NB 32
__global__ __launch_bounds__(256, 1)
void match_chain(const unsigned short* __restrict__ WrT_b,
                 const unsigned short* __restrict__ mWihL_b,
                 const unsigned short* __restrict__ mWhh_b,
                 const unsigned short* __restrict__ OHWh_bt,
                 const unsigned short* __restrict__ OHGI_bt,
                 const float* __restrict__ m_bhh, const float* __restrict__ Walpha,
                 const unsigned short* __restrict__ Yw_bb,
                 const unsigned short* __restrict__ Y_bb,
                 const int* __restrict__ prem, const int* __restrict__ hyp,
                 float* __restrict__ r32,
                 unsigned short* __restrict__ r16a, unsigned short* __restrict__ r16b,
                 unsigned short* __restrict__ a16, unsigned short* __restrict__ s16,
                 unsigned* __restrict__ lflags, unsigned* __restrict__ uflags,
                 unsigned* __restrict__ sflags)
{
    __shared__ __align__(16) unsigned char smem[157696];
    const int tid = threadIdx.x;
    const int wv = tid >> 6, lane = tid & 63;

    if (blockIdx.x < 128) {
        // ================= LOW: attention for b = blockIdx.x =================
        const int b = blockIdx.x;
        unsigned short (*ywl)[ND] = (unsigned short(*)[ND])smem;             // 128 KB
        float* lg  = (float*)(smem + 131072);                                // 512 B
        float* red = (float*)(smem + 131072 + 512);
        float* sr2 = (float*)(smem + 131072 + 1024);                         // 2 KB wsum partials

        for (int s = 0; s < 32; ++s) {
            int c = s * 256 + tid;
            *(s16x8*)&ywl[c >> 6][(c & 63) * 8] =
                *(const s16x8*)&Yw_bb[((long)b * T_SZ + (c >> 6)) * ND + (c & 63) * 8];
        }
        float wa[8];
#pragma unroll
        for (int j = 0; j < 8; ++j) wa[j] = Walpha[lane * 8 + j];
        __syncthreads();

        for (int t = 0; t < T_SZ; ++t) {
            waitflags(sflags, UP_NB, (unsigned)(t + 1));   // s for step t ready
            // read s row (coherent)
            float sv[8];
            {
                s16x8 q = cld_frag(&s16[(long)b * ND + lane * 8]);
#pragma unroll
                for (int j = 0; j < 8; ++j) sv[j] = b2f((unsigned short)q[j]);
            }
            // logits
            for (int i = 0; i < 32; ++i) {
                int tp = i * 4 + wv;
                s16x8 yw = *(s16x8*)&ywl[tp][lane * 8];
                float acc = 0.f;
#pragma unroll
                for (int j = 0; j < 8; ++j)
                    acc += ftanh(b2f((unsigned short)yw[j]) + sv[j]) * wa[j];
#pragma unroll
                for (int off = 32; off; off >>= 1) acc += __shfl_xor(acc, off);
                if (lane == 0) {
                    float mm = (prem[b * T_SZ + tp] != 0) ? 0.f : 1000.f;
                    lg[tp] = acc - mm;
                }
            }
            __syncthreads();
            if (tid < 64) {
                float v = fmaxf(lg[tid], lg[tid + 64]);
#pragma unroll
                for (int off = 32; off; off >>= 1) v = fmaxf(v, __shfl_xor(v, off));
                if (tid == 0) red[0] = v;
            }
            __syncthreads();
            float mx = red[0];
            if (tid < T_SZ) lg[tid] = __expf(lg[tid] - mx);
            __syncthreads();
            if (tid < 64) {
                float v = lg[tid] + lg[tid + 64];
#pragma unroll
                for (int off = 32; off; off >>= 1) v += __shfl_xor(v, off);
                if (tid == 0) red[1] = v;
            }
            __syncthreads();
            // weighted sum over Y (normal cached), tp split in halves
            float inv = 1.0f / red[1];
            int g = tid >> 7, lt = tid & 127, n4 = lt * 4;
            f32x4 acw = {0.f, 0.f, 0.f, 0.f};
#pragma unroll 8
            for (int i = 0; i < 64; ++i) {
                int tp = g * 64 + i;
                float al = lg[tp] * inv;
                u64 q = *(const u64*)&Y_bb[((long)b * T_SZ + tp) * ND + n4];
                acw[0] += al * b2f((unsigned short)q);
                acw[1] += al * b2f((unsigned short)(q >> 16));
                acw[2] += al * b2f((unsigned short)(q >> 32));
                acw[3] += al * b2f((unsigned short)(q >> 48));
            }
            if (g == 1) *(f32x4*)&sr2[n4] = acw;
            __syncthreads();
            if (g == 0) {
                f32x4 o = *(f32x4*)&sr2[n4];
                u64 pk = (u64)f2b(acw[0] + o[0]) | ((u64)f2b(acw[1] + o[1]) << 16)
                       | ((u64)f2b(acw[2] + o[2]) << 32) | ((u64)f2b(acw[3] + o[3]) << 48);
                cst64(&a16[(long)b * ND + n4], pk);
            }
            __syncthreads();
            if (tid == 0) cst32(&lflags[(long)b * FPAD], (unsigned)(t + 1));
        }
    } else {
        // ================= UP: gates + s + combine; d-slice ug*16..+16 =================
        const int ug = blockIdx.x - 128;
        unsigned short (*wA)[16][512] = (unsigned short(*)[16][512])smem;           // 48 KB {SR_a,SZ_a,GIN}
        unsigned short (*wR)[16][512] = (unsigned short(*)[16][512])(smem + 49152); // 64 KB {SR_r,SZ_r,GHN,S}
        float (*bounce)[84] = (float(*)[84])(smem + 49152 + 65536);                 // 43 KB

        for (int s = 0; s < 12; ++s) {
            int slot = tid + s * 256;
            int fam = slot >> 10, rem = slot & 1023, ks = rem >> 6, ln = rem & 63;
            int row = fam * ND + ug * 16 + (ln & 15);
            int k = ks * 32 + (ln >> 4) * 8;
            *(s16x8*)&wA[fam][ks][ln * 8] = *(const s16x8*)&mWihL_b[(long)row * ND + k];
        }
        for (int s = 0; s < 16; ++s) {
            int slot = tid + s * 256;
            int fam = slot >> 10, rem = slot & 1023, ks = rem >> 6, ln = rem & 63;
            int k = ks * 32 + (ln >> 4) * 8;
            const unsigned short* src = (fam < 3)
                ? &mWhh_b[(long)(fam * ND + ug * 16 + (ln & 15)) * ND + k]
                : &WrT_b[(long)(ug * 16 + (ln & 15)) * ND + k];
            *(s16x8*)&wR[fam][ks][ln * 8] = *(const s16x8*)src;
        }
        __syncthreads();

        const int akoff = (lane >> 4) * 8;
        const int cb = tid >> 1;                 // combine: b
        const int half = tid & 1;
        const int d0 = ug * 16 + half * 8;       // combine: first of 8 d's

        for (int t = 0; t < T_SZ; ++t) {
            waitflags(uflags, UP_NB, (unsigned)t);
            const unsigned short* r16rd = (t & 1) ? r16b : r16a;
            unsigned short*       r16wr = (t & 1) ? r16a : r16b;

            // ---- r-phase: {SR,SZ,GHN,S} over full r rows ----
            f32x4 aSR[2] = {{0,0,0,0},{0,0,0,0}}, aSZ[2] = {{0,0,0,0},{0,0,0,0}};
            f32x4 aHN[2] = {{0,0,0,0},{0,0,0,0}}, aS[2]  = {{0,0,0,0},{0,0,0,0}};
            f32x4 aGN[2] = {{0,0,0,0},{0,0,0,0}};
#pragma unroll
            for (int f = 0; f < 2; ++f) {
                int row = wv * 32 + f * 16 + (lane & 15);
#pragma unroll
                for (int ks = 0; ks < 16; ++ks) {
                    s16x8 a = cld_frag(&r16rd[(long)row * ND + ks * 32 + akoff]);
                    aSR[f] = mfma16(a, *(s16x8*)&wR[0][ks][lane * 8], aSR[f]);
                    aSZ[f] = mfma16(a, *(s16x8*)&wR[1][ks][lane * 8], aSZ[f]);
                    aHN[f] = mfma16(a, *(s16x8*)&wR[2][ks][lane * 8], aHN[f]);
                    aS[f]  = mfma16(a, *(s16x8*)&wR[3][ks][lane * 8], aS[f]);
                }
            }
            // s-part -> bounce cols 64..79
#pragma unroll
            for (int f = 0; f < 2; ++f)
#pragma unroll
                for (int rr = 0; rr < 4; ++rr)
                    bounce[wv * 32 + f * 16 + (lane >> 4) * 4 + rr][64 + (lane & 15)] = aS[f][rr];
            __syncthreads();
            {
                // s16 = S + OHWh (8 d's per thread)
                u64 qo = *(const u64*)&OHWh_bt[((long)cb * T_SZ + t) * ND + d0];
                unsigned short o8[8];
#pragma unroll
                for (int j = 0; j < 8; ++j) {
                    float v = bounce[cb][64 + half * 8 + j] + b2f((unsigned short)(qo >> (16 * (j & 3)) >> (32 * (j >> 2) * 0)));
                    o8[j] = 0; (void)v;
                }
                // NOTE: OHWh is 8 bf16 = 16 bytes -> two u64 loads
                u64 qa = *(const u64*)&OHWh_bt[((long)cb * T_SZ + t) * ND + d0];
                u64 qb = *(const u64*)&OHWh_bt[((long)cb * T_SZ + t) * ND + d0 + 4];
                u64 w0 = 0, w1 = 0;
#pragma unroll
                for (int j = 0; j < 4; ++j) {
                    float v0 = bounce[cb][64 + half * 8 + j]     + b2f((unsigned short)(qa >> (16 * j)));
                    float v1 = bounce[cb][64 + half * 8 + 4 + j] + b2f((unsigned short)(qb >> (16 * j)));
                    w0 |= (u64)f2b(v0) << (16 * j);
                    w1 |= (u64)f2b(v1) << (16 * j);
                }
                cst64(&s16[(long)cb * ND + d0], w0);
                cst64(&s16[(long)cb * ND + d0 + 4], w1);
            }
            __syncthreads();
            if (tid == 0) cst32(&sflags[(long)ug * FPAD], (unsigned)(t + 1));

            // ---- a-phase: {SR,SZ,GIN} over full a rows ----
            waitflags(lflags, 128, (unsigned)(t + 1));
#pragma unroll
            for (int f = 0; f < 2; ++f) {
                int row = wv * 32 + f * 16 + (lane & 15);
#pragma unroll
                for (int ks = 0; ks < 16; ++ks) {
                    s16x8 a = cld_frag(&a16[(long)row * ND + ks * 32 + akoff]);
                    aSR[f] = mfma16(a, *(s16x8*)&wA[0][ks][lane * 8], aSR[f]);
                    aSZ[f] = mfma16(a, *(s16x8*)&wA[1][ks][lane * 8], aSZ[f]);
                    aGN[f] = mfma16(a, *(s16x8*)&wA[2][ks][lane * 8], aGN[f]);
                }
            }
#pragma unroll
            for (int f = 0; f < 2; ++f)
#pragma unroll
                for (int rr = 0; rr < 4; ++rr) {
                    int bb = wv * 32 + f * 16 + (lane >> 4) * 4 + rr;
                    bounce[bb][0  + (lane & 15)] = aSR[f][rr];
                    bounce[bb][16 + (lane & 15)] = aSZ[f][rr];
                    bounce[bb][32 + (lane & 15)] = aGN[f][rr];
                    bounce[bb][48 + (lane & 15)] = aHN[f][rr];
                }
            __syncthreads();
            {
                const unsigned short* og = OHGI_bt + ((long)cb * T_SZ + t) * G3;
                u64 q0a = *(const u64*)&og[d0];            u64 q0b = *(const u64*)&og[d0 + 4];
                u64 q1a = *(const u64*)&og[ND + d0];       u64 q1b = *(const u64*)&og[ND + d0 + 4];
                u64 q2a = *(const u64*)&og[2 * ND + d0];   u64 q2b = *(const u64*)&og[2 * ND + d0 + 4];
                f32x4 rpA = *(const f32x4*)&r32[(long)cb * ND + d0];
                f32x4 rpB = *(const f32x4*)&r32[(long)cb * ND + d0 + 4];
                bool mkk = hyp[cb * T_SZ + t] != 0;
                u64 w0 = 0, w1 = 0;
#pragma unroll
                for (int j = 0; j < 8; ++j) {
                    int dl = half * 8 + j;
                    int dd = ug * 16 + dl;
                    u64 qg0 = (j < 4) ? q0a : q0b;
                    u64 qg1 = (j < 4) ? q1a : q1b;
                    u64 qg2 = (j < 4) ? q2a : q2b;
                    int sh = 16 * (j & 3);
                    float sr  = bounce[cb][0 + dl]  + b2f((unsigned short)(qg0 >> sh)) + m_bhh[dd];
                    float sz  = bounce[cb][16 + dl] + b2f((unsigned short)(qg1 >> sh)) + m_bhh[ND + dd];
                    float gin = bounce[cb][32 + dl] + b2f((unsigned short)(qg2 >> sh));
                    float ghn = bounce[cb][48 + dl] + m_bhh[2 * ND + dd];
                    float rg = fsigmoid(sr), zg = fsigmoid(sz);
                    float ng = ftanh(gin + rg * ghn);
                    float rp = (j < 4) ? rpA[j & 3] : rpB[j & 3];
                    float rn = (1.0f - zg) * ng + zg * rp;
                    float v = mkk ? rn : rp;
                    if (j < 4) rpA[j & 3] = v; else rpB[j & 3] = v;
                    if (j < 4) w0 |= (u64)f2b(v) << sh; else w1 |= (u64)f2b(v) << sh;
                }
                *(f32x4*)&r32[(long)cb * ND + d0] = rpA;       // block-private
                *(f32x4*)&r32[(long)cb * ND + d0 + 4] = rpB;
                cst64(&r16wr[(long)cb * ND + d0], w0);         // coherent, dbuf
                cst64(&r16wr[(long)cb * ND + d0 + 4], w1);
            }
            __syncthreads();
            if (tid == 0) cst32(&uflags[(long)ug * FPAD], (unsigned)(t + 1));
        }
    }
}

// ---------------- prep / misc ----------------
__global__ void prep_idx(const int* __restrict__ prem, const int* __restrict__ hyp,
                         int* __restrict__ idx_p, int* __restrict__ idx_h)
{
    int i = blockIdx.x * blockDim.x + threadIdx.x;
    if (i < B_SZ * T_SZ) {
        int t = i / B_SZ, b = i % B_SZ;
        idx_p[i] = prem[b * T_SZ + t];
        idx_h[i] = hyp[b * T_SZ + t];
    }
}

__global__ void conv_w(const float* __restrict__ in, unsigned short* __restrict__ out,
                       int N, int K, int Kpad, int ldIn, int colOff)
{
    long i = (long)blockIdx.x * blockDim.x + threadIdx.x;
    if (i >= (long)N * Kpad) return;
    int n = (int)(i / Kpad), k = (int)(i % Kpad);
    float v = (k < K) ? in[(long)n * ldIn + k + colOff] : 0.0f;
    out[i] = f2b(v);
}

__global__ void conv_wT(const float* __restrict__ in, unsigned short* __restrict__ out,
                        int N, int K, int Kpad, int ldIn)
{
    long i = (long)blockIdx.x * blockDim.x + threadIdx.x;
    if (i >= (long)N * Kpad) return;
    int n = (int)(i / Kpad), k = (int)(i % Kpad);
    float v = (k < K) ? in[(long)k * ldIn + n] : 0.0f;
    out[i] = f2b(v);
}

__global__ void zero_kernel(float* __restrict__ p, int n)
{
    int i = blockIdx.x * blockDim.x + threadIdx.x;
    if (i < n) p[i] = 0.0f;
}

__global__ void final_logits(const float* __restrict__ r, const float* __restrict__ outW,
                             const float* __restrict__ outb, float* __restrict__ out)
{
    int b = blockIdx.x;
    int lane = threadIdx.x;
    float a0 = 0.0f, a1 = 0.0f, a2 = 0.0f;
    for (int k = lane; k < ND; k += 64) {
        float rv = r[(long)b * ND + k];
        a0 += rv * outW[0 * ND + k];
        a1 += rv * outW[1 * ND + k];
        a2 += rv * outW[2 * ND + k];
    }
#pragma unroll
    for (int off = 32; off; off >>= 1) {
        a0 += __shfl_down(a0, off);
        a1 += __shfl_down(a1, off);
        a2 += __shfl_down(a2, off);
    }
    if (lane == 0) {
        float l0 = a0 + outb[0], l1 = a1 + outb[1], l2 = a2 + outb[2];
        float mx = fmaxf(l0, fmaxf(l1, l2));
        float se = expf(l0 - mx) + expf(l1 - mx) + expf(l2 - mx);
        float ls = mx + logf(se);
        out[b * 3 + 0] = l0 - ls;
        out[b * 3 + 1] = l1 - ls;
        out[b * 3 + 2] = l2 - ls;
    }
}

// ---------------- host ----------------
extern "C" void kernel_launch(void* const* d_in, const int* in_sizes, int n_in,
                              void* d_out, int out_size, void* d_ws, size_t ws_size,
                              hipStream_t stream)
{
    const int*   prem    = (const int*)d_in[0];
    const int*   hyp     = (const int*)d_in[1];
    const float* E       = (const float*)d_in[2];
    const float* p_Wih   = (const float*)d_in[3];
    const float* p_Whh   = (const float*)d_in[4];
    const float* p_bih   = (const float*)d_in[5];
    const float* p_bhh   = (const float*)d_in[6];
    const float* h_Wih   = (const float*)d_in[7];
    const float* h_Whh   = (const float*)d_in[8];
    const float* h_bih   = (const float*)d_in[9];
    const float* h_bhh   = (const float*)d_in[10];
    const float* m_Wih   = (const float*)d_in[11];
    const float* m_Whh   = (const float*)d_in[12];
    const float* m_bih   = (const float*)d_in[13];
    const float* m_bhh   = (const float*)d_in[14];
    const float* W_y     = (const float*)d_in[15];
    const float* W_h     = (const float*)d_in[16];
    const float* W_r     = (const float*)d_in[17];
    const float* W_alpha = (const float*)d_in[18];
    const float* out_W   = (const float*)d_in[19];
    const float* out_b   = (const float*)d_in[20];
    float* out = (float*)d_out;

    const int MB = T_SZ * B_SZ;  // 16384
    const int NFLAGS = 320 * FPAD;  // gruP 64 | gruH 64 | lflags 128 | uflags 32 | sflags 32

    float* ws = (float*)d_ws;
    size_t off = 0;
    float* GI    = ws + off; off += (size_t)MB * G3;
    float* h32a  = ws + off; off += (size_t)B_SZ * ND;
    float* h32b  = ws + off; off += (size_t)B_SZ * ND;
    float* r32   = ws + off; off += (size_t)B_SZ * ND;
    unsigned* flags = (unsigned*)(ws + off); off += NFLAGS;
    int* idx_p = (int*)(ws + off); off += (size_t)B_SZ * T_SZ;
    int* idx_h = (int*)(ws + off); off += (size_t)B_SZ * T_SZ;
    unsigned short* ub = (unsigned short*)(ws + off);
    size_t uoff = 0;
    unsigned short* o_p_bt = ub + uoff; uoff += (size_t)MB * ND;   // Y_bb
    unsigned short* o_h_bt = ub + uoff; uoff += (size_t)MB * ND;
    unsigned short* Yw_bb  = ub + uoff; uoff += (size_t)MB * ND;
    unsigned short* OHWh_bt= ub + uoff; uoff += (size_t)MB * ND;
    unsigned short* OHGI_bt= ub + uoff; uoff += (size_t)MB * G3;
    unsigned short* h16a   = ub + uoff; uoff += (size_t)B_SZ * ND;
    unsigned short* h16b   = ub + uoff; uoff += (size_t)B_SZ * ND;
    unsigned short* r16a   = ub + uoff; uoff += (size_t)B_SZ * ND;
    unsigned short* r16b   = ub + uoff; uoff += (size_t)B_SZ * ND;
    unsigned short* a16    = ub + uoff; uoff += (size_t)B_SZ * ND;
    unsigned short* s16    = ub + uoff; uoff += (size_t)B_SZ * ND;
    unsigned short* pWih_b = ub + uoff; uoff += (size_t)G3 * 320;
    unsigned short* hWih_b = ub + uoff; uoff += (size_t)G3 * 320;
    unsigned short* pWhh_b = ub + uoff; uoff += (size_t)G3 * ND;
    unsigned short* hWhh_b = ub + uoff; uoff += (size_t)G3 * ND;
    unsigned short* mWihL_b= ub + uoff; uoff += (size_t)G3 * ND;
    unsigned short* mWihR  = ub + uoff; uoff += (size_t)G3 * ND;
    unsigned short* mWhh_b = ub + uoff; uoff += (size_t)G3 * ND;
    unsigned short* WyT_b  = ub + uoff; uoff += (size_t)ND * ND;
    unsigned short* WhT_b  = ub + uoff; uoff += (size_t)ND * ND;
    unsigned short* WrT_b  = ub + uoff; uoff += (size_t)ND * ND;
    off += (uoff + 1) / 2;
    if (ws_size < off * sizeof(float)) return;

    auto cblk = [](long n) { return (int)((n + 255) / 256); };

    // ---- prep ----
    prep_idx<<<cblk(MB), 256, 0, stream>>>(prem, hyp, idx_p, idx_h);
    conv_w <<<cblk((long)G3 * 320), 256, 0, stream>>>(p_Wih, pWih_b, G3, EMBD, 320, EMBD, 0);
    conv_w <<<cblk((long)G3 * 320), 256, 0, stream>>>(h_Wih, hWih_b, G3, EMBD, 320, EMBD, 0);
    conv_w <<<cblk((long)G3 * ND), 256, 0, stream>>>(p_Whh, pWhh_b, G3, ND, ND, ND, 0);
    conv_w <<<cblk((long)G3 * ND), 256, 0, stream>>>(h_Whh, hWhh_b, G3, ND, ND, ND, 0);
    conv_w <<<cblk((long)G3 * ND), 256, 0, stream>>>(m_Wih, mWihL_b, G3, ND, ND, 2 * ND, 0);
    conv_w <<<cblk((long)G3 * ND), 256, 0, stream>>>(m_Wih, mWihR, G3, ND, ND, 2 * ND, ND);
    conv_w <<<cblk((long)G3 * ND), 256, 0, stream>>>(m_Whh, mWhh_b, G3, ND, ND, ND, 0);
    conv_wT<<<cblk((long)ND * ND), 256, 0, stream>>>(W_y, WyT_b, ND, ND, ND, ND);
    conv_wT<<<cblk((long)ND * ND), 256, 0, stream>>>(W_h, WhT_b, ND, ND, ND, ND);
    conv_wT<<<cblk((long)ND * ND), 256, 0, stream>>>(W_r, WrT_b, ND, ND, ND, ND);
    zero_kernel<<<cblk(B_SZ * ND), 256, 0, stream>>>(h32a, B_SZ * ND);
    zero_kernel<<<cblk(B_SZ * ND / 2), 256, 0, stream>>>((float*)h16a, B_SZ * ND / 2);
    zero_kernel<<<cblk(B_SZ * ND), 256, 0, stream>>>(r32, B_SZ * ND);
    zero_kernel<<<cblk(B_SZ * ND / 2), 256, 0, stream>>>((float*)r16a, B_SZ * ND / 2);
    zero_kernel<<<cblk(B_SZ * ND / 2), 256, 0, stream>>>((float*)r16b, B_SZ * ND / 2);
    zero_kernel<<<cblk(NFLAGS), 256, 0, stream>>>((float*)flags, NFLAGS);

    // ---- premise ----
    {
        dim3 g(G3 / 64, MB / 64);
        mfma_gemm<float, false><<<g, 256, 0, stream>>>(E, idx_p, pWih_b, p_bih, GI,
                                                       MB, G3, EMBD, EMBD, 320, G3);
    }
    gru_chain<<<GRU_NB, 256, 0, stream>>>(pWhh_b, GI, p_bhh, prem, h32a, h32b, h16a, h16b,
                                          o_p_bt, &flags[0]);

    // ---- hypothesis ----
    {
        dim3 g(G3 / 64, MB / 64);
        mfma_gemm<float, false><<<g, 256, 0, stream>>>(E, idx_h, hWih_b, h_bih, GI,
                                                       MB, G3, EMBD, EMBD, 320, G3);
    }
    gru_chain<<<GRU_NB, 256, 0, stream>>>(hWhh_b, GI, h_bhh, hyp, h32a, h32b, h16a, h16b,
                                          o_h_bt, &flags[64 * FPAD]);

    // ---- attention precompute (all [b][t]-row GEMMs, bf16 outputs) ----
    {
        dim3 g(ND / 64, MB / 64);
        mfma_gemm<unsigned short, true><<<g, 256, 0, stream>>>(o_p_bt, nullptr, WyT_b, nullptr,
                                                               Yw_bb, MB, ND, ND, ND, ND, ND);
        mfma_gemm<unsigned short, true><<<g, 256, 0, stream>>>(o_h_bt, nullptr, WhT_b, nullptr,
                                                               OHWh_bt, MB, ND, ND, ND, ND, ND);
        dim3 g2(G3 / 64, MB / 64);
        mfma_gemm<unsigned short, true><<<g2, 256, 0, stream>>>(o_h_bt, nullptr, mWihR, m_bih,
                                                                OHGI_bt, MB, G3, ND, ND, ND, G3);
    }

    // ---- match chain (160 blocks: 128 LOW + 32 UP) ----
    match_chain<<<160, 256, 0, stream>>>(WrT_b, mWihL_b, mWhh_b, OHWh_bt, OHGI_bt,
                                         m_bhh, W_alpha, Yw_bb, o_p_bt, prem, hyp,
                                         r32, r16a, r16b, a16, s16,
                                         &flags[128 * FPAD], &flags[256 * FPAD],
                                         &flags[288 * FPAD]);

    final_logits<<<B_SZ, 64, 0, stream>>>(r32, out_W, out_b, out);
}

// Round 10
// 7347.625 us; speedup vs baseline: 2.2949x; 1.1294x over previous
//
#include <hip/hip_runtime.h>
#include <math.h>

#define B_SZ 128
#define T_SZ 128
#define EMBD 300
#define ND 512
#define G3 1536
#define FPAD 32   // flag padding stride (u32s) = 128 B

typedef short s16x8 __attribute__((ext_vector_type(8)));
typedef float f32x4 __attribute__((ext_vector_type(4)));
typedef unsigned long long u64;

__device__ __forceinline__ unsigned short f2b(float x) {
    unsigned u = __float_as_uint(x);
    unsigned r = (u + 0x7fff + ((u >> 16) & 1)) >> 16;  // RNE
    return (unsigned short)r;
}
__device__ __forceinline__ float b2f(unsigned short v) {
    return __uint_as_float(((unsigned)v) << 16);
}
__device__ __forceinline__ float fsigmoid(float x) { return 1.0f / (1.0f + __expf(-x)); }
__device__ __forceinline__ float ftanh(float x) { return 1.0f - 2.0f / (__expf(2.0f * x) + 1.0f); }

__device__ __forceinline__ f32x4 mfma16(s16x8 a, s16x8 b, f32x4 c) {
    return __builtin_amdgcn_mfma_f32_16x16x32_bf16(a, b, c, 0, 0, 0);
}

// ---- coherent (LLC-point, fence-free) access helpers ----
__device__ __forceinline__ u64 cld64(const void* p) {
    return __hip_atomic_load((const u64*)p, __ATOMIC_RELAXED, __HIP_MEMORY_SCOPE_AGENT);
}
__device__ __forceinline__ void cst64(void* p, u64 v) {
    __hip_atomic_store((u64*)p, v, __ATOMIC_RELAXED, __HIP_MEMORY_SCOPE_AGENT);
}
__device__ __forceinline__ unsigned cld32(const void* p) {
    return __hip_atomic_load((const unsigned*)p, __ATOMIC_RELAXED, __HIP_MEMORY_SCOPE_AGENT);
}
__device__ __forceinline__ void cst32(void* p, unsigned v) {
    __hip_atomic_store((unsigned*)p, v, __ATOMIC_RELAXED, __HIP_MEMORY_SCOPE_AGENT);
}
__device__ __forceinline__ s16x8 cld_frag(const unsigned short* p) {
    union { u64 q[2]; s16x8 v; } u;
    u.q[0] = cld64(p);
    u.q[1] = cld64(p + 4);
    return u.v;
}

// ---- wave-0-only flag wait (flags padded: id i at f[i*FPAD]) ----
__device__ __forceinline__ void waitflags(const unsigned* f, int n, unsigned ep)
{
    if (threadIdx.x < 64) {
#pragma unroll 1
        for (int i = threadIdx.x; i < n; i += 64)
            while (cld32(&f[(long)i * FPAD]) < ep)
                __builtin_amdgcn_s_sleep(2);
    }
    __syncthreads();
}

// ---- full-grid fence-free barrier (gru chains) ----
__device__ __forceinline__ void fbar(unsigned* flags, int nb, unsigned ep)
{
    __syncthreads();   // drains vmcnt per wave before s_barrier
    if (threadIdx.x == 0)
        cst32(&flags[(long)blockIdx.x * FPAD], ep);
    waitflags(flags, nb, ep);
}

// ---------------- generic MFMA GEMM (precompute only) ----------------
template<typename AT, bool OB>
__global__ __launch_bounds__(256)
void mfma_gemm(const AT* __restrict__ A, const int* __restrict__ idxA,
               const unsigned short* __restrict__ Wb, const float* __restrict__ bias,
               void* __restrict__ Cv,
               int M, int N, int K, int ldA, int Kpad, int ldC)
{
    __shared__ unsigned short As[64][40];
    __shared__ unsigned short Bs[64][40];
    const int tid = threadIdx.x;
    const int wv = tid >> 6, lane = tid & 63;
    const int wm = wv >> 1, wn = wv & 1;
    const int m0 = blockIdx.y * 64, n0 = blockIdx.x * 64;

    f32x4 acc[2][2] = {{{0.f,0.f,0.f,0.f},{0.f,0.f,0.f,0.f}},
                       {{0.f,0.f,0.f,0.f},{0.f,0.f,0.f,0.f}}};
    const int r_st = tid >> 2, k_st = (tid & 3) * 8;

    long arow = -1;
    {
        int gm = m0 + r_st;
        if (gm < M) arow = idxA ? (long)idxA[gm] : (long)gm;
    }

    const int kIters = (K + 31) / 32;
    for (int it = 0; it < kIters; ++it) {
        const int kg = it * 32 + k_st;
        {
            s16x8 pk = {0,0,0,0,0,0,0,0};
            if (arow >= 0) {
                if constexpr (sizeof(AT) == 2) {
                    if (kg + 8 <= K) {
                        pk = *(const s16x8*)((const unsigned short*)A + arow * (long)ldA + kg);
                    } else {
#pragma unroll
                        for (int j = 0; j < 8; ++j)
                            if (kg + j < K) pk[j] = (short)((const unsigned short*)A)[arow * (long)ldA + kg + j];
                    }
                } else {
                    if (kg + 8 <= K) {
                        const float* p = (const float*)A + arow * (long)ldA + kg;
                        f32x4 u0 = *(const f32x4*)p;
                        f32x4 u1 = *(const f32x4*)(p + 4);
#pragma unroll
                        for (int j = 0; j < 4; ++j) { pk[j] = (short)f2b(u0[j]); pk[4+j] = (short)f2b(u1[j]); }
                    } else {
#pragma unroll
                        for (int j = 0; j < 8; ++j) {
                            int kk = kg + j;
                            if (kk < K) pk[j] = (short)f2b(((const float*)A)[arow * (long)ldA + kk]);
                        }
                    }
                }
            }
            *(s16x8*)&As[r_st][k_st] = pk;
        }
        {
            int gn = n0 + r_st;
            s16x8 pk = {0,0,0,0,0,0,0,0};
            if (gn < N) pk = *(const s16x8*)&Wb[(long)gn * Kpad + kg];
            *(s16x8*)&Bs[r_st][k_st] = pk;
        }
        __syncthreads();
        {
            const int koff = (lane >> 4) * 8;
            s16x8 af[2], bfr[2];
#pragma unroll
            for (int f = 0; f < 2; ++f) {
                af[f]  = *(s16x8*)&As[wm * 32 + f * 16 + (lane & 15)][koff];
                bfr[f] = *(s16x8*)&Bs[wn * 32 + f * 16 + (lane & 15)][koff];
            }
#pragma unroll
            for (int fi = 0; fi < 2; ++fi)
#pragma unroll
                for (int fj = 0; fj < 2; ++fj)
                    acc[fi][fj] = mfma16(af[fi], bfr[fj], acc[fi][fj]);
        }
        __syncthreads();
    }
#pragma unroll
    for (int fi = 0; fi < 2; ++fi)
#pragma unroll
        for (int fj = 0; fj < 2; ++fj)
#pragma unroll
            for (int r = 0; r < 4; ++r) {
                int m = m0 + wm * 32 + fi * 16 + (lane >> 4) * 4 + r;
                int n = n0 + wn * 32 + fj * 16 + (lane & 15);
                if (m < M && n < N) {
                    float v = acc[fi][fj][r];
                    if (bias) v += bias[n];
                    if constexpr (OB) ((unsigned short*)Cv)[(long)m * ldC + n] = f2b(v);
                    else               ((float*)Cv)[(long)m * ldC + n] = v;
                }
            }
}

// ---------------- persistent GRU chain ----------------
#define GRU_NB 64
__global__ __launch_bounds__(256, 1)
void gru_chain(const unsigned short* __restrict__ Whh_b, const float* __restrict__ GI,
               const float* __restrict__ bhh, const int* __restrict__ toks,
               float* __restrict__ h32a, float* __restrict__ h32b,
               unsigned short* __restrict__ h16a, unsigned short* __restrict__ h16b,
               unsigned short* __restrict__ o_bt,
               unsigned* __restrict__ flags)
{
    __shared__ unsigned short wlds[3][16][512];   // 48 KB
    __shared__ unsigned short ht[64][20];         // transpose buffer
    const int tid = threadIdx.x;
    const int wv = tid >> 6, lane = tid & 63;
    const int dt = blockIdx.x & 31, bh = blockIdx.x >> 5;
    const int b0 = bh * 64;

    for (int s = 0; s < 12; ++s) {
        int slot = tid + s * 256;
        int g = slot >> 10, rem = slot & 1023, ks = rem >> 6, ln = rem & 63;
        int row = g * ND + dt * 16 + (ln & 15);
        int k = ks * 32 + (ln >> 4) * 8;
        *(s16x8*)&wlds[g][ks][ln * 8] = *(const s16x8*)&Whh_b[(long)row * ND + k];
    }
    __syncthreads();

    const int d = dt * 16 + (lane & 15);
    const int brow = b0 + wv * 16 + (lane >> 4) * 4;
    const int arow = b0 + wv * 16 + (lane & 15);
    const int akoff = (lane >> 4) * 8;

    float o_run[4] = {0.f, 0.f, 0.f, 0.f};
    unsigned ep = 0;

    for (int t = 0; t < T_SZ; ++t) {
        const unsigned short* hin16 = (t & 1) ? h16b : h16a;
        const float*          hin32 = (t & 1) ? h32b : h32a;
        float*          hout32 = (t & 1) ? h32a : h32b;
        unsigned short* hout16 = (t & 1) ? h16a : h16b;

        const float* git = GI + (long)t * (B_SZ * G3);
        float gi_r[4], gi_z[4], gi_n[4], hp[4]; int mk[4];
#pragma unroll
        for (int rr = 0; rr < 4; ++rr) {
            int b = brow + rr;
            gi_r[rr] = git[(long)b * G3 + d];
            gi_z[rr] = git[(long)b * G3 + ND + d];
            gi_n[rr] = git[(long)b * G3 + 2 * ND + d];
            hp[rr]   = hin32[(long)b * ND + d];
            mk[rr]   = toks[b * T_SZ + t];
        }

        f32x4 acc0 = {0,0,0,0}, acc1 = {0,0,0,0}, acc2 = {0,0,0,0};
#pragma unroll
        for (int ks = 0; ks < 16; ++ks) {
            s16x8 a  = cld_frag(&hin16[(long)arow * ND + ks * 32 + akoff]);
            s16x8 br = *(s16x8*)&wlds[0][ks][lane * 8];
            s16x8 bz = *(s16x8*)&wlds[1][ks][lane * 8];
            s16x8 bn = *(s16x8*)&wlds[2][ks][lane * 8];
            acc0 = mfma16(a, br, acc0);
            acc1 = mfma16(a, bz, acc1);
            acc2 = mfma16(a, bn, acc2);
        }

#pragma unroll
        for (int rr = 0; rr < 4; ++rr) {
            int b = brow + rr;
            float rg = fsigmoid(gi_r[rr] + acc0[rr] + bhh[d]);
            float zg = fsigmoid(gi_z[rr] + acc1[rr] + bhh[ND + d]);
            float ng = ftanh(gi_n[rr] + rg * (acc2[rr] + bhh[2 * ND + d]));
            float hr = (1.0f - zg) * ng + zg * hp[rr];
            bool m = mk[rr] != 0;
            float hn = m ? hr : hp[rr];
            hout32[(long)b * ND + d] = hn;              // block-private: normal
            ht[b - b0][lane & 15] = f2b(hn);
            o_run[rr] = (t == 0) ? hr : (m ? hr : o_run[rr]);
            o_bt[((long)b * T_SZ + t) * ND + d] = f2b(o_run[rr]);  // later launches: normal
        }
        __syncthreads();
        {
            int bl = tid & 63, dq = tid >> 6;
            u64 v = *(u64*)&ht[bl][dq * 4];
            cst64(&hout16[(long)(b0 + bl) * ND + dt * 16 + dq * 4], v);   // coherent
        }
        fbar(flags, GRU_NB, ++ep);
    }
}

// ---------------- persistent match chain: 160 blocks, role-split ----------------
// LOW (0..127):  b = blk. LDS Yw[b] (padded rows). Per step: wait sflags ->
//                transposed-reduce logits -> softmax -> wsum -> a16, lflag.
// UP (128..159): ug = blk-128, d-slice ug*16..+16. r-phase {SR,SZ,GHN,S} -> s16,
//                sflag -> wait lflags -> a-phase {SR,SZ,GIN} -> combine -> r16, uflag.
#define UP_NB 32
#define YPITCH 520   // ywl row pitch (bf16 elems): 16B-aligned, 8-way max conflict
__global__ __launch_bounds__(256, 1)
void match_chain(const unsigned short* __restrict__ WrT_b,
                 const unsigned short* __restrict__ mWihL_b,
                 const unsigned short* __restrict__ mWhh_b,
                 const unsigned short* __restrict__ OHWh_bt,
                 const unsigned short* __restrict__ OHGI_bt,
                 const float* __restrict__ m_bhh, const float* __restrict__ Walpha,
                 const unsigned short* __restrict__ Yw_bb,
                 const unsigned short* __restrict__ Y_bb,
                 const int* __restrict__ prem, const int* __restrict__ hyp,
                 float* __restrict__ r32,
                 unsigned short* __restrict__ r16a, unsigned short* __restrict__ r16b,
                 unsigned short* __restrict__ a16, unsigned short* __restrict__ s16,
                 unsigned* __restrict__ lflags, unsigned* __restrict__ uflags,
                 unsigned* __restrict__ sflags)
{
    __shared__ __align__(16) unsigned char smem[157696];
    const int tid = threadIdx.x;
    const int wv = tid >> 6, lane = tid & 63;

    if (blockIdx.x < 128) {
        // ================= LOW: attention for b = blockIdx.x =================
        const int b = blockIdx.x;
        unsigned short (*ywl)[YPITCH] = (unsigned short(*)[YPITCH])smem;     // 130 KB
        float* wal  = (float*)(smem + 133120);                               // 2 KB
        float* sarr = (float*)(smem + 135168);                               // 2 KB
        float* part = (float*)(smem + 137216);                               // 1 KB
        float* lg   = (float*)(smem + 138240);                               // 512 B
        float* red  = (float*)(smem + 138752);                               // 32 B
        float* sr2  = (float*)(smem + 138784);                               // 2 KB

        for (int s = 0; s < 32; ++s) {
            int c = s * 256 + tid;
            int row = c >> 6, cg = c & 63;
            *(s16x8*)&ywl[row][cg * 8] =
                *(const s16x8*)&Yw_bb[((long)b * T_SZ + row) * ND + cg * 8];
        }
        if (tid < 128) {
            f32x4 w = *(const f32x4*)&Walpha[tid * 4];
            *(f32x4*)&wal[tid * 4] = w;
        }
        __syncthreads();

        const int tp = tid >> 1, gh = tid & 1;      // logits ownership
        const unsigned short* yrow = &ywl[tp][gh * 256];
        const float* sp  = &sarr[gh * 256];
        const float* wap = &wal[gh * 256];

        for (int t = 0; t < T_SZ; ++t) {
            waitflags(sflags, UP_NB, (unsigned)(t + 1));   // s for step t ready
            // s row -> LDS f32
            if (tid < 64) {
                s16x8 q = cld_frag(&s16[(long)b * ND + tid * 8]);
#pragma unroll
                for (int j = 0; j < 8; ++j) sarr[tid * 8 + j] = b2f((unsigned short)q[j]);
            }
            __syncthreads();
            // logits phase A: private partial over 256 d's (no cross-lane ops)
            {
                float acc = 0.f;
#pragma unroll 4
                for (int i8 = 0; i8 < 32; ++i8) {
                    s16x8 yw = *(const s16x8*)&yrow[i8 * 8];
                    f32x4 s0 = *(const f32x4*)&sp[i8 * 8];
                    f32x4 s1 = *(const f32x4*)&sp[i8 * 8 + 4];
                    f32x4 w0 = *(const f32x4*)&wap[i8 * 8];
                    f32x4 w1 = *(const f32x4*)&wap[i8 * 8 + 4];
#pragma unroll
                    for (int j = 0; j < 4; ++j)
                        acc += ftanh(b2f((unsigned short)yw[j]) + s0[j]) * w0[j];
#pragma unroll
                    for (int j = 0; j < 4; ++j)
                        acc += ftanh(b2f((unsigned short)yw[4 + j]) + s1[j]) * w1[j];
                }
                part[tid] = acc;
            }
            __syncthreads();
            // phase B: 2 partials -> logit
            if (tid < 128) {
                float v = part[tid * 2] + part[tid * 2 + 1];
                float mm = (prem[b * T_SZ + tid] != 0) ? 0.f : 1000.f;
                lg[tid] = v - mm;
            }
            __syncthreads();
            if (tid < 64) {
                float v = fmaxf(lg[tid], lg[tid + 64]);
#pragma unroll
                for (int off = 32; off; off >>= 1) v = fmaxf(v, __shfl_xor(v, off));
                if (tid == 0) red[0] = v;
            }
            __syncthreads();
            float mx = red[0];
            if (tid < T_SZ) lg[tid] = __expf(lg[tid] - mx);
            __syncthreads();
            if (tid < 64) {
                float v = lg[tid] + lg[tid + 64];
#pragma unroll
                for (int off = 32; off; off >>= 1) v += __shfl_xor(v, off);
                if (tid == 0) red[1] = v;
            }
            __syncthreads();
            // weighted sum over Y (L2-cached), tp split in halves
            float inv = 1.0f / red[1];
            int g = tid >> 7, lt = tid & 127, n4 = lt * 4;
            f32x4 acw = {0.f, 0.f, 0.f, 0.f};
#pragma unroll 8
            for (int i = 0; i < 64; ++i) {
                int tpp = g * 64 + i;
                float al = lg[tpp] * inv;
                u64 q = *(const u64*)&Y_bb[((long)b * T_SZ + tpp) * ND + n4];
                acw[0] += al * b2f((unsigned short)q);
                acw[1] += al * b2f((unsigned short)(q >> 16));
                acw[2] += al * b2f((unsigned short)(q >> 32));
                acw[3] += al * b2f((unsigned short)(q >> 48));
            }
            if (g == 1) *(f32x4*)&sr2[n4] = acw;
            __syncthreads();
            if (g == 0) {
                f32x4 o = *(f32x4*)&sr2[n4];
                u64 pk = (u64)f2b(acw[0] + o[0]) | ((u64)f2b(acw[1] + o[1]) << 16)
                       | ((u64)f2b(acw[2] + o[2]) << 32) | ((u64)f2b(acw[3] + o[3]) << 48);
                cst64(&a16[(long)b * ND + n4], pk);
            }
            __syncthreads();
            if (tid == 0) cst32(&lflags[(long)b * FPAD], (unsigned)(t + 1));
        }
    } else {
        // ================= UP: gates + s + combine; d-slice ug*16..+16 =================
        const int ug = blockIdx.x - 128;
        unsigned short (*wA)[16][512] = (unsigned short(*)[16][512])smem;           // 48 KB {SR_a,SZ_a,GIN}
        unsigned short (*wR)[16][512] = (unsigned short(*)[16][512])(smem + 49152); // 64 KB {SR_r,SZ_r,GHN,S}
        float (*bounce)[84] = (float(*)[84])(smem + 49152 + 65536);                 // 43 KB

        for (int s = 0; s < 12; ++s) {
            int slot = tid + s * 256;
            int fam = slot >> 10, rem = slot & 1023, ks = rem >> 6, ln = rem & 63;
            int row = fam * ND + ug * 16 + (ln & 15);
            int k = ks * 32 + (ln >> 4) * 8;
            *(s16x8*)&wA[fam][ks][ln * 8] = *(const s16x8*)&mWihL_b[(long)row * ND + k];
        }
        for (int s = 0; s < 16; ++s) {
            int slot = tid + s * 256;
            int fam = slot >> 10, rem = slot & 1023, ks = rem >> 6, ln = rem & 63;
            int k = ks * 32 + (ln >> 4) * 8;
            const unsigned short* src = (fam < 3)
                ? &mWhh_b[(long)(fam * ND + ug * 16 + (ln & 15)) * ND + k]
                : &WrT_b[(long)(ug * 16 + (ln & 15)) * ND + k];
            *(s16x8*)&wR[fam][ks][ln * 8] = *(const s16x8*)src;
        }
        __syncthreads();

        const int akoff = (lane >> 4) * 8;
        const int cb = tid >> 1;                 // combine: b
        const int half = tid & 1;
        const int d0 = ug * 16 + half * 8;       // combine: first of 8 d's

        for (int t = 0; t < T_SZ; ++t) {
            waitflags(uflags, UP_NB, (unsigned)t);
            const unsigned short* r16rd = (t & 1) ? r16b : r16a;
            unsigned short*       r16wr = (t & 1) ? r16a : r16b;

            // ---- r-phase: {SR,SZ,GHN,S} over full r rows ----
            f32x4 aSR[2] = {{0,0,0,0},{0,0,0,0}}, aSZ[2] = {{0,0,0,0},{0,0,0,0}};
            f32x4 aHN[2] = {{0,0,0,0},{0,0,0,0}}, aS[2]  = {{0,0,0,0},{0,0,0,0}};
            f32x4 aGN[2] = {{0,0,0,0},{0,0,0,0}};
#pragma unroll
            for (int f = 0; f < 2; ++f) {
                int row = wv * 32 + f * 16 + (lane & 15);
#pragma unroll
                for (int ks = 0; ks < 16; ++ks) {
                    s16x8 a = cld_frag(&r16rd[(long)row * ND + ks * 32 + akoff]);
                    aSR[f] = mfma16(a, *(s16x8*)&wR[0][ks][lane * 8], aSR[f]);
                    aSZ[f] = mfma16(a, *(s16x8*)&wR[1][ks][lane * 8], aSZ[f]);
                    aHN[f] = mfma16(a, *(s16x8*)&wR[2][ks][lane * 8], aHN[f]);
                    aS[f]  = mfma16(a, *(s16x8*)&wR[3][ks][lane * 8], aS[f]);
                }
            }
            // s-part -> bounce cols 64..79
#pragma unroll
            for (int f = 0; f < 2; ++f)
#pragma unroll
                for (int rr = 0; rr < 4; ++rr)
                    bounce[wv * 32 + f * 16 + (lane >> 4) * 4 + rr][64 + (lane & 15)] = aS[f][rr];
            __syncthreads();
            {
                // s16 = S + OHWh (8 d's per thread)
                u64 qa = *(const u64*)&OHWh_bt[((long)cb * T_SZ + t) * ND + d0];
                u64 qb = *(const u64*)&OHWh_bt[((long)cb * T_SZ + t) * ND + d0 + 4];
                u64 w0 = 0, w1 = 0;
#pragma unroll
                for (int j = 0; j < 4; ++j) {
                    float v0 = bounce[cb][64 + half * 8 + j]     + b2f((unsigned short)(qa >> (16 * j)));
                    float v1 = bounce[cb][64 + half * 8 + 4 + j] + b2f((unsigned short)(qb >> (16 * j)));
                    w0 |= (u64)f2b(v0) << (16 * j);
                    w1 |= (u64)f2b(v1) << (16 * j);
                }
                cst64(&s16[(long)cb * ND + d0], w0);
                cst64(&s16[(long)cb * ND + d0 + 4], w1);
            }
            __syncthreads();
            if (tid == 0) cst32(&sflags[(long)ug * FPAD], (unsigned)(t + 1));

            // ---- a-phase: {SR,SZ,GIN} over full a rows ----
            waitflags(lflags, 128, (unsigned)(t + 1));
#pragma unroll
            for (int f = 0; f < 2; ++f) {
                int row = wv * 32 + f * 16 + (lane & 15);
#pragma unroll
                for (int ks = 0; ks < 16; ++ks) {
                    s16x8 a = cld_frag(&a16[(long)row * ND + ks * 32 + akoff]);
                    aSR[f] = mfma16(a, *(s16x8*)&wA[0][ks][lane * 8], aSR[f]);
                    aSZ[f] = mfma16(a, *(s16x8*)&wA[1][ks][lane * 8], aSZ[f]);
                    aGN[f] = mfma16(a, *(s16x8*)&wA[2][ks][lane * 8], aGN[f]);
                }
            }
#pragma unroll
            for (int f = 0; f < 2; ++f)
#pragma unroll
                for (int rr = 0; rr < 4; ++rr) {
                    int bb = wv * 32 + f * 16 + (lane >> 4) * 4 + rr;
                    bounce[bb][0  + (lane & 15)] = aSR[f][rr];
                    bounce[bb][16 + (lane & 15)] = aSZ[f][rr];
                    bounce[bb][32 + (lane & 15)] = aGN[f][rr];
                    bounce[bb][48 + (lane & 15)] = aHN[f][rr];
                }
            __syncthreads();
            {
                const unsigned short* og = OHGI_bt + ((long)cb * T_SZ + t) * G3;
                u64 q0a = *(const u64*)&og[d0];            u64 q0b = *(const u64*)&og[d0 + 4];
                u64 q1a = *(const u64*)&og[ND + d0];       u64 q1b = *(const u64*)&og[ND + d0 + 4];
                u64 q2a = *(const u64*)&og[2 * ND + d0];   u64 q2b = *(const u64*)&og[2 * ND + d0 + 4];
                f32x4 rpA = *(const f32x4*)&r32[(long)cb * ND + d0];
                f32x4 rpB = *(const f32x4*)&r32[(long)cb * ND + d0 + 4];
                bool mkk = hyp[cb * T_SZ + t] != 0;
                u64 w0 = 0, w1 = 0;
#pragma unroll
                for (int j = 0; j < 8; ++j) {
                    int dl = half * 8 + j;
                    int dd = ug * 16 + dl;
                    u64 qg0 = (j < 4) ? q0a : q0b;
                    u64 qg1 = (j < 4) ? q1a : q1b;
                    u64 qg2 = (j < 4) ? q2a : q2b;
                    int sh = 16 * (j & 3);
                    float sr  = bounce[cb][0 + dl]  + b2f((unsigned short)(qg0 >> sh)) + m_bhh[dd];
                    float sz  = bounce[cb][16 + dl] + b2f((unsigned short)(qg1 >> sh)) + m_bhh[ND + dd];
                    float gin = bounce[cb][32 + dl] + b2f((unsigned short)(qg2 >> sh));
                    float ghn = bounce[cb][48 + dl] + m_bhh[2 * ND + dd];
                    float rg = fsigmoid(sr), zg = fsigmoid(sz);
                    float ng = ftanh(gin + rg * ghn);
                    float rp = (j < 4) ? rpA[j & 3] : rpB[j & 3];
                    float rn = (1.0f - zg) * ng + zg * rp;
                    float v = mkk ? rn : rp;
                    if (j < 4) rpA[j & 3] = v; else rpB[j & 3] = v;
                    if (j < 4) w0 |= (u64)f2b(v) << sh; else w1 |= (u64)f2b(v) << sh;
                }
                *(f32x4*)&r32[(long)cb * ND + d0] = rpA;       // block-private
                *(f32x4*)&r32[(long)cb * ND + d0 + 4] = rpB;
                cst64(&r16wr[(long)cb * ND + d0], w0);         // coherent, dbuf
                cst64(&r16wr[(long)cb * ND + d0 + 4], w1);
            }
            __syncthreads();
            if (tid == 0) cst32(&uflags[(long)ug * FPAD], (unsigned)(t + 1));
        }
    }
}

// ---------------- prep / misc ----------------
__global__ void prep_idx(const int* __restrict__ prem, const int* __restrict__ hyp,
                         int* __restrict__ idx_p, int* __restrict__ idx_h)
{
    int i = blockIdx.x * blockDim.x + threadIdx.x;
    if (i < B_SZ * T_SZ) {
        int t = i / B_SZ, b = i % B_SZ;
        idx_p[i] = prem[b * T_SZ + t];
        idx_h[i] = hyp[b * T_SZ + t];
    }
}

__global__ void conv_w(const float* __restrict__ in, unsigned short* __restrict__ out,
                       int N, int K, int Kpad, int ldIn, int colOff)
{
    long i = (long)blockIdx.x * blockDim.x + threadIdx.x;
    if (i >= (long)N * Kpad) return;
    int n = (int)(i / Kpad), k = (int)(i % Kpad);
    float v = (k < K) ? in[(long)n * ldIn + k + colOff] : 0.0f;
    out[i] = f2b(v);
}

__global__ void conv_wT(const float* __restrict__ in, unsigned short* __restrict__ out,
                        int N, int K, int Kpad, int ldIn)
{
    long i = (long)blockIdx.x * blockDim.x + threadIdx.x;
    if (i >= (long)N * Kpad) return;
    int n = (int)(i / Kpad), k = (int)(i % Kpad);
    float v = (k < K) ? in[(long)k * ldIn + n] : 0.0f;
    out[i] = f2b(v);
}

__global__ void zero_kernel(float* __restrict__ p, int n)
{
    int i = blockIdx.x * blockDim.x + threadIdx.x;
    if (i < n) p[i] = 0.0f;
}

__global__ void final_logits(const float* __restrict__ r, const float* __restrict__ outW,
                             const float* __restrict__ outb, float* __restrict__ out)
{
    int b = blockIdx.x;
    int lane = threadIdx.x;
    float a0 = 0.0f, a1 = 0.0f, a2 = 0.0f;
    for (int k = lane; k < ND; k += 64) {
        float rv = r[(long)b * ND + k];
        a0 += rv * outW[0 * ND + k];
        a1 += rv * outW[1 * ND + k];
        a2 += rv * outW[2 * ND + k];
    }
#pragma unroll
    for (int off = 32; off; off >>= 1) {
        a0 += __shfl_down(a0, off);
        a1 += __shfl_down(a1, off);
        a2 += __shfl_down(a2, off);
    }
    if (lane == 0) {
        float l0 = a0 + outb[0], l1 = a1 + outb[1], l2 = a2 + outb[2];
        float mx = fmaxf(l0, fmaxf(l1, l2));
        float se = expf(l0 - mx) + expf(l1 - mx) + expf(l2 - mx);
        float ls = mx + logf(se);
        out[b * 3 + 0] = l0 - ls;
        out[b * 3 + 1] = l1 - ls;
        out[b * 3 + 2] = l2 - ls;
    }
}

// ---------------- host ----------------
extern "C" void kernel_launch(void* const* d_in, const int* in_sizes, int n_in,
                              void* d_out, int out_size, void* d_ws, size_t ws_size,
                              hipStream_t stream)
{
    const int*   prem    = (const int*)d_in[0];
    const int*   hyp     = (const int*)d_in[1];
    const float* E       = (const float*)d_in[2];
    const float* p_Wih   = (const float*)d_in[3];
    const float* p_Whh   = (const float*)d_in[4];
    const float* p_bih   = (const float*)d_in[5];
    const float* p_bhh   = (const float*)d_in[6];
    const float* h_Wih   = (const float*)d_in[7];
    const float* h_Whh   = (const float*)d_in[8];
    const float* h_bih   = (const float*)d_in[9];
    const float* h_bhh   = (const float*)d_in[10];
    const float* m_Wih   = (const float*)d_in[11];
    const float* m_Whh   = (const float*)d_in[12];
    const float* m_bih   = (const float*)d_in[13];
    const float* m_bhh   = (const float*)d_in[14];
    const float* W_y     = (const float*)d_in[15];
    const float* W_h     = (const float*)d_in[16];
    const float* W_r     = (const float*)d_in[17];
    const float* W_alpha = (const float*)d_in[18];
    const float* out_W   = (const float*)d_in[19];
    const float* out_b   = (const float*)d_in[20];
    float* out = (float*)d_out;

    const int MB = T_SZ * B_SZ;  // 16384
    const int NFLAGS = 320 * FPAD;  // gruP 64 | gruH 64 | lflags 128 | uflags 32 | sflags 32

    float* ws = (float*)d_ws;
    size_t off = 0;
    float* GI    = ws + off; off += (size_t)MB * G3;
    float* h32a  = ws + off; off += (size_t)B_SZ * ND;
    float* h32b  = ws + off; off += (size_t)B_SZ * ND;
    float* r32   = ws + off; off += (size_t)B_SZ * ND;
    unsigned* flags = (unsigned*)(ws + off); off += NFLAGS;
    int* idx_p = (int*)(ws + off); off += (size_t)B_SZ * T_SZ;
    int* idx_h = (int*)(ws + off); off += (size_t)B_SZ * T_SZ;
    unsigned short* ub = (unsigned short*)(ws + off);
    size_t uoff = 0;
    unsigned short* o_p_bt = ub + uoff; uoff += (size_t)MB * ND;   // Y_bb
    unsigned short* o_h_bt = ub + uoff; uoff += (size_t)MB * ND;
    unsigned short* Yw_bb  = ub + uoff; uoff += (size_t)MB * ND;
    unsigned short* OHWh_bt= ub + uoff; uoff += (size_t)MB * ND;
    unsigned short* OHGI_bt= ub + uoff; uoff += (size_t)MB * G3;
    unsigned short* h16a   = ub + uoff; uoff += (size_t)B_SZ * ND;
    unsigned short* h16b   = ub + uoff; uoff += (size_t)B_SZ * ND;
    unsigned short* r16a   = ub + uoff; uoff += (size_t)B_SZ * ND;
    unsigned short* r16b   = ub + uoff; uoff += (size_t)B_SZ * ND;
    unsigned short* a16    = ub + uoff; uoff += (size_t)B_SZ * ND;
    unsigned short* s16    = ub + uoff; uoff += (size_t)B_SZ * ND;
    unsigned short* pWih_b = ub + uoff; uoff += (size_t)G3 * 320;
    unsigned short* hWih_b = ub + uoff; uoff += (size_t)G3 * 320;
    unsigned short* pWhh_b = ub + uoff; uoff += (size_t)G3 * ND;
    unsigned short* hWhh_b = ub + uoff; uoff += (size_t)G3 * ND;
    unsigned short* mWihL_b= ub + uoff; uoff += (size_t)G3 * ND;
    unsigned short* mWihR  = ub + uoff; uoff += (size_t)G3 * ND;
    unsigned short* mWhh_b = ub + uoff; uoff += (size_t)G3 * ND;
    unsigned short* WyT_b  = ub + uoff; uoff += (size_t)ND * ND;
    unsigned short* WhT_b  = ub + uoff; uoff += (size_t)ND * ND;
    unsigned short* WrT_b  = ub + uoff; uoff += (size_t)ND * ND;
    off += (uoff + 1) / 2;
    if (ws_size < off * sizeof(float)) return;

    auto cblk = [](long n) { return (int)((n + 255) / 256); };

    // ---- prep ----
    prep_idx<<<cblk(MB), 256, 0, stream>>>(prem, hyp, idx_p, idx_h);
    conv_w <<<cblk((long)G3 * 320), 256, 0, stream>>>(p_Wih, pWih_b, G3, EMBD, 320, EMBD, 0);
    conv_w <<<cblk((long)G3 * 320), 256, 0, stream>>>(h_Wih, hWih_b, G3, EMBD, 320, EMBD, 0);
    conv_w <<<cblk((long)G3 * ND), 256, 0, stream>>>(p_Whh, pWhh_b, G3, ND, ND, ND, 0);
    conv_w <<<cblk((long)G3 * ND), 256, 0, stream>>>(h_Whh, hWhh_b, G3, ND, ND, ND, 0);
    conv_w <<<cblk((long)G3 * ND), 256, 0, stream>>>(m_Wih, mWihL_b, G3, ND, ND, 2 * ND, 0);
    conv_w <<<cblk((long)G3 * ND), 256, 0, stream>>>(m_Wih, mWihR, G3, ND, ND, 2 * ND, ND);
    conv_w <<<cblk((long)G3 * ND), 256, 0, stream>>>(m_Whh, mWhh_b, G3, ND, ND, ND, 0);
    conv_wT<<<cblk((long)ND * ND), 256, 0, stream>>>(W_y, WyT_b, ND, ND, ND, ND);
    conv_wT<<<cblk((long)ND * ND), 256, 0, stream>>>(W_h, WhT_b, ND, ND, ND, ND);
    conv_wT<<<cblk((long)ND * ND), 256, 0, stream>>>(W_r, WrT_b, ND, ND, ND, ND);
    zero_kernel<<<cblk(B_SZ * ND), 256, 0, stream>>>(h32a, B_SZ * ND);
    zero_kernel<<<cblk(B_SZ * ND / 2), 256, 0, stream>>>((float*)h16a, B_SZ * ND / 2);
    zero_kernel<<<cblk(B_SZ * ND), 256, 0, stream>>>(r32, B_SZ * ND);
    zero_kernel<<<cblk(B_SZ * ND / 2), 256, 0, stream>>>((float*)r16a, B_SZ * ND / 2);
    zero_kernel<<<cblk(B_SZ * ND / 2), 256, 0, stream>>>((float*)r16b, B_SZ * ND / 2);
    zero_kernel<<<cblk(NFLAGS), 256, 0, stream>>>((float*)flags, NFLAGS);

    // ---- premise ----
    {
        dim3 g(G3 / 64, MB / 64);
        mfma_gemm<float, false><<<g, 256, 0, stream>>>(E, idx_p, pWih_b, p_bih, GI,
                                                       MB, G3, EMBD, EMBD, 320, G3);
    }
    gru_chain<<<GRU_NB, 256, 0, stream>>>(pWhh_b, GI, p_bhh, prem, h32a, h32b, h16a, h16b,
                                          o_p_bt, &flags[0]);

    // ---- hypothesis ----
    {
        dim3 g(G3 / 64, MB / 64);
        mfma_gemm<float, false><<<g, 256, 0, stream>>>(E, idx_h, hWih_b, h_bih, GI,
                                                       MB, G3, EMBD, EMBD, 320, G3);
    }
    gru_chain<<<GRU_NB, 256, 0, stream>>>(hWhh_b, GI, h_bhh, hyp, h32a, h32b, h16a, h16b,
                                          o_h_bt, &flags[64 * FPAD]);

    // ---- attention precompute (all [b][t]-row GEMMs, bf16 outputs) ----
    {
        dim3 g(ND / 64, MB / 64);
        mfma_gemm<unsigned short, true><<<g, 256, 0, stream>>>(o_p_bt, nullptr, WyT_b, nullptr,
                                                               Yw_bb, MB, ND, ND, ND, ND, ND);
        mfma_gemm<unsigned short, true><<<g, 256, 0, stream>>>(o_h_bt, nullptr, WhT_b, nullptr,
                                                               OHWh_bt, MB, ND, ND, ND, ND, ND);
        dim3 g2(G3 / 64, MB / 64);
        mfma_gemm<unsigned short, true><<<g2, 256, 0, stream>>>(o_h_bt, nullptr, mWihR, m_bih,
                                                                OHGI_bt, MB, G3, ND, ND, ND, G3);
    }

    // ---- match chain (160 blocks: 128 LOW + 32 UP) ----
    match_chain<<<160, 256, 0, stream>>>(WrT_b, mWihL_b, mWhh_b, OHWh_bt, OHGI_bt,
                                         m_bhh, W_alpha, Yw_bb, o_p_bt, prem, hyp,
                                         r32, r16a, r16b, a16, s16,
                                         &flags[128 * FPAD], &flags[256 * FPAD],
                                         &flags[288 * FPAD]);

    final_logits<<<B_SZ, 64, 0, stream>>>(r32, out_W, out_b, out);
}

// Round 11
// 7024.700 us; speedup vs baseline: 2.4004x; 1.0460x over previous
//
#include <hip/hip_runtime.h>
#include <math.h>

#define B_SZ 128
#define T_SZ 128
#define EMBD 300
#define ND 512
#define G3 1536
#define FPAD 32    // flag padding stride (u32s) = 128 B
#define NFID 320   // flag ids per replica
#define NREP 8     // flag replicas

typedef short s16x8 __attribute__((ext_vector_type(8)));
typedef float f32x4 __attribute__((ext_vector_type(4)));
typedef unsigned long long u64;

__device__ __forceinline__ unsigned short f2b(float x) {
    unsigned u = __float_as_uint(x);
    unsigned r = (u + 0x7fff + ((u >> 16) & 1)) >> 16;  // RNE
    return (unsigned short)r;
}
__device__ __forceinline__ float b2f(unsigned short v) {
    return __uint_as_float(((unsigned)v) << 16);
}
__device__ __forceinline__ float fsigmoid(float x) { return 1.0f / (1.0f + __expf(-x)); }
__device__ __forceinline__ float ftanh(float x) { return 1.0f - 2.0f / (__expf(2.0f * x) + 1.0f); }

__device__ __forceinline__ f32x4 mfma16(s16x8 a, s16x8 b, f32x4 c) {
    return __builtin_amdgcn_mfma_f32_16x16x32_bf16(a, b, c, 0, 0, 0);
}

// ---- coherent (LLC-point, fence-free) access helpers ----
__device__ __forceinline__ u64 cld64(const void* p) {
    return __hip_atomic_load((const u64*)p, __ATOMIC_RELAXED, __HIP_MEMORY_SCOPE_AGENT);
}
__device__ __forceinline__ void cst64(void* p, u64 v) {
    __hip_atomic_store((u64*)p, v, __ATOMIC_RELAXED, __HIP_MEMORY_SCOPE_AGENT);
}
__device__ __forceinline__ unsigned cld32(const void* p) {
    return __hip_atomic_load((const unsigned*)p, __ATOMIC_RELAXED, __HIP_MEMORY_SCOPE_AGENT);
}
__device__ __forceinline__ void cst32(void* p, unsigned v) {
    __hip_atomic_store((unsigned*)p, v, __ATOMIC_RELAXED, __HIP_MEMORY_SCOPE_AGENT);
}
__device__ __forceinline__ s16x8 cld_frag(const unsigned short* p) {
    union { u64 q[2]; s16x8 v; } u;
    u.q[0] = cld64(p);
    u.q[1] = cld64(p + 4);
    return u.v;
}

// ---- replicated-flag sync: writer posts NREP copies; pollers use replica rep ----
__device__ __forceinline__ void postflag(unsigned* flags, int base, int id, unsigned ep)
{
    if (threadIdx.x < NREP)
        cst32(&flags[((long)threadIdx.x * NFID + base + id) * FPAD], ep);
}
__device__ __forceinline__ void waitflags(const unsigned* flags, int base, int n,
                                          unsigned ep, int rep)
{
    const unsigned* fr = flags + (long)rep * NFID * FPAD;
    if (threadIdx.x < 64) {
#pragma unroll 1
        for (int i = threadIdx.x; i < n; i += 64)
            while (cld32(&fr[(long)(base + i) * FPAD]) < ep)
                __builtin_amdgcn_s_sleep(2);
    }
    __syncthreads();
}
__device__ __forceinline__ void fbar(unsigned* flags, int base, int nb, unsigned ep)
{
    __syncthreads();   // drains vmcnt per wave before s_barrier
    postflag(flags, base, blockIdx.x & 63, ep);
    waitflags(flags, base, nb, ep, blockIdx.x & 7);
}

// flag id bases
#define FB_GRUP 0
#define FB_GRUH 64
#define FB_LF   128
#define FB_UF   256
#define FB_SF   288

// ---------------- generic MFMA GEMM (precompute only) ----------------
// permC: output row m = b*T+t remapped to t*B+b
template<typename AT, bool OB>
__global__ __launch_bounds__(256)
void mfma_gemm(const AT* __restrict__ A, const int* __restrict__ idxA,
               const unsigned short* __restrict__ Wb, const float* __restrict__ bias,
               void* __restrict__ Cv,
               int M, int N, int K, int ldA, int Kpad, int ldC, int permC)
{
    __shared__ unsigned short As[64][40];
    __shared__ unsigned short Bs[64][40];
    const int tid = threadIdx.x;
    const int wv = tid >> 6, lane = tid & 63;
    const int wm = wv >> 1, wn = wv & 1;
    const int m0 = blockIdx.y * 64, n0 = blockIdx.x * 64;

    f32x4 acc[2][2] = {{{0.f,0.f,0.f,0.f},{0.f,0.f,0.f,0.f}},
                       {{0.f,0.f,0.f,0.f},{0.f,0.f,0.f,0.f}}};
    const int r_st = tid >> 2, k_st = (tid & 3) * 8;

    long arow = -1;
    {
        int gm = m0 + r_st;
        if (gm < M) arow = idxA ? (long)idxA[gm] : (long)gm;
    }

    const int kIters = (K + 31) / 32;
    for (int it = 0; it < kIters; ++it) {
        const int kg = it * 32 + k_st;
        {
            s16x8 pk = {0,0,0,0,0,0,0,0};
            if (arow >= 0) {
                if constexpr (sizeof(AT) == 2) {
                    if (kg + 8 <= K) {
                        pk = *(const s16x8*)((const unsigned short*)A + arow * (long)ldA + kg);
                    } else {
#pragma unroll
                        for (int j = 0; j < 8; ++j)
                            if (kg + j < K) pk[j] = (short)((const unsigned short*)A)[arow * (long)ldA + kg + j];
                    }
                } else {
                    if (kg + 8 <= K) {
                        const float* p = (const float*)A + arow * (long)ldA + kg;
                        f32x4 u0 = *(const f32x4*)p;
                        f32x4 u1 = *(const f32x4*)(p + 4);
#pragma unroll
                        for (int j = 0; j < 4; ++j) { pk[j] = (short)f2b(u0[j]); pk[4+j] = (short)f2b(u1[j]); }
                    } else {
#pragma unroll
                        for (int j = 0; j < 8; ++j) {
                            int kk = kg + j;
                            if (kk < K) pk[j] = (short)f2b(((const float*)A)[arow * (long)ldA + kk]);
                        }
                    }
                }
            }
            *(s16x8*)&As[r_st][k_st] = pk;
        }
        {
            int gn = n0 + r_st;
            s16x8 pk = {0,0,0,0,0,0,0,0};
            if (gn < N) pk = *(const s16x8*)&Wb[(long)gn * Kpad + kg];
            *(s16x8*)&Bs[r_st][k_st] = pk;
        }
        __syncthreads();
        {
            const int koff = (lane >> 4) * 8;
            s16x8 af[2], bfr[2];
#pragma unroll
            for (int f = 0; f < 2; ++f) {
                af[f]  = *(s16x8*)&As[wm * 32 + f * 16 + (lane & 15)][koff];
                bfr[f] = *(s16x8*)&Bs[wn * 32 + f * 16 + (lane & 15)][koff];
            }
#pragma unroll
            for (int fi = 0; fi < 2; ++fi)
#pragma unroll
                for (int fj = 0; fj < 2; ++fj)
                    acc[fi][fj] = mfma16(af[fi], bfr[fj], acc[fi][fj]);
        }
        __syncthreads();
    }
#pragma unroll
    for (int fi = 0; fi < 2; ++fi)
#pragma unroll
        for (int fj = 0; fj < 2; ++fj)
#pragma unroll
            for (int r = 0; r < 4; ++r) {
                int m = m0 + wm * 32 + fi * 16 + (lane >> 4) * 4 + r;
                int n = n0 + wn * 32 + fj * 16 + (lane & 15);
                if (m < M && n < N) {
                    float v = acc[fi][fj][r];
                    if (bias) v += bias[n];
                    long mo = permC ? ((long)(m & 127) * B_SZ + (m >> 7)) : (long)m;
                    if constexpr (OB) ((unsigned short*)Cv)[mo * ldC + n] = f2b(v);
                    else               ((float*)Cv)[mo * ldC + n] = v;
                }
            }
}

// ---------------- persistent GRU chain ----------------
#define GRU_NB 64
__global__ __launch_bounds__(256, 1)
void gru_chain(const unsigned short* __restrict__ Whh_b, const float* __restrict__ GI,
               const float* __restrict__ bhh, const int* __restrict__ toks,
               float* __restrict__ h32,
               unsigned short* __restrict__ h16a, unsigned short* __restrict__ h16b,
               unsigned short* __restrict__ o_bt,
               unsigned* __restrict__ flags, int fbase)
{
    __shared__ unsigned short wlds[3][16][512];   // 48 KB
    __shared__ unsigned short ht[64][20];         // transpose buffer
    const int tid = threadIdx.x;
    const int wv = tid >> 6, lane = tid & 63;
    const int dt = blockIdx.x & 31, bh = blockIdx.x >> 5;
    const int b0 = bh * 64;

    for (int s = 0; s < 12; ++s) {
        int slot = tid + s * 256;
        int g = slot >> 10, rem = slot & 1023, ks = rem >> 6, ln = rem & 63;
        int row = g * ND + dt * 16 + (ln & 15);
        int k = ks * 32 + (ln >> 4) * 8;
        *(s16x8*)&wlds[g][ks][ln * 8] = *(const s16x8*)&Whh_b[(long)row * ND + k];
    }
    __syncthreads();

    const int d = dt * 16 + (lane & 15);
    const int brow = b0 + wv * 16 + (lane >> 4) * 4;
    const int arow = b0 + wv * 16 + (lane & 15);
    const int akoff = (lane >> 4) * 8;

    float hreg[4];
#pragma unroll
    for (int rr = 0; rr < 4; ++rr) hreg[rr] = h32[(long)(brow + rr) * ND + d];

    float o_run[4] = {0.f, 0.f, 0.f, 0.f};
    unsigned ep = 0;

    for (int t = 0; t < T_SZ; ++t) {
        const unsigned short* hin16 = (t & 1) ? h16b : h16a;
        unsigned short* hout16 = (t & 1) ? h16a : h16b;

        const float* git = GI + (long)t * (B_SZ * G3);
        float gi_r[4], gi_z[4], gi_n[4]; int mk[4];
#pragma unroll
        for (int rr = 0; rr < 4; ++rr) {
            int b = brow + rr;
            gi_r[rr] = git[(long)b * G3 + d];
            gi_z[rr] = git[(long)b * G3 + ND + d];
            gi_n[rr] = git[(long)b * G3 + 2 * ND + d];
            mk[rr]   = toks[b * T_SZ + t];
        }

        f32x4 acc0 = {0,0,0,0}, acc1 = {0,0,0,0}, acc2 = {0,0,0,0};
#pragma unroll
        for (int ks = 0; ks < 16; ++ks) {
            s16x8 a  = cld_frag(&hin16[(long)arow * ND + ks * 32 + akoff]);
            s16x8 br = *(s16x8*)&wlds[0][ks][lane * 8];
            s16x8 bz = *(s16x8*)&wlds[1][ks][lane * 8];
            s16x8 bn = *(s16x8*)&wlds[2][ks][lane * 8];
            acc0 = mfma16(a, br, acc0);
            acc1 = mfma16(a, bz, acc1);
            acc2 = mfma16(a, bn, acc2);
        }

#pragma unroll
        for (int rr = 0; rr < 4; ++rr) {
            int b = brow + rr;
            float rg = fsigmoid(gi_r[rr] + acc0[rr] + bhh[d]);
            float zg = fsigmoid(gi_z[rr] + acc1[rr] + bhh[ND + d]);
            float ng = ftanh(gi_n[rr] + rg * (acc2[rr] + bhh[2 * ND + d]));
            float hr = (1.0f - zg) * ng + zg * hreg[rr];
            bool m = mk[rr] != 0;
            float hn = m ? hr : hreg[rr];
            hreg[rr] = hn;
            ht[b - b0][lane & 15] = f2b(hn);
            if (t == T_SZ - 1) h32[(long)b * ND + d] = hn;
            o_run[rr] = (t == 0) ? hr : (m ? hr : o_run[rr]);
            o_bt[((long)b * T_SZ + t) * ND + d] = f2b(o_run[rr]);
        }
        __syncthreads();
        {
            int bl = tid & 63, dq = tid >> 6;
            u64 v = *(u64*)&ht[bl][dq * 4];
            cst64(&hout16[(long)(b0 + bl) * ND + dt * 16 + dq * 4], v);   // coherent
        }
        fbar(flags, fbase, GRU_NB, ++ep);
    }
}

// ---------------- persistent match chain: 160 blocks, role-split ----------------
#define UP_NB 32
#define YPITCH 536   // 268 words, 268 % 32 = 12 -> 3*tp bank rotation (conflict-free)
__global__ __launch_bounds__(256, 1)
void match_chain(const unsigned short* __restrict__ WrT_b,
                 const unsigned short* __restrict__ mWihL_b,
                 const unsigned short* __restrict__ mWhh_b,
                 const unsigned short* __restrict__ OHWh_tb,
                 const unsigned short* __restrict__ OHGI_tb,
                 const float* __restrict__ m_bhh, const float* __restrict__ Walpha,
                 const unsigned short* __restrict__ Yw_bb,
                 const unsigned short* __restrict__ Y_bb,
                 const int* __restrict__ prem, const int* __restrict__ hyp,
                 float* __restrict__ r32,
                 unsigned short* __restrict__ r16a, unsigned short* __restrict__ r16b,
                 unsigned short* __restrict__ a16, unsigned short* __restrict__ s16,
                 unsigned* __restrict__ flags)
{
    __shared__ __align__(16) unsigned char smem[157696];
    const int tid = threadIdx.x;
    const int wv = tid >> 6, lane = tid & 63;

    if (blockIdx.x < 128) {
        // ================= LOW: attention for b = blockIdx.x =================
        const int b = blockIdx.x;
        const int rep = b & 7;
        unsigned short (*ywl)[YPITCH] = (unsigned short(*)[YPITCH])smem;     // 137.2 KB
        float* wal  = (float*)(smem + 137216);                               // 2 KB
        float* sarr = (float*)(smem + 139264);                               // 2 KB
        float* part = (float*)(smem + 141312);                               // 1 KB
        float* lg   = (float*)(smem + 142336);                               // 512 B
        float* red  = (float*)(smem + 142848);                               // 32 B
        float* sr2  = (float*)(smem + 142880);                               // 2 KB

        for (int s = 0; s < 32; ++s) {
            int c = s * 256 + tid;
            int row = c >> 6, cg = c & 63;
            *(s16x8*)&ywl[row][cg * 8] =
                *(const s16x8*)&Yw_bb[((long)b * T_SZ + row) * ND + cg * 8];
        }
        if (tid < 128) {
            f32x4 w = *(const f32x4*)&Walpha[tid * 4];
            *(f32x4*)&wal[tid * 4] = w;
        }
        float mmreg = 0.f;
        if (tid < 128) mmreg = (prem[b * T_SZ + tid] != 0) ? 0.f : 1000.f;
        __syncthreads();

        const int tp = tid >> 1, gh = tid & 1;
        const unsigned short* yrow = &ywl[tp][gh * 256];
        const float* sp  = &sarr[gh * 256];
        const float* wap = &wal[gh * 256];
        const int g = tid >> 7, lt = tid & 127, n4 = lt * 4;

        for (int t = 0; t < T_SZ; ++t) {
            waitflags(flags, FB_SF, UP_NB, (unsigned)(t + 1), rep);
            if (tid < 64) {
                s16x8 q = cld_frag(&s16[(long)b * ND + tid * 8]);
#pragma unroll
                for (int j = 0; j < 8; ++j) sarr[tid * 8 + j] = b2f((unsigned short)q[j]);
            }
            __syncthreads();
            // logits partial over 256 d's (no cross-lane ops)
            {
                float acc = 0.f;
#pragma unroll 4
                for (int i8 = 0; i8 < 32; ++i8) {
                    s16x8 yw = *(const s16x8*)&yrow[i8 * 8];
                    f32x4 s0 = *(const f32x4*)&sp[i8 * 8];
                    f32x4 s1 = *(const f32x4*)&sp[i8 * 8 + 4];
                    f32x4 w0 = *(const f32x4*)&wap[i8 * 8];
                    f32x4 w1 = *(const f32x4*)&wap[i8 * 8 + 4];
#pragma unroll
                    for (int j = 0; j < 4; ++j)
                        acc += ftanh(b2f((unsigned short)yw[j]) + s0[j]) * w0[j];
#pragma unroll
                    for (int j = 0; j < 4; ++j)
                        acc += ftanh(b2f((unsigned short)yw[4 + j]) + s1[j]) * w1[j];
                }
                part[tid] = acc;
            }
            __syncthreads();
            // no-max exp (logit bounded by sum|Walpha| << 88; masked -> underflow 0)
            if (tid < 128) lg[tid] = __expf(part[tid * 2] + part[tid * 2 + 1] - mmreg);
            __syncthreads();
            // unnormalized weighted sum + inline denominator
            float suml = 0.f;
            f32x4 acw = {0.f, 0.f, 0.f, 0.f};
#pragma unroll 8
            for (int i = 0; i < 64; ++i) {
                int tpp = g * 64 + i;
                float al = lg[tpp];
                suml += al;
                u64 q = *(const u64*)&Y_bb[((long)b * T_SZ + tpp) * ND + n4];
                acw[0] += al * b2f((unsigned short)q);
                acw[1] += al * b2f((unsigned short)(q >> 16));
                acw[2] += al * b2f((unsigned short)(q >> 32));
                acw[3] += al * b2f((unsigned short)(q >> 48));
            }
            if (g == 1) {
                *(f32x4*)&sr2[n4] = acw;
                if (lt == 0) red[0] = suml;
            }
            __syncthreads();
            if (g == 0) {
                float inv = 1.0f / (suml + red[0]);
                f32x4 o = *(f32x4*)&sr2[n4];
                u64 pk = (u64)f2b((acw[0] + o[0]) * inv) | ((u64)f2b((acw[1] + o[1]) * inv) << 16)
                       | ((u64)f2b((acw[2] + o[2]) * inv) << 32) | ((u64)f2b((acw[3] + o[3]) * inv) << 48);
                cst64(&a16[(long)b * ND + n4], pk);
            }
            __syncthreads();
            postflag(flags, FB_LF, b, (unsigned)(t + 1));
        }
    } else {
        // ================= UP: gates + s + combine; d-slice ug*16..+16 =================
        const int ug = blockIdx.x - 128;
        const int rep = ug & 7;
        unsigned short (*wA)[16][512] = (unsigned short(*)[16][512])smem;           // 48 KB
        unsigned short (*wR)[16][512] = (unsigned short(*)[16][512])(smem + 49152); // 64 KB
        float (*bounce)[84] = (float(*)[84])(smem + 49152 + 65536);                 // 43 KB

        for (int s = 0; s < 12; ++s) {
            int slot = tid + s * 256;
            int fam = slot >> 10, rem = slot & 1023, ks = rem >> 6, ln = rem & 63;
            int row = fam * ND + ug * 16 + (ln & 15);
            int k = ks * 32 + (ln >> 4) * 8;
            *(s16x8*)&wA[fam][ks][ln * 8] = *(const s16x8*)&mWihL_b[(long)row * ND + k];
        }
        for (int s = 0; s < 16; ++s) {
            int slot = tid + s * 256;
            int fam = slot >> 10, rem = slot & 1023, ks = rem >> 6, ln = rem & 63;
            int k = ks * 32 + (ln >> 4) * 8;
            const unsigned short* src = (fam < 3)
                ? &mWhh_b[(long)(fam * ND + ug * 16 + (ln & 15)) * ND + k]
                : &WrT_b[(long)(ug * 16 + (ln & 15)) * ND + k];
            *(s16x8*)&wR[fam][ks][ln * 8] = *(const s16x8*)src;
        }
        __syncthreads();

        const int akoff = (lane >> 4) * 8;
        const int cb = tid >> 1;
        const int half = tid & 1;
        const int d0 = ug * 16 + half * 8;

        f32x4 rpA = {0,0,0,0}, rpB = {0,0,0,0};   // r-state in registers

        for (int t = 0; t < T_SZ; ++t) {
            // ---- prefetch step-t [t][b] slabs (flag-independent) ----
            const unsigned short* ohw = &OHWh_tb[((long)t * B_SZ + cb) * ND + d0];
            u64 qa = *(const u64*)ohw;
            u64 qb = *(const u64*)(ohw + 4);
            const unsigned short* og = &OHGI_tb[((long)t * B_SZ + cb) * G3];
            u64 q0a = *(const u64*)&og[d0];            u64 q0b = *(const u64*)&og[d0 + 4];
            u64 q1a = *(const u64*)&og[ND + d0];       u64 q1b = *(const u64*)&og[ND + d0 + 4];
            u64 q2a = *(const u64*)&og[2 * ND + d0];   u64 q2b = *(const u64*)&og[2 * ND + d0 + 4];
            int hv = hyp[cb * T_SZ + t];

            waitflags(flags, FB_UF, UP_NB, (unsigned)t, rep);
            const unsigned short* r16rd = (t & 1) ? r16b : r16a;
            unsigned short*       r16wr = (t & 1) ? r16a : r16b;

            // ---- r-phase: {SR,SZ,GHN,S} over full r rows ----
            f32x4 aSR[2] = {{0,0,0,0},{0,0,0,0}}, aSZ[2] = {{0,0,0,0},{0,0,0,0}};
            f32x4 aHN[2] = {{0,0,0,0},{0,0,0,0}}, aS[2]  = {{0,0,0,0},{0,0,0,0}};
            f32x4 aGN[2] = {{0,0,0,0},{0,0,0,0}};
#pragma unroll
            for (int f = 0; f < 2; ++f) {
                int row = wv * 32 + f * 16 + (lane & 15);
#pragma unroll
                for (int ks = 0; ks < 16; ++ks) {
                    s16x8 a = cld_frag(&r16rd[(long)row * ND + ks * 32 + akoff]);
                    aSR[f] = mfma16(a, *(s16x8*)&wR[0][ks][lane * 8], aSR[f]);
                    aSZ[f] = mfma16(a, *(s16x8*)&wR[1][ks][lane * 8], aSZ[f]);
                    aHN[f] = mfma16(a, *(s16x8*)&wR[2][ks][lane * 8], aHN[f]);
                    aS[f]  = mfma16(a, *(s16x8*)&wR[3][ks][lane * 8], aS[f]);
                }
            }
#pragma unroll
            for (int f = 0; f < 2; ++f)
#pragma unroll
                for (int rr = 0; rr < 4; ++rr)
                    bounce[wv * 32 + f * 16 + (lane >> 4) * 4 + rr][64 + (lane & 15)] = aS[f][rr];
            __syncthreads();
            {
                u64 w0 = 0, w1 = 0;
#pragma unroll
                for (int j = 0; j < 4; ++j) {
                    float v0 = bounce[cb][64 + half * 8 + j]     + b2f((unsigned short)(qa >> (16 * j)));
                    float v1 = bounce[cb][64 + half * 8 + 4 + j] + b2f((unsigned short)(qb >> (16 * j)));
                    w0 |= (u64)f2b(v0) << (16 * j);
                    w1 |= (u64)f2b(v1) << (16 * j);
                }
                cst64(&s16[(long)cb * ND + d0], w0);
                cst64(&s16[(long)cb * ND + d0 + 4], w1);
            }
            __syncthreads();
            postflag(flags, FB_SF, ug, (unsigned)(t + 1));

            // ---- a-phase: {SR,SZ,GIN} over full a rows ----
            waitflags(flags, FB_LF, 128, (unsigned)(t + 1), rep);
#pragma unroll
            for (int f = 0; f < 2; ++f) {
                int row = wv * 32 + f * 16 + (lane & 15);
#pragma unroll
                for (int ks = 0; ks < 16; ++ks) {
                    s16x8 a = cld_frag(&a16[(long)row * ND + ks * 32 + akoff]);
                    aSR[f] = mfma16(a, *(s16x8*)&wA[0][ks][lane * 8], aSR[f]);
                    aSZ[f] = mfma16(a, *(s16x8*)&wA[1][ks][lane * 8], aSZ[f]);
                    aGN[f] = mfma16(a, *(s16x8*)&wA[2][ks][lane * 8], aGN[f]);
                }
            }
#pragma unroll
            for (int f = 0; f < 2; ++f)
#pragma unroll
                for (int rr = 0; rr < 4; ++rr) {
                    int bb = wv * 32 + f * 16 + (lane >> 4) * 4 + rr;
                    bounce[bb][0  + (lane & 15)] = aSR[f][rr];
                    bounce[bb][16 + (lane & 15)] = aSZ[f][rr];
                    bounce[bb][32 + (lane & 15)] = aGN[f][rr];
                    bounce[bb][48 + (lane & 15)] = aHN[f][rr];
                }
            __syncthreads();
            {
                bool mkk = hv != 0;
                u64 w0 = 0, w1 = 0;
#pragma unroll
                for (int j = 0; j < 8; ++j) {
                    int dl = half * 8 + j;
                    int dd = ug * 16 + dl;
                    u64 qg0 = (j < 4) ? q0a : q0b;
                    u64 qg1 = (j < 4) ? q1a : q1b;
                    u64 qg2 = (j < 4) ? q2a : q2b;
                    int sh = 16 * (j & 3);
                    float sr  = bounce[cb][0 + dl]  + b2f((unsigned short)(qg0 >> sh)) + m_bhh[dd];
                    float sz  = bounce[cb][16 + dl] + b2f((unsigned short)(qg1 >> sh)) + m_bhh[ND + dd];
                    float gin = bounce[cb][32 + dl] + b2f((unsigned short)(qg2 >> sh));
                    float ghn = bounce[cb][48 + dl] + m_bhh[2 * ND + dd];
                    float rg = fsigmoid(sr), zg = fsigmoid(sz);
                    float ng = ftanh(gin + rg * ghn);
                    float rp = (j < 4) ? rpA[j & 3] : rpB[j & 3];
                    float rn = (1.0f - zg) * ng + zg * rp;
                    float v = mkk ? rn : rp;
                    if (j < 4) rpA[j & 3] = v; else rpB[j & 3] = v;
                    if (j < 4) w0 |= (u64)f2b(v) << sh; else w1 |= (u64)f2b(v) << sh;
                }
                if (t == T_SZ - 1) {
                    *(f32x4*)&r32[(long)cb * ND + d0] = rpA;
                    *(f32x4*)&r32[(long)cb * ND + d0 + 4] = rpB;
                }
                cst64(&r16wr[(long)cb * ND + d0], w0);
                cst64(&r16wr[(long)cb * ND + d0 + 4], w1);
            }
            __syncthreads();
            postflag(flags, FB_UF, ug, (unsigned)(t + 1));
        }
    }
}

// ---------------- prep / misc ----------------
__global__ void prep_idx(const int* __restrict__ prem, const int* __restrict__ hyp,
                         int* __restrict__ idx_p, int* __restrict__ idx_h)
{
    int i = blockIdx.x * blockDim.x + threadIdx.x;
    if (i < B_SZ * T_SZ) {
        int t = i / B_SZ, b = i % B_SZ;
        idx_p[i] = prem[b * T_SZ + t];
        idx_h[i] = hyp[b * T_SZ + t];
    }
}

__global__ void conv_w(const float* __restrict__ in, unsigned short* __restrict__ out,
                       int N, int K, int Kpad, int ldIn, int colOff)
{
    long i = (long)blockIdx.x * blockDim.x + threadIdx.x;
    if (i >= (long)N * Kpad) return;
    int n = (int)(i / Kpad), k = (int)(i % Kpad);
    float v = (k < K) ? in[(long)n * ldIn + k + colOff] : 0.0f;
    out[i] = f2b(v);
}

__global__ void conv_wT(const float* __restrict__ in, unsigned short* __restrict__ out,
                        int N, int K, int Kpad, int ldIn)
{
    long i = (long)blockIdx.x * blockDim.x + threadIdx.x;
    if (i >= (long)N * Kpad) return;
    int n = (int)(i / Kpad), k = (int)(i % Kpad);
    float v = (k < K) ? in[(long)k * ldIn + n] : 0.0f;
    out[i] = f2b(v);
}

__global__ void zero_kernel(float* __restrict__ p, int n)
{
    int i = blockIdx.x * blockDim.x + threadIdx.x;
    if (i < n) p[i] = 0.0f;
}

__global__ void final_logits(const float* __restrict__ r, const float* __restrict__ outW,
                             const float* __restrict__ outb, float* __restrict__ out)
{
    int b = blockIdx.x;
    int lane = threadIdx.x;
    float a0 = 0.0f, a1 = 0.0f, a2 = 0.0f;
    for (int k = lane; k < ND; k += 64) {
        float rv = r[(long)b * ND + k];
        a0 += rv * outW[0 * ND + k];
        a1 += rv * outW[1 * ND + k];
        a2 += rv * outW[2 * ND + k];
    }
#pragma unroll
    for (int off = 32; off; off >>= 1) {
        a0 += __shfl_down(a0, off);
        a1 += __shfl_down(a1, off);
        a2 += __shfl_down(a2, off);
    }
    if (lane == 0) {
        float l0 = a0 + outb[0], l1 = a1 + outb[1], l2 = a2 + outb[2];
        float mx = fmaxf(l0, fmaxf(l1, l2));
        float se = expf(l0 - mx) + expf(l1 - mx) + expf(l2 - mx);
        float ls = mx + logf(se);
        out[b * 3 + 0] = l0 - ls;
        out[b * 3 + 1] = l1 - ls;
        out[b * 3 + 2] = l2 - ls;
    }
}

// ---------------- host ----------------
extern "C" void kernel_launch(void* const* d_in, const int* in_sizes, int n_in,
                              void* d_out, int out_size, void* d_ws, size_t ws_size,
                              hipStream_t stream)
{
    const int*   prem    = (const int*)d_in[0];
    const int*   hyp     = (const int*)d_in[1];
    const float* E       = (const float*)d_in[2];
    const float* p_Wih   = (const float*)d_in[3];
    const float* p_Whh   = (const float*)d_in[4];
    const float* p_bih   = (const float*)d_in[5];
    const float* p_bhh   = (const float*)d_in[6];
    const float* h_Wih   = (const float*)d_in[7];
    const float* h_Whh   = (const float*)d_in[8];
    const float* h_bih   = (const float*)d_in[9];
    const float* h_bhh   = (const float*)d_in[10];
    const float* m_Wih   = (const float*)d_in[11];
    const float* m_Whh   = (const float*)d_in[12];
    const float* m_bih   = (const float*)d_in[13];
    const float* m_bhh   = (const float*)d_in[14];
    const float* W_y     = (const float*)d_in[15];
    const float* W_h     = (const float*)d_in[16];
    const float* W_r     = (const float*)d_in[17];
    const float* W_alpha = (const float*)d_in[18];
    const float* out_W   = (const float*)d_in[19];
    const float* out_b   = (const float*)d_in[20];
    float* out = (float*)d_out;

    const int MB = T_SZ * B_SZ;  // 16384
    const int NFLAGS = NREP * NFID * FPAD;  // 81920 words

    float* ws = (float*)d_ws;
    size_t off = 0;
    float* GI    = ws + off; off += (size_t)MB * G3;
    float* h32   = ws + off; off += (size_t)B_SZ * ND;
    float* r32   = ws + off; off += (size_t)B_SZ * ND;
    unsigned* flags = (unsigned*)(ws + off); off += NFLAGS;
    int* idx_p = (int*)(ws + off); off += (size_t)B_SZ * T_SZ;
    int* idx_h = (int*)(ws + off); off += (size_t)B_SZ * T_SZ;
    unsigned short* ub = (unsigned short*)(ws + off);
    size_t uoff = 0;
    unsigned short* o_p_bt = ub + uoff; uoff += (size_t)MB * ND;   // Y_bb
    unsigned short* o_h_bt = ub + uoff; uoff += (size_t)MB * ND;
    unsigned short* Yw_bb  = ub + uoff; uoff += (size_t)MB * ND;
    unsigned short* OHWh_tb= ub + uoff; uoff += (size_t)MB * ND;
    unsigned short* OHGI_tb= ub + uoff; uoff += (size_t)MB * G3;
    unsigned short* h16a   = ub + uoff; uoff += (size_t)B_SZ * ND;
    unsigned short* h16b   = ub + uoff; uoff += (size_t)B_SZ * ND;
    unsigned short* r16a   = ub + uoff; uoff += (size_t)B_SZ * ND;
    unsigned short* r16b   = ub + uoff; uoff += (size_t)B_SZ * ND;
    unsigned short* a16    = ub + uoff; uoff += (size_t)B_SZ * ND;
    unsigned short* s16    = ub + uoff; uoff += (size_t)B_SZ * ND;
    unsigned short* pWih_b = ub + uoff; uoff += (size_t)G3 * 320;
    unsigned short* hWih_b = ub + uoff; uoff += (size_t)G3 * 320;
    unsigned short* pWhh_b = ub + uoff; uoff += (size_t)G3 * ND;
    unsigned short* hWhh_b = ub + uoff; uoff += (size_t)G3 * ND;
    unsigned short* mWihL_b= ub + uoff; uoff += (size_t)G3 * ND;
    unsigned short* mWihR  = ub + uoff; uoff += (size_t)G3 * ND;
    unsigned short* mWhh_b = ub + uoff; uoff += (size_t)G3 * ND;
    unsigned short* WyT_b  = ub + uoff; uoff += (size_t)ND * ND;
    unsigned short* WhT_b  = ub + uoff; uoff += (size_t)ND * ND;
    unsigned short* WrT_b  = ub + uoff; uoff += (size_t)ND * ND;
    off += (uoff + 1) / 2;
    if (ws_size < off * sizeof(float)) return;

    auto cblk = [](long n) { return (int)((n + 255) / 256); };

    // ---- prep ----
    prep_idx<<<cblk(MB), 256, 0, stream>>>(prem, hyp, idx_p, idx_h);
    conv_w <<<cblk((long)G3 * 320), 256, 0, stream>>>(p_Wih, pWih_b, G3, EMBD, 320, EMBD, 0);
    conv_w <<<cblk((long)G3 * 320), 256, 0, stream>>>(h_Wih, hWih_b, G3, EMBD, 320, EMBD, 0);
    conv_w <<<cblk((long)G3 * ND), 256, 0, stream>>>(p_Whh, pWhh_b, G3, ND, ND, ND, 0);
    conv_w <<<cblk((long)G3 * ND), 256, 0, stream>>>(h_Whh, hWhh_b, G3, ND, ND, ND, 0);
    conv_w <<<cblk((long)G3 * ND), 256, 0, stream>>>(m_Wih, mWihL_b, G3, ND, ND, 2 * ND, 0);
    conv_w <<<cblk((long)G3 * ND), 256, 0, stream>>>(m_Wih, mWihR, G3, ND, ND, 2 * ND, ND);
    conv_w <<<cblk((long)G3 * ND), 256, 0, stream>>>(m_Whh, mWhh_b, G3, ND, ND, ND, 0);
    conv_wT<<<cblk((long)ND * ND), 256, 0, stream>>>(W_y, WyT_b, ND, ND, ND, ND);
    conv_wT<<<cblk((long)ND * ND), 256, 0, stream>>>(W_h, WhT_b, ND, ND, ND, ND);
    conv_wT<<<cblk((long)ND * ND), 256, 0, stream>>>(W_r, WrT_b, ND, ND, ND, ND);
    zero_kernel<<<cblk(B_SZ * ND), 256, 0, stream>>>(h32, B_SZ * ND);
    zero_kernel<<<cblk(B_SZ * ND / 2), 256, 0, stream>>>((float*)h16a, B_SZ * ND / 2);
    zero_kernel<<<cblk(B_SZ * ND), 256, 0, stream>>>(r32, B_SZ * ND);
    zero_kernel<<<cblk(B_SZ * ND / 2), 256, 0, stream>>>((float*)r16a, B_SZ * ND / 2);
    zero_kernel<<<cblk(B_SZ * ND / 2), 256, 0, stream>>>((float*)r16b, B_SZ * ND / 2);
    zero_kernel<<<cblk(NFLAGS), 256, 0, stream>>>((float*)flags, NFLAGS);

    // ---- premise ----
    {
        dim3 g(G3 / 64, MB / 64);
        mfma_gemm<float, false><<<g, 256, 0, stream>>>(E, idx_p, pWih_b, p_bih, GI,
                                                       MB, G3, EMBD, EMBD, 320, G3, 0);
    }
    gru_chain<<<GRU_NB, 256, 0, stream>>>(pWhh_b, GI, p_bhh, prem, h32, h16a, h16b,
                                          o_p_bt, flags, FB_GRUP);

    // ---- hypothesis ----
    {
        dim3 g(G3 / 64, MB / 64);
        mfma_gemm<float, false><<<g, 256, 0, stream>>>(E, idx_h, hWih_b, h_bih, GI,
                                                       MB, G3, EMBD, EMBD, 320, G3, 0);
    }
    gru_chain<<<GRU_NB, 256, 0, stream>>>(hWhh_b, GI, h_bhh, hyp, h32, h16a, h16b,
                                          o_h_bt, flags, FB_GRUH);

    // ---- attention precompute ----
    {
        dim3 g(ND / 64, MB / 64);
        mfma_gemm<unsigned short, true><<<g, 256, 0, stream>>>(o_p_bt, nullptr, WyT_b, nullptr,
                                                               Yw_bb, MB, ND, ND, ND, ND, ND, 0);
        mfma_gemm<unsigned short, true><<<g, 256, 0, stream>>>(o_h_bt, nullptr, WhT_b, nullptr,
                                                               OHWh_tb, MB, ND, ND, ND, ND, ND, 1);
        dim3 g2(G3 / 64, MB / 64);
        mfma_gemm<unsigned short, true><<<g2, 256, 0, stream>>>(o_h_bt, nullptr, mWihR, m_bih,
                                                                OHGI_tb, MB, G3, ND, ND, ND, G3, 1);
    }

    // ---- match chain (160 blocks: 128 LOW + 32 UP) ----
    match_chain<<<160, 256, 0, stream>>>(WrT_b, mWihL_b, mWhh_b, OHWh_tb, OHGI_tb,
                                         m_bhh, W_alpha, Yw_bb, o_p_bt, prem, hyp,
                                         r32, r16a, r16b, a16, s16, flags);

    final_logits<<<B_SZ, 64, 0, stream>>>(r32, out_W, out_b, out);
}

// Round 12
// 6665.828 us; speedup vs baseline: 2.5297x; 1.0538x over previous
//
#include <hip/hip_runtime.h>
#include <math.h>

#define B_SZ 128
#define T_SZ 128
#define EMBD 300
#define ND 512
#define G3 1536
#define FPAD 32    // flag padding stride (u32s) = 128 B
#define NFID 320   // flag ids per replica
#define NREP 8     // flag replicas

typedef short s16x8 __attribute__((ext_vector_type(8)));
typedef float f32x4 __attribute__((ext_vector_type(4)));
typedef unsigned long long u64;

__device__ __forceinline__ unsigned short f2b(float x) {
    unsigned u = __float_as_uint(x);
    unsigned r = (u + 0x7fff + ((u >> 16) & 1)) >> 16;  // RNE
    return (unsigned short)r;
}
__device__ __forceinline__ float b2f(unsigned short v) {
    return __uint_as_float(((unsigned)v) << 16);
}
__device__ __forceinline__ float fsigmoid(float x) { return 1.0f / (1.0f + __expf(-x)); }
__device__ __forceinline__ float ftanh(float x) { return 1.0f - 2.0f / (__expf(2.0f * x) + 1.0f); }

__device__ __forceinline__ f32x4 mfma16(s16x8 a, s16x8 b, f32x4 c) {
    return __builtin_amdgcn_mfma_f32_16x16x32_bf16(a, b, c, 0, 0, 0);
}

// ---- coherent (LLC-point, fence-free) access helpers ----
__device__ __forceinline__ u64 cld64(const void* p) {
    return __hip_atomic_load((const u64*)p, __ATOMIC_RELAXED, __HIP_MEMORY_SCOPE_AGENT);
}
__device__ __forceinline__ void cst64(void* p, u64 v) {
    __hip_atomic_store((u64*)p, v, __ATOMIC_RELAXED, __HIP_MEMORY_SCOPE_AGENT);
}
__device__ __forceinline__ unsigned cld32(const void* p) {
    return __hip_atomic_load((const unsigned*)p, __ATOMIC_RELAXED, __HIP_MEMORY_SCOPE_AGENT);
}
__device__ __forceinline__ void cst32(void* p, unsigned v) {
    __hip_atomic_store((unsigned*)p, v, __ATOMIC_RELAXED, __HIP_MEMORY_SCOPE_AGENT);
}
__device__ __forceinline__ s16x8 cld_frag(const unsigned short* p) {
    union { u64 q[2]; s16x8 v; } u;
    u.q[0] = cld64(p);
    u.q[1] = cld64(p + 4);
    return u.v;
}

// ---- replicated-flag sync ----
__device__ __forceinline__ void postflag(unsigned* flags, int base, int id, unsigned ep)
{
    if (threadIdx.x < NREP)
        cst32(&flags[((long)threadIdx.x * NFID + base + id) * FPAD], ep);
}
__device__ __forceinline__ void waitflags(const unsigned* flags, int base, int n,
                                          unsigned ep, int rep)
{
    const unsigned* fr = flags + (long)rep * NFID * FPAD;
    if (threadIdx.x < 64) {
#pragma unroll 1
        for (int i = threadIdx.x; i < n; i += 64)
            while (cld32(&fr[(long)(base + i) * FPAD]) < ep)
                __builtin_amdgcn_s_sleep(2);
    }
    __syncthreads();
}
__device__ __forceinline__ void fbar(unsigned* flags, int base, int nb, unsigned ep)
{
    __syncthreads();
    postflag(flags, base, blockIdx.x & 63, ep);
    waitflags(flags, base, nb, ep, blockIdx.x & 7);
}

#define FB_GRUP 0
#define FB_GRUH 64
#define FB_LF   128
#define FB_UF   256
#define FB_SF   288

// ---------------- generic MFMA GEMM (precompute only) ----------------
template<typename AT, bool OB>
__global__ __launch_bounds__(256)
void mfma_gemm(const AT* __restrict__ A, const int* __restrict__ idxA,
               const unsigned short* __restrict__ Wb, const float* __restrict__ bias,
               void* __restrict__ Cv,
               int M, int N, int K, int ldA, int Kpad, int ldC, int permC)
{
    __shared__ unsigned short As[64][40];
    __shared__ unsigned short Bs[64][40];
    const int tid = threadIdx.x;
    const int wv = tid >> 6, lane = tid & 63;
    const int wm = wv >> 1, wn = wv & 1;
    const int m0 = blockIdx.y * 64, n0 = blockIdx.x * 64;

    f32x4 acc[2][2] = {{{0.f,0.f,0.f,0.f},{0.f,0.f,0.f,0.f}},
                       {{0.f,0.f,0.f,0.f},{0.f,0.f,0.f,0.f}}};
    const int r_st = tid >> 2, k_st = (tid & 3) * 8;

    long arow = -1;
    {
        int gm = m0 + r_st;
        if (gm < M) arow = idxA ? (long)idxA[gm] : (long)gm;
    }

    const int kIters = (K + 31) / 32;
    for (int it = 0; it < kIters; ++it) {
        const int kg = it * 32 + k_st;
        {
            s16x8 pk = {0,0,0,0,0,0,0,0};
            if (arow >= 0) {
                if constexpr (sizeof(AT) == 2) {
                    if (kg + 8 <= K) {
                        pk = *(const s16x8*)((const unsigned short*)A + arow * (long)ldA + kg);
                    } else {
#pragma unroll
                        for (int j = 0; j < 8; ++j)
                            if (kg + j < K) pk[j] = (short)((const unsigned short*)A)[arow * (long)ldA + kg + j];
                    }
                } else {
                    if (kg + 8 <= K) {
                        const float* p = (const float*)A + arow * (long)ldA + kg;
                        f32x4 u0 = *(const f32x4*)p;
                        f32x4 u1 = *(const f32x4*)(p + 4);
#pragma unroll
                        for (int j = 0; j < 4; ++j) { pk[j] = (short)f2b(u0[j]); pk[4+j] = (short)f2b(u1[j]); }
                    } else {
#pragma unroll
                        for (int j = 0; j < 8; ++j) {
                            int kk = kg + j;
                            if (kk < K) pk[j] = (short)f2b(((const float*)A)[arow * (long)ldA + kk]);
                        }
                    }
                }
            }
            *(s16x8*)&As[r_st][k_st] = pk;
        }
        {
            int gn = n0 + r_st;
            s16x8 pk = {0,0,0,0,0,0,0,0};
            if (gn < N) pk = *(const s16x8*)&Wb[(long)gn * Kpad + kg];
            *(s16x8*)&Bs[r_st][k_st] = pk;
        }
        __syncthreads();
        {
            const int koff = (lane >> 4) * 8;
            s16x8 af[2], bfr[2];
#pragma unroll
            for (int f = 0; f < 2; ++f) {
                af[f]  = *(s16x8*)&As[wm * 32 + f * 16 + (lane & 15)][koff];
                bfr[f] = *(s16x8*)&Bs[wn * 32 + f * 16 + (lane & 15)][koff];
            }
#pragma unroll
            for (int fi = 0; fi < 2; ++fi)
#pragma unroll
                for (int fj = 0; fj < 2; ++fj)
                    acc[fi][fj] = mfma16(af[fi], bfr[fj], acc[fi][fj]);
        }
        __syncthreads();
    }
#pragma unroll
    for (int fi = 0; fi < 2; ++fi)
#pragma unroll
        for (int fj = 0; fj < 2; ++fj)
#pragma unroll
            for (int r = 0; r < 4; ++r) {
                int m = m0 + wm * 32 + fi * 16 + (lane >> 4) * 4 + r;
                int n = n0 + wn * 32 + fj * 16 + (lane & 15);
                if (m < M && n < N) {
                    float v = acc[fi][fj][r];
                    if (bias) v += bias[n];
                    long mo = permC ? ((long)(m & 127) * B_SZ + (m >> 7)) : (long)m;
                    if constexpr (OB) ((unsigned short*)Cv)[mo * ldC + n] = f2b(v);
                    else               ((float*)Cv)[mo * ldC + n] = v;
                }
            }
}

// ---------------- persistent GRU chain (fragment-order h16 mailbox) ----------------
// FH layout: elem addr = ((g8*16 + ks) << 9) + lane*8 + j,  g8 = bh*4 + wv
#define GRU_NB 64
__global__ __launch_bounds__(256, 1)
void gru_chain(const unsigned short* __restrict__ Whh_b, const float* __restrict__ GI,
               const float* __restrict__ bhh, const int* __restrict__ toks,
               float* __restrict__ h32,
               unsigned short* __restrict__ h16a, unsigned short* __restrict__ h16b,
               unsigned short* __restrict__ o_bt,
               unsigned* __restrict__ flags, int fbase)
{
    __shared__ unsigned short wlds[3][16][512];   // 48 KB
    __shared__ unsigned short ht[64][20];
    const int tid = threadIdx.x;
    const int wv = tid >> 6, lane = tid & 63;
    const int dt = blockIdx.x & 31, bh = blockIdx.x >> 5;
    const int b0 = bh * 64;

    for (int s = 0; s < 12; ++s) {
        int slot = tid + s * 256;
        int g = slot >> 10, rem = slot & 1023, ks = rem >> 6, ln = rem & 63;
        int row = g * ND + dt * 16 + (ln & 15);
        int k = ks * 32 + (ln >> 4) * 8;
        *(s16x8*)&wlds[g][ks][ln * 8] = *(const s16x8*)&Whh_b[(long)row * ND + k];
    }
    __syncthreads();

    const int d = dt * 16 + (lane & 15);
    const int brow = b0 + wv * 16 + (lane >> 4) * 4;
    const long fhrd = ((long)(bh * 4 + wv) * 16) << 9;   // read base (this wave)

    // write mapping (ht transpose -> fragment slot)
    const int bl = tid & 63, dq = tid >> 6;
    const long fhwr = (((long)(bh * 4 + (bl >> 4)) * 16 + (dt >> 1)) << 9)
                    + (((((dt & 1) * 16 + dq * 4) >> 3) * 16 + (bl & 15)) * 8)
                    + (((dt & 1) * 16 + dq * 4) & 7);

    float hreg[4];
#pragma unroll
    for (int rr = 0; rr < 4; ++rr) hreg[rr] = h32[(long)(brow + rr) * ND + d];

    float o_run[4] = {0.f, 0.f, 0.f, 0.f};
    unsigned ep = 0;

    for (int t = 0; t < T_SZ; ++t) {
        const unsigned short* hin16 = (t & 1) ? h16b : h16a;
        unsigned short* hout16 = (t & 1) ? h16a : h16b;

        const float* git = GI + (long)t * (B_SZ * G3);
        float gi_r[4], gi_z[4], gi_n[4]; int mk[4];
#pragma unroll
        for (int rr = 0; rr < 4; ++rr) {
            int b = brow + rr;
            gi_r[rr] = git[(long)b * G3 + d];
            gi_z[rr] = git[(long)b * G3 + ND + d];
            gi_n[rr] = git[(long)b * G3 + 2 * ND + d];
            mk[rr]   = toks[b * T_SZ + t];
        }

        f32x4 acc0 = {0,0,0,0}, acc1 = {0,0,0,0}, acc2 = {0,0,0,0};
#pragma unroll
        for (int ks = 0; ks < 16; ++ks) {
            s16x8 a  = cld_frag(&hin16[fhrd + ((long)ks << 9) + lane * 8]);  // coalesced 1KB/wave
            s16x8 br = *(s16x8*)&wlds[0][ks][lane * 8];
            s16x8 bz = *(s16x8*)&wlds[1][ks][lane * 8];
            s16x8 bn = *(s16x8*)&wlds[2][ks][lane * 8];
            acc0 = mfma16(a, br, acc0);
            acc1 = mfma16(a, bz, acc1);
            acc2 = mfma16(a, bn, acc2);
        }

#pragma unroll
        for (int rr = 0; rr < 4; ++rr) {
            int b = brow + rr;
            float rg = fsigmoid(gi_r[rr] + acc0[rr] + bhh[d]);
            float zg = fsigmoid(gi_z[rr] + acc1[rr] + bhh[ND + d]);
            float ng = ftanh(gi_n[rr] + rg * (acc2[rr] + bhh[2 * ND + d]));
            float hr = (1.0f - zg) * ng + zg * hreg[rr];
            bool m = mk[rr] != 0;
            float hn = m ? hr : hreg[rr];
            hreg[rr] = hn;
            ht[b - b0][lane & 15] = f2b(hn);
            if (t == T_SZ - 1) h32[(long)b * ND + d] = hn;
            o_run[rr] = (t == 0) ? hr : (m ? hr : o_run[rr]);
            o_bt[((long)b * T_SZ + t) * ND + d] = f2b(o_run[rr]);
        }
        __syncthreads();
        {
            u64 v = *(u64*)&ht[bl][dq * 4];
            cst64(&hout16[fhwr], v);   // coherent, fragment slot
        }
        fbar(flags, fbase, GRU_NB, ++ep);
    }
}

// ---------------- persistent match chain: 160 blocks, role-split ----------------
// a16/r16 in fragment layout: addr = ((g8*16+ks)<<9) + lane*8, g8 = row>>4
#define UP_NB 32
#define YPITCH 536
__global__ __launch_bounds__(256, 1)
void match_chain(const unsigned short* __restrict__ WrT_b,
                 const unsigned short* __restrict__ mWihL_b,
                 const unsigned short* __restrict__ mWhh_b,
                 const unsigned short* __restrict__ OHWh_tb,
                 const unsigned short* __restrict__ OHGI_tb,
                 const float* __restrict__ m_bhh, const float* __restrict__ Walpha,
                 const unsigned short* __restrict__ Yw_bb,
                 const unsigned short* __restrict__ Y_bb,
                 const int* __restrict__ prem, const int* __restrict__ hyp,
                 float* __restrict__ r32,
                 unsigned short* __restrict__ r16a, unsigned short* __restrict__ r16b,
                 unsigned short* __restrict__ a16, unsigned short* __restrict__ s16,
                 unsigned* __restrict__ flags)
{
    __shared__ __align__(16) unsigned char smem[157696];
    const int tid = threadIdx.x;
    const int wv = tid >> 6, lane = tid & 63;

    if (blockIdx.x < 128) {
        // ================= LOW: attention for b = blockIdx.x =================
        const int b = blockIdx.x;
        const int rep = b & 7;
        unsigned short (*ywl)[YPITCH] = (unsigned short(*)[YPITCH])smem;
        float* wal  = (float*)(smem + 137216);
        float* sarr = (float*)(smem + 139264);
        float* part = (float*)(smem + 141312);
        float* lg   = (float*)(smem + 142336);
        float* red  = (float*)(smem + 142848);
        float* sr2  = (float*)(smem + 142880);

        for (int s = 0; s < 32; ++s) {
            int c = s * 256 + tid;
            int row = c >> 6, cg = c & 63;
            *(s16x8*)&ywl[row][cg * 8] =
                *(const s16x8*)&Yw_bb[((long)b * T_SZ + row) * ND + cg * 8];
        }
        if (tid < 128) {
            f32x4 w = *(const f32x4*)&Walpha[tid * 4];
            *(f32x4*)&wal[tid * 4] = w;
        }
        float mmreg = 0.f;
        if (tid < 128) mmreg = (prem[b * T_SZ + tid] != 0) ? 0.f : 1000.f;
        __syncthreads();

        const int tp = tid >> 1, gh = tid & 1;
        const unsigned short* yrow = &ywl[tp][gh * 256];
        const float* sp  = &sarr[gh * 256];
        const float* wap = &wal[gh * 256];
        const int g = tid >> 7, lt = tid & 127, n4 = lt * 4;
        // a16 fragment write slot for (row=b, cols n4..n4+3)
        const long fa_wr = (((long)(b >> 4) * 16 + (n4 >> 5)) << 9)
                         + ((((n4 >> 3) & 3) * 16 + (b & 15)) * 8) + (n4 & 7);

        for (int t = 0; t < T_SZ; ++t) {
            waitflags(flags, FB_SF, UP_NB, (unsigned)(t + 1), rep);
            if (tid < 64) {
                s16x8 q = cld_frag(&s16[(long)b * ND + tid * 8]);
#pragma unroll
                for (int j = 0; j < 8; ++j) sarr[tid * 8 + j] = b2f((unsigned short)q[j]);
            }
            __syncthreads();
            {
                float acc = 0.f;
#pragma unroll 4
                for (int i8 = 0; i8 < 32; ++i8) {
                    s16x8 yw = *(const s16x8*)&yrow[i8 * 8];
                    f32x4 s0 = *(const f32x4*)&sp[i8 * 8];
                    f32x4 s1 = *(const f32x4*)&sp[i8 * 8 + 4];
                    f32x4 w0 = *(const f32x4*)&wap[i8 * 8];
                    f32x4 w1 = *(const f32x4*)&wap[i8 * 8 + 4];
#pragma unroll
                    for (int j = 0; j < 4; ++j)
                        acc += ftanh(b2f((unsigned short)yw[j]) + s0[j]) * w0[j];
#pragma unroll
                    for (int j = 0; j < 4; ++j)
                        acc += ftanh(b2f((unsigned short)yw[4 + j]) + s1[j]) * w1[j];
                }
                part[tid] = acc;
            }
            __syncthreads();
            if (tid < 128) lg[tid] = __expf(part[tid * 2] + part[tid * 2 + 1] - mmreg);
            __syncthreads();
            float suml = 0.f;
            f32x4 acw = {0.f, 0.f, 0.f, 0.f};
#pragma unroll 8
            for (int i = 0; i < 64; ++i) {
                int tpp = g * 64 + i;
                float al = lg[tpp];
                suml += al;
                u64 q = *(const u64*)&Y_bb[((long)b * T_SZ + tpp) * ND + n4];
                acw[0] += al * b2f((unsigned short)q);
                acw[1] += al * b2f((unsigned short)(q >> 16));
                acw[2] += al * b2f((unsigned short)(q >> 32));
                acw[3] += al * b2f((unsigned short)(q >> 48));
            }
            if (g == 1) {
                *(f32x4*)&sr2[n4] = acw;
                if (lt == 0) red[0] = suml;
            }
            __syncthreads();
            if (g == 0) {
                float inv = 1.0f / (suml + red[0]);
                f32x4 o = *(f32x4*)&sr2[n4];
                u64 pk = (u64)f2b((acw[0] + o[0]) * inv) | ((u64)f2b((acw[1] + o[1]) * inv) << 16)
                       | ((u64)f2b((acw[2] + o[2]) * inv) << 32) | ((u64)f2b((acw[3] + o[3]) * inv) << 48);
                cst64(&a16[fa_wr], pk);
            }
            __syncthreads();
            postflag(flags, FB_LF, b, (unsigned)(t + 1));
        }
    } else {
        // ================= UP: gates + s + combine; d-slice ug*16..+16 =================
        const int ug = blockIdx.x - 128;
        const int rep = ug & 7;
        unsigned short (*wA)[16][512] = (unsigned short(*)[16][512])smem;
        unsigned short (*wR)[16][512] = (unsigned short(*)[16][512])(smem + 49152);
        float (*bounce)[84] = (float(*)[84])(smem + 49152 + 65536);

        for (int s = 0; s < 12; ++s) {
            int slot = tid + s * 256;
            int fam = slot >> 10, rem = slot & 1023, ks = rem >> 6, ln = rem & 63;
            int row = fam * ND + ug * 16 + (ln & 15);
            int k = ks * 32 + (ln >> 4) * 8;
            *(s16x8*)&wA[fam][ks][ln * 8] = *(const s16x8*)&mWihL_b[(long)row * ND + k];
        }
        for (int s = 0; s < 16; ++s) {
            int slot = tid + s * 256;
            int fam = slot >> 10, rem = slot & 1023, ks = rem >> 6, ln = rem & 63;
            int k = ks * 32 + (ln >> 4) * 8;
            const unsigned short* src = (fam < 3)
                ? &mWhh_b[(long)(fam * ND + ug * 16 + (ln & 15)) * ND + k]
                : &WrT_b[(long)(ug * 16 + (ln & 15)) * ND + k];
            *(s16x8*)&wR[fam][ks][ln * 8] = *(const s16x8*)src;
        }
        __syncthreads();

        const int cb = tid >> 1;
        const int half = tid & 1;
        const int d0 = ug * 16 + half * 8;
        // r16 fragment write slot for (row=cb, cols d0..d0+7)
        const long fr_wr = (((long)(cb >> 4) * 16 + (ug >> 1)) << 9)
                         + ((((d0 >> 3) & 3) * 16 + (cb & 15)) * 8);

        f32x4 rpA = {0,0,0,0}, rpB = {0,0,0,0};

        for (int t = 0; t < T_SZ; ++t) {
            const unsigned short* ohw = &OHWh_tb[((long)t * B_SZ + cb) * ND + d0];
            u64 qa = *(const u64*)ohw;
            u64 qb = *(const u64*)(ohw + 4);
            const unsigned short* og = &OHGI_tb[((long)t * B_SZ + cb) * G3];
            u64 q0a = *(const u64*)&og[d0];            u64 q0b = *(const u64*)&og[d0 + 4];
            u64 q1a = *(const u64*)&og[ND + d0];       u64 q1b = *(const u64*)&og[ND + d0 + 4];
            u64 q2a = *(const u64*)&og[2 * ND + d0];   u64 q2b = *(const u64*)&og[2 * ND + d0 + 4];
            int hv = hyp[cb * T_SZ + t];

            waitflags(flags, FB_UF, UP_NB, (unsigned)t, rep);
            const unsigned short* r16rd = (t & 1) ? r16b : r16a;
            unsigned short*       r16wr = (t & 1) ? r16a : r16b;

            // ---- r-phase: fragment reads are contiguous 1KB/wave ----
            f32x4 aSR[2] = {{0,0,0,0},{0,0,0,0}}, aSZ[2] = {{0,0,0,0},{0,0,0,0}};
            f32x4 aHN[2] = {{0,0,0,0},{0,0,0,0}}, aS[2]  = {{0,0,0,0},{0,0,0,0}};
            f32x4 aGN[2] = {{0,0,0,0},{0,0,0,0}};
#pragma unroll
            for (int f = 0; f < 2; ++f) {
                const long gbase = ((long)(wv * 2 + f) * 16) << 9;
#pragma unroll
                for (int ks = 0; ks < 16; ++ks) {
                    s16x8 a = cld_frag(&r16rd[gbase + ((long)ks << 9) + lane * 8]);
                    aSR[f] = mfma16(a, *(s16x8*)&wR[0][ks][lane * 8], aSR[f]);
                    aSZ[f] = mfma16(a, *(s16x8*)&wR[1][ks][lane * 8], aSZ[f]);
                    aHN[f] = mfma16(a, *(s16x8*)&wR[2][ks][lane * 8], aHN[f]);
                    aS[f]  = mfma16(a, *(s16x8*)&wR[3][ks][lane * 8], aS[f]);
                }
            }
#pragma unroll
            for (int f = 0; f < 2; ++f)
#pragma unroll
                for (int rr = 0; rr < 4; ++rr)
                    bounce[wv * 32 + f * 16 + (lane >> 4) * 4 + rr][64 + (lane & 15)] = aS[f][rr];
            __syncthreads();
            {
                u64 w0 = 0, w1 = 0;
#pragma unroll
                for (int j = 0; j < 4; ++j) {
                    float v0 = bounce[cb][64 + half * 8 + j]     + b2f((unsigned short)(qa >> (16 * j)));
                    float v1 = bounce[cb][64 + half * 8 + 4 + j] + b2f((unsigned short)(qb >> (16 * j)));
                    w0 |= (u64)f2b(v0) << (16 * j);
                    w1 |= (u64)f2b(v1) << (16 * j);
                }
                cst64(&s16[(long)cb * ND + d0], w0);
                cst64(&s16[(long)cb * ND + d0 + 4], w1);
            }
            __syncthreads();
            postflag(flags, FB_SF, ug, (unsigned)(t + 1));

            // ---- a-phase ----
            waitflags(flags, FB_LF, 128, (unsigned)(t + 1), rep);
#pragma unroll
            for (int f = 0; f < 2; ++f) {
                const long gbase = ((long)(wv * 2 + f) * 16) << 9;
#pragma unroll
                for (int ks = 0; ks < 16; ++ks) {
                    s16x8 a = cld_frag(&a16[gbase + ((long)ks << 9) + lane * 8]);
                    aSR[f] = mfma16(a, *(s16x8*)&wA[0][ks][lane * 8], aSR[f]);
                    aSZ[f] = mfma16(a, *(s16x8*)&wA[1][ks][lane * 8], aSZ[f]);
                    aGN[f] = mfma16(a, *(s16x8*)&wA[2][ks][lane * 8], aGN[f]);
                }
            }
#pragma unroll
            for (int f = 0; f < 2; ++f)
#pragma unroll
                for (int rr = 0; rr < 4; ++rr) {
                    int bb = wv * 32 + f * 16 + (lane >> 4) * 4 + rr;
                    bounce[bb][0  + (lane & 15)] = aSR[f][rr];
                    bounce[bb][16 + (lane & 15)] = aSZ[f][rr];
                    bounce[bb][32 + (lane & 15)] = aGN[f][rr];
                    bounce[bb][48 + (lane & 15)] = aHN[f][rr];
                }
            __syncthreads();
            {
                bool mkk = hv != 0;
                u64 w0 = 0, w1 = 0;
#pragma unroll
                for (int j = 0; j < 8; ++j) {
                    int dl = half * 8 + j;
                    int dd = ug * 16 + dl;
                    u64 qg0 = (j < 4) ? q0a : q0b;
                    u64 qg1 = (j < 4) ? q1a : q1b;
                    u64 qg2 = (j < 4) ? q2a : q2b;
                    int sh = 16 * (j & 3);
                    float sr  = bounce[cb][0 + dl]  + b2f((unsigned short)(qg0 >> sh)) + m_bhh[dd];
                    float sz  = bounce[cb][16 + dl] + b2f((unsigned short)(qg1 >> sh)) + m_bhh[ND + dd];
                    float gin = bounce[cb][32 + dl] + b2f((unsigned short)(qg2 >> sh));
                    float ghn = bounce[cb][48 + dl] + m_bhh[2 * ND + dd];
                    float rg = fsigmoid(sr), zg = fsigmoid(sz);
                    float ng = ftanh(gin + rg * ghn);
                    float rp = (j < 4) ? rpA[j & 3] : rpB[j & 3];
                    float rn = (1.0f - zg) * ng + zg * rp;
                    float v = mkk ? rn : rp;
                    if (j < 4) rpA[j & 3] = v; else rpB[j & 3] = v;
                    if (j < 4) w0 |= (u64)f2b(v) << sh; else w1 |= (u64)f2b(v) << sh;
                }
                if (t == T_SZ - 1) {
                    *(f32x4*)&r32[(long)cb * ND + d0] = rpA;
                    *(f32x4*)&r32[(long)cb * ND + d0 + 4] = rpB;
                }
                cst64(&r16wr[fr_wr], w0);
                cst64(&r16wr[fr_wr + 4], w1);
            }
            __syncthreads();
            postflag(flags, FB_UF, ug, (unsigned)(t + 1));
        }
    }
}

// ---------------- prep / misc ----------------
__global__ void prep_idx(const int* __restrict__ prem, const int* __restrict__ hyp,
                         int* __restrict__ idx_p, int* __restrict__ idx_h)
{
    int i = blockIdx.x * blockDim.x + threadIdx.x;
    if (i < B_SZ * T_SZ) {
        int t = i / B_SZ, b = i % B_SZ;
        idx_p[i] = prem[b * T_SZ + t];
        idx_h[i] = hyp[b * T_SZ + t];
    }
}

__global__ void conv_w(const float* __restrict__ in, unsigned short* __restrict__ out,
                       int N, int K, int Kpad, int ldIn, int colOff)
{
    long i = (long)blockIdx.x * blockDim.x + threadIdx.x;
    if (i >= (long)N * Kpad) return;
    int n = (int)(i / Kpad), k = (int)(i % Kpad);
    float v = (k < K) ? in[(long)n * ldIn + k + colOff] : 0.0f;
    out[i] = f2b(v);
}

__global__ void conv_wT(const float* __restrict__ in, unsigned short* __restrict__ out,
                        int N, int K, int Kpad, int ldIn)
{
    long i = (long)blockIdx.x * blockDim.x + threadIdx.x;
    if (i >= (long)N * Kpad) return;
    int n = (int)(i / Kpad), k = (int)(i % Kpad);
    float v = (k < K) ? in[(long)k * ldIn + n] : 0.0f;
    out[i] = f2b(v);
}

__global__ void zero_kernel(float* __restrict__ p, int n)
{
    int i = blockIdx.x * blockDim.x + threadIdx.x;
    if (i < n) p[i] = 0.0f;
}

__global__ void final_logits(const float* __restrict__ r, const float* __restrict__ outW,
                             const float* __restrict__ outb, float* __restrict__ out)
{
    int b = blockIdx.x;
    int lane = threadIdx.x;
    float a0 = 0.0f, a1 = 0.0f, a2 = 0.0f;
    for (int k = lane; k < ND; k += 64) {
        float rv = r[(long)b * ND + k];
        a0 += rv * outW[0 * ND + k];
        a1 += rv * outW[1 * ND + k];
        a2 += rv * outW[2 * ND + k];
    }
#pragma unroll
    for (int off = 32; off; off >>= 1) {
        a0 += __shfl_down(a0, off);
        a1 += __shfl_down(a1, off);
        a2 += __shfl_down(a2, off);
    }
    if (lane == 0) {
        float l0 = a0 + outb[0], l1 = a1 + outb[1], l2 = a2 + outb[2];
        float mx = fmaxf(l0, fmaxf(l1, l2));
        float se = expf(l0 - mx) + expf(l1 - mx) + expf(l2 - mx);
        float ls = mx + logf(se);
        out[b * 3 + 0] = l0 - ls;
        out[b * 3 + 1] = l1 - ls;
        out[b * 3 + 2] = l2 - ls;
    }
}

// ---------------- host ----------------
extern "C" void kernel_launch(void* const* d_in, const int* in_sizes, int n_in,
                              void* d_out, int out_size, void* d_ws, size_t ws_size,
                              hipStream_t stream)
{
    const int*   prem    = (const int*)d_in[0];
    const int*   hyp     = (const int*)d_in[1];
    const float* E       = (const float*)d_in[2];
    const float* p_Wih   = (const float*)d_in[3];
    const float* p_Whh   = (const float*)d_in[4];
    const float* p_bih   = (const float*)d_in[5];
    const float* p_bhh   = (const float*)d_in[6];
    const float* h_Wih   = (const float*)d_in[7];
    const float* h_Whh   = (const float*)d_in[8];
    const float* h_bih   = (const float*)d_in[9];
    const float* h_bhh   = (const float*)d_in[10];
    const float* m_Wih   = (const float*)d_in[11];
    const float* m_Whh   = (const float*)d_in[12];
    const float* m_bih   = (const float*)d_in[13];
    const float* m_bhh   = (const float*)d_in[14];
    const float* W_y     = (const float*)d_in[15];
    const float* W_h     = (const float*)d_in[16];
    const float* W_r     = (const float*)d_in[17];
    const float* W_alpha = (const float*)d_in[18];
    const float* out_W   = (const float*)d_in[19];
    const float* out_b   = (const float*)d_in[20];
    float* out = (float*)d_out;

    const int MB = T_SZ * B_SZ;  // 16384
    const int NFLAGS = NREP * NFID * FPAD;

    float* ws = (float*)d_ws;
    size_t off = 0;
    float* GI    = ws + off; off += (size_t)MB * G3;
    float* h32   = ws + off; off += (size_t)B_SZ * ND;
    float* r32   = ws + off; off += (size_t)B_SZ * ND;
    unsigned* flags = (unsigned*)(ws + off); off += NFLAGS;
    int* idx_p = (int*)(ws + off); off += (size_t)B_SZ * T_SZ;
    int* idx_h = (int*)(ws + off); off += (size_t)B_SZ * T_SZ;
    unsigned short* ub = (unsigned short*)(ws + off);
    size_t uoff = 0;
    unsigned short* o_p_bt = ub + uoff; uoff += (size_t)MB * ND;   // Y_bb
    unsigned short* o_h_bt = ub + uoff; uoff += (size_t)MB * ND;
    unsigned short* Yw_bb  = ub + uoff; uoff += (size_t)MB * ND;
    unsigned short* OHWh_tb= ub + uoff; uoff += (size_t)MB * ND;
    unsigned short* OHGI_tb= ub + uoff; uoff += (size_t)MB * G3;
    unsigned short* h16a   = ub + uoff; uoff += (size_t)B_SZ * ND;
    unsigned short* h16b   = ub + uoff; uoff += (size_t)B_SZ * ND;
    unsigned short* r16a   = ub + uoff; uoff += (size_t)B_SZ * ND;
    unsigned short* r16b   = ub + uoff; uoff += (size_t)B_SZ * ND;
    unsigned short* a16    = ub + uoff; uoff += (size_t)B_SZ * ND;
    unsigned short* s16    = ub + uoff; uoff += (size_t)B_SZ * ND;
    unsigned short* pWih_b = ub + uoff; uoff += (size_t)G3 * 320;
    unsigned short* hWih_b = ub + uoff; uoff += (size_t)G3 * 320;
    unsigned short* pWhh_b = ub + uoff; uoff += (size_t)G3 * ND;
    unsigned short* hWhh_b = ub + uoff; uoff += (size_t)G3 * ND;
    unsigned short* mWihL_b= ub + uoff; uoff += (size_t)G3 * ND;
    unsigned short* mWihR  = ub + uoff; uoff += (size_t)G3 * ND;
    unsigned short* mWhh_b = ub + uoff; uoff += (size_t)G3 * ND;
    unsigned short* WyT_b  = ub + uoff; uoff += (size_t)ND * ND;
    unsigned short* WhT_b  = ub + uoff; uoff += (size_t)ND * ND;
    unsigned short* WrT_b  = ub + uoff; uoff += (size_t)ND * ND;
    off += (uoff + 1) / 2;
    if (ws_size < off * sizeof(float)) return;

    auto cblk = [](long n) { return (int)((n + 255) / 256); };

    // ---- prep ----
    prep_idx<<<cblk(MB), 256, 0, stream>>>(prem, hyp, idx_p, idx_h);
    conv_w <<<cblk((long)G3 * 320), 256, 0, stream>>>(p_Wih, pWih_b, G3, EMBD, 320, EMBD, 0);
    conv_w <<<cblk((long)G3 * 320), 256, 0, stream>>>(h_Wih, hWih_b, G3, EMBD, 320, EMBD, 0);
    conv_w <<<cblk((long)G3 * ND), 256, 0, stream>>>(p_Whh, pWhh_b, G3, ND, ND, ND, 0);
    conv_w <<<cblk((long)G3 * ND), 256, 0, stream>>>(h_Whh, hWhh_b, G3, ND, ND, ND, 0);
    conv_w <<<cblk((long)G3 * ND), 256, 0, stream>>>(m_Wih, mWihL_b, G3, ND, ND, 2 * ND, 0);
    conv_w <<<cblk((long)G3 * ND), 256, 0, stream>>>(m_Wih, mWihR, G3, ND, ND, 2 * ND, ND);
    conv_w <<<cblk((long)G3 * ND), 256, 0, stream>>>(m_Whh, mWhh_b, G3, ND, ND, ND, 0);
    conv_wT<<<cblk((long)ND * ND), 256, 0, stream>>>(W_y, WyT_b, ND, ND, ND, ND);
    conv_wT<<<cblk((long)ND * ND), 256, 0, stream>>>(W_h, WhT_b, ND, ND, ND, ND);
    conv_wT<<<cblk((long)ND * ND), 256, 0, stream>>>(W_r, WrT_b, ND, ND, ND, ND);
    zero_kernel<<<cblk(B_SZ * ND), 256, 0, stream>>>(h32, B_SZ * ND);
    zero_kernel<<<cblk(B_SZ * ND / 2), 256, 0, stream>>>((float*)h16a, B_SZ * ND / 2);
    zero_kernel<<<cblk(B_SZ * ND), 256, 0, stream>>>(r32, B_SZ * ND);
    zero_kernel<<<cblk(B_SZ * ND / 2), 256, 0, stream>>>((float*)r16a, B_SZ * ND / 2);
    zero_kernel<<<cblk(B_SZ * ND / 2), 256, 0, stream>>>((float*)r16b, B_SZ * ND / 2);
    zero_kernel<<<cblk(NFLAGS), 256, 0, stream>>>((float*)flags, NFLAGS);

    // ---- premise ----
    {
        dim3 g(G3 / 64, MB / 64);
        mfma_gemm<float, false><<<g, 256, 0, stream>>>(E, idx_p, pWih_b, p_bih, GI,
                                                       MB, G3, EMBD, EMBD, 320, G3, 0);
    }
    gru_chain<<<GRU_NB, 256, 0, stream>>>(pWhh_b, GI, p_bhh, prem, h32, h16a, h16b,
                                          o_p_bt, flags, FB_GRUP);

    // ---- hypothesis ----
    {
        dim3 g(G3 / 64, MB / 64);
        mfma_gemm<float, false><<<g, 256, 0, stream>>>(E, idx_h, hWih_b, h_bih, GI,
                                                       MB, G3, EMBD, EMBD, 320, G3, 0);
    }
    gru_chain<<<GRU_NB, 256, 0, stream>>>(hWhh_b, GI, h_bhh, hyp, h32, h16a, h16b,
                                          o_h_bt, flags, FB_GRUH);

    // ---- attention precompute ----
    {
        dim3 g(ND / 64, MB / 64);
        mfma_gemm<unsigned short, true><<<g, 256, 0, stream>>>(o_p_bt, nullptr, WyT_b, nullptr,
                                                               Yw_bb, MB, ND, ND, ND, ND, ND, 0);
        mfma_gemm<unsigned short, true><<<g, 256, 0, stream>>>(o_h_bt, nullptr, WhT_b, nullptr,
                                                               OHWh_tb, MB, ND, ND, ND, ND, ND, 1);
        dim3 g2(G3 / 64, MB / 64);
        mfma_gemm<unsigned short, true><<<g2, 256, 0, stream>>>(o_h_bt, nullptr, mWihR, m_bih,
                                                                OHGI_tb, MB, G3, ND, ND, ND, G3, 1);
    }

    // ---- match chain ----
    match_chain<<<160, 256, 0, stream>>>(WrT_b, mWihL_b, mWhh_b, OHWh_tb, OHGI_tb,
                                         m_bhh, W_alpha, Yw_bb, o_p_bt, prem, hyp,
                                         r32, r16a, r16b, a16, s16, flags);

    final_logits<<<B_SZ, 64, 0, stream>>>(r32, out_W, out_b, out);
}